// Round 1
// baseline (9596.754 us; speedup 1.0000x reference)
//
#include <hip/hip_runtime.h>
#include <math.h>

#define N_NODES 51200
#define N_EDGES 409600
#define FEAT    768
#define HID     256
#define NPG     200
#define G_GRAPHS 256

// ---------------- CSR build ----------------
__global__ __launch_bounds__(256) void k_deg(const int* __restrict__ ei, int* __restrict__ deg) {
    int e = blockIdx.x * 256 + threadIdx.x;
    if (e < N_EDGES) atomicAdd(&deg[ei[N_EDGES + e]], 1);
}

__global__ __launch_bounds__(1024) void k_scan(const int* __restrict__ deg, int* __restrict__ rowp) {
    __shared__ int sums[1024];
    int tid = threadIdx.x;
    int base = tid * 50;
    int s = 0;
    for (int j = 0; j < 50; ++j) s += deg[base + j];
    sums[tid] = s;
    __syncthreads();
    for (int off = 1; off < 1024; off <<= 1) {
        int v = 0;
        if (tid >= off) v = sums[tid - off];
        __syncthreads();
        sums[tid] += v;
        __syncthreads();
    }
    int run = sums[tid] - s; // exclusive prefix
    for (int j = 0; j < 50; ++j) { rowp[base + j] = run; run += deg[base + j]; }
    if (tid == 1023) rowp[N_NODES] = run;
}

__global__ __launch_bounds__(256) void k_fill(const int* __restrict__ ei, const int* __restrict__ rowp,
                                              int* __restrict__ fill, int* __restrict__ col) {
    int e = blockIdx.x * 256 + threadIdx.x;
    if (e < N_EDGES) {
        int d = ei[N_EDGES + e];
        int pos = atomicAdd(&fill[d], 1);
        col[rowp[d] + pos] = ei[e];
    }
}

// ---------------- generic fp32 GEMM: C[N,J] = A[N,K] @ op(B) + bias ----------------
// NT=1: B is [J,K] row-major (C = A @ B^T).  NT=0: B is [K,J] row-major (C = A @ B).
// Tile 128x128, BK=16, 256 threads, 8x8 micro-tile in split 4+4 chunks.
template<int NT>
__global__ __launch_bounds__(256) void k_gemm(const float* __restrict__ A, const float* __restrict__ B,
                                              const float* __restrict__ bias, float* __restrict__ C,
                                              int K, int J) {
    __shared__ float As[16][128];
    __shared__ float Bs[16][128];
    int tid = threadIdx.x;
    int mt = tid & 15, nt = tid >> 4;
    int rowBase = blockIdx.x * 128;
    int colBase = blockIdx.y * 128;
    float acc[8][8] = {};
    for (int k0 = 0; k0 < K; k0 += 16) {
        // stage A (transpose to k-major)
        #pragma unroll
        for (int i = 0; i < 2; ++i) {
            int chunk = tid + i * 256;        // 0..511
            int r = chunk >> 2;               // 0..127
            int kc = (chunk & 3) << 2;        // 0,4,8,12
            const float4 v = *(const float4*)&A[(size_t)(rowBase + r) * K + k0 + kc];
            As[kc + 0][r] = v.x; As[kc + 1][r] = v.y; As[kc + 2][r] = v.z; As[kc + 3][r] = v.w;
        }
        if (NT) {
            #pragma unroll
            for (int i = 0; i < 2; ++i) {
                int chunk = tid + i * 256;
                int r = chunk >> 2;
                int kc = (chunk & 3) << 2;
                const float4 v = *(const float4*)&B[(size_t)(colBase + r) * K + k0 + kc];
                Bs[kc + 0][r] = v.x; Bs[kc + 1][r] = v.y; Bs[kc + 2][r] = v.z; Bs[kc + 3][r] = v.w;
            }
        } else {
            #pragma unroll
            for (int i = 0; i < 2; ++i) {
                int chunk = tid + i * 256;
                int kr = chunk >> 5;              // 0..15
                int jc = (chunk & 31) << 2;       // 0..124
                *(float4*)&Bs[kr][jc] = *(const float4*)&B[(size_t)(k0 + kr) * J + colBase + jc];
            }
        }
        __syncthreads();
        #pragma unroll
        for (int k = 0; k < 16; ++k) {
            float4 a0 = *(const float4*)&As[k][mt * 4];
            float4 a1 = *(const float4*)&As[k][mt * 4 + 64];
            float4 b0 = *(const float4*)&Bs[k][nt * 4];
            float4 b1 = *(const float4*)&Bs[k][nt * 4 + 64];
            float a[8] = {a0.x, a0.y, a0.z, a0.w, a1.x, a1.y, a1.z, a1.w};
            float b[8] = {b0.x, b0.y, b0.z, b0.w, b1.x, b1.y, b1.z, b1.w};
            #pragma unroll
            for (int i = 0; i < 8; ++i)
                #pragma unroll
                for (int j = 0; j < 8; ++j)
                    acc[i][j] = fmaf(a[i], b[j], acc[i][j]);
        }
        __syncthreads();
    }
    #pragma unroll
    for (int i = 0; i < 8; ++i) {
        int rloc = (i < 4) ? (mt * 4 + i) : (64 + mt * 4 + (i - 4));
        size_t row = (size_t)(rowBase + rloc);
        #pragma unroll
        for (int half = 0; half < 2; ++half) {
            int c = colBase + nt * 4 + half * 64;
            float4 v;
            v.x = acc[i][half * 4 + 0]; v.y = acc[i][half * 4 + 1];
            v.z = acc[i][half * 4 + 2]; v.w = acc[i][half * 4 + 3];
            if (bias) {
                const float4 bv = *(const float4*)&bias[c];
                v.x += bv.x; v.y += bv.y; v.z += bv.z; v.w += bv.w;
            }
            *(float4*)&C[row * J + c] = v;
        }
    }
}

// ---------------- per-node gather-sum (segment_sum via CSR) ----------------
__global__ __launch_bounds__(256) void k_agg(const float* __restrict__ m, const int* __restrict__ rowp,
                                             const int* __restrict__ col, float* __restrict__ agg) {
    int v = blockIdx.x;
    int f = threadIdx.x;
    int beg = rowp[v], end = rowp[v + 1];
    float s = 0.f;
    for (int i = beg; i < end; ++i)
        s += m[(size_t)col[i] * HID + f];
    agg[(size_t)v * HID + f] = s;
}

// ---------------- GRU elementwise update (in-place on h) ----------------
__global__ __launch_bounds__(256) void k_gru(float* __restrict__ h, const float* __restrict__ gi,
                                             const float* __restrict__ gh) {
    size_t idx = (size_t)blockIdx.x * 256 + threadIdx.x;   // < N*HID
    int n = (int)(idx >> 8);
    int c = (int)(idx & 255);
    size_t b = (size_t)n * 768;
    float ir = gi[b + c], iz = gi[b + 256 + c], inn = gi[b + 512 + c];
    float hr = gh[b + c], hz = gh[b + 256 + c], hnn = gh[b + 512 + c];
    float hv = h[idx];
    float r = 1.f / (1.f + expf(-(ir + hr)));
    float z = 1.f / (1.f + expf(-(iz + hz)));
    float ng = tanhf(inn + r * hnn);
    h[idx] = (1.f - z) * ng + z * hv;
}

// ---------------- conv1 (in=NPG channels over length H, k=3 pad 1) + ReLU ----------------
// input(t) = t<HID ? h[node][t] : x[node][t-HID]; node = g*NPG + c
__global__ __launch_bounds__(256) void k_conv1(const float* __restrict__ h, const float* __restrict__ x,
                                               const float* __restrict__ Wc1, const float* __restrict__ bc1,
                                               float* __restrict__ out, int H) {
    __shared__ float inL[25][68];
    __shared__ float wL[25][50][4];
    int g = blockIdx.x;
    int t0 = blockIdx.y * 64;
    int tid = threadIdx.x;
    int t4 = tid & 15, og = tid >> 4;
    int ni = (og < 2) ? 4 : 3;   // o = og + 16*i, o<50
    float acc[4][4] = {};
    for (int cc0 = 0; cc0 < NPG; cc0 += 25) {
        for (int l = tid; l < 25 * 66; l += 256) {
            int r = l / 66, lc = l - r * 66;
            int t = t0 - 1 + lc;
            int node = g * NPG + cc0 + r;
            float v = 0.f;
            if (t >= 0 && t < H)
                v = (t < HID) ? h[(size_t)node * HID + t] : x[(size_t)node * FEAT + (t - HID)];
            inL[r][lc] = v;
        }
        for (int l = tid; l < 25 * 150; l += 256) {
            int cc = l / 150; int rem = l - cc * 150;
            int o = rem / 3;  int dk = rem - o * 3;
            wL[cc][o][dk] = Wc1[o * 600 + (cc0 + cc) * 3 + dk];
        }
        __syncthreads();
        for (int cc = 0; cc < 25; ++cc) {
            float4 va = *(const float4*)&inL[cc][t4 * 4];
            float2 vb = *(const float2*)&inL[cc][t4 * 4 + 4];
            float in6[6] = {va.x, va.y, va.z, va.w, vb.x, vb.y};
            #pragma unroll 4
            for (int i = 0; i < ni; ++i) {
                int o = og + 16 * i;
                float4 w = *(const float4*)&wL[cc][o][0];
                acc[i][0] += w.x * in6[0] + w.y * in6[1] + w.z * in6[2];
                acc[i][1] += w.x * in6[1] + w.y * in6[2] + w.z * in6[3];
                acc[i][2] += w.x * in6[2] + w.y * in6[3] + w.z * in6[4];
                acc[i][3] += w.x * in6[3] + w.y * in6[4] + w.z * in6[5];
            }
        }
        __syncthreads();
    }
    for (int i = 0; i < ni; ++i) {
        int o = og + 16 * i;
        float b = bc1[o];
        float4 v;
        float r0 = acc[i][0] + b, r1 = acc[i][1] + b, r2 = acc[i][2] + b, r3 = acc[i][3] + b;
        v.x = r0 > 0.f ? r0 : 0.f; v.y = r1 > 0.f ? r1 : 0.f;
        v.z = r2 > 0.f ? r2 : 0.f; v.w = r3 > 0.f ? r3 : 0.f;
        size_t base = (size_t)g * 50 * H + (size_t)o * H + t0 + t4 * 4;
        *(float4*)&out[base] = v;
    }
}

// ---------------- maxpool1d k=3 s=2 ----------------
__global__ __launch_bounds__(256) void k_pool1(const float* __restrict__ in, float* __restrict__ out,
                                               int H, int U) {
    int g = blockIdx.x, o = blockIdx.y;
    const float* p = in + ((size_t)g * 50 + o) * H;
    float* q = out + ((size_t)g * 50 + o) * U;
    for (int u = threadIdx.x; u < U; u += 256) {
        float a = p[2 * u], b = p[2 * u + 1], c = p[2 * u + 2];
        float mm = a > b ? a : b;
        q[u] = mm > c ? mm : c;
    }
}

// ---------------- conv2 (k=1) + maxpool k=2 s=2 ----------------
__global__ __launch_bounds__(256) void k_c2p2(const float* __restrict__ P1, const float* __restrict__ Wc2,
                                              const float* __restrict__ bc2, float* __restrict__ out,
                                              int U, int U2) {
    int g = blockIdx.x, o2 = blockIdx.y;
    float b = bc2[o2];
    for (int u2 = threadIdx.x; u2 < U2; u2 += 256) {
        float a0 = b, a1 = b;
        #pragma unroll 5
        for (int i = 0; i < 50; ++i) {
            float wv = Wc2[o2 * 50 + i];
            const float* p = P1 + ((size_t)g * 50 + i) * U + 2 * u2;
            a0 = fmaf(p[0], wv, a0);
            a1 = fmaf(p[1], wv, a1);
        }
        out[((size_t)g * 20 + o2) * U2 + u2] = a0 > a1 ? a0 : a1;
    }
}

// ---------------- fully-connected (per-graph dot) ----------------
__global__ __launch_bounds__(256) void k_fc(const float* __restrict__ P2, const float* __restrict__ Wf,
                                            const float* __restrict__ bf, float* __restrict__ out, int len) {
    __shared__ float red[256];
    int g = blockIdx.x, tid = threadIdx.x;
    const float* p = P2 + (size_t)g * len;
    float s = 0.f;
    for (int i = tid; i < len; i += 256) s = fmaf(p[i], Wf[i], s);
    red[tid] = s;
    __syncthreads();
    for (int off = 128; off > 0; off >>= 1) {
        if (tid < off) red[tid] += red[tid + off];
        __syncthreads();
    }
    if (tid == 0) out[g] = red[0] + bf[0];
}

// ---------------- final: sigmoid(z*y) -> clip -> logit -> [0, z1] ----------------
__global__ __launch_bounds__(256) void k_final(const float* __restrict__ z, const float* __restrict__ y,
                                               float* __restrict__ out) {
    int g = threadIdx.x;
    float t = z[g] * y[g];
    float p = 1.f / (1.f + expf(-t));
    p = fminf(fmaxf(p, 1e-6f), 1.f - 1e-6f);
    float z1 = logf(p / (1.f - p));
    out[2 * g] = 0.f;
    out[2 * g + 1] = z1;
}

extern "C" void kernel_launch(void* const* d_in, const int* in_sizes, int n_in,
                              void* d_out, int out_size, void* d_ws, size_t ws_size,
                              hipStream_t stream) {
    const float* x     = (const float*)d_in[0];
    const int*   ei    = (const int*)d_in[1];
    const float* W_in  = (const float*)d_in[2];
    const float* b_in  = (const float*)d_in[3];
    const float* W_g   = (const float*)d_in[4];
    const float* W_ih  = (const float*)d_in[5];
    const float* W_hh  = (const float*)d_in[6];
    const float* b_ih  = (const float*)d_in[7];
    const float* b_hh  = (const float*)d_in[8];
    const float* Wc1   = (const float*)d_in[9];
    const float* bc1   = (const float*)d_in[10];
    const float* Wc2   = (const float*)d_in[11];
    const float* bc2   = (const float*)d_in[12];
    const float* Wf1   = (const float*)d_in[13];
    const float* bf1   = (const float*)d_in[14];
    const float* Wf2   = (const float*)d_in[15];
    const float* bf2   = (const float*)d_in[16];

    float* ws = (float*)d_ws;
    const size_t F_H   = 0;
    const size_t F_B   = (size_t)N_NODES * HID;                 // region B: 39.3M floats (m/gi/conv)
    const size_t F_C   = F_B + (size_t)N_NODES * 768;           // region C: gh/conv
    const size_t F_AGG = F_C + (size_t)N_NODES * 768;
    const size_t F_INT = F_AGG + (size_t)N_NODES * HID;

    float* h   = ws + F_H;
    float* m   = ws + F_B;
    float* gi  = ws + F_B;
    float* gh  = ws + F_C;
    float* agg = ws + F_AGG;

    int* deg  = (int*)(ws + F_INT);
    int* fill = deg + N_NODES;
    int* rowp = fill + N_NODES;
    int* col  = rowp + (N_NODES + 1);
    float* zb = (float*)(col + N_EDGES);
    float* yb = zb + 256;

    // conv-phase aliases (GGNN scratch is dead by then)
    float* C1Z = ws + F_B;
    float* P1Z = ws + F_B + 16777216;
    float* P2Z = ws + F_C;
    float* C1Y = ws + F_B;
    float* P1Y = ws + F_B + 8388608;
    float* P2Y = ws + F_C + 4194304;

    // ---- CSR build ----
    hipMemsetAsync(deg, 0, N_NODES * sizeof(int), stream);
    hipMemsetAsync(fill, 0, N_NODES * sizeof(int), stream);
    k_deg<<<N_EDGES / 256, 256, 0, stream>>>(ei, deg);
    k_scan<<<1, 1024, 0, stream>>>(deg, rowp);
    k_fill<<<N_EDGES / 256, 256, 0, stream>>>(ei, rowp, fill, col);

    // ---- h0 = x @ W_in^T + b_in ----
    k_gemm<1><<<dim3(N_NODES / 128, 2), 256, 0, stream>>>(x, W_in, b_in, h, FEAT, HID);

    // ---- GGNN layers ----
    for (int l = 0; l < 6; ++l) {
        k_gemm<0><<<dim3(N_NODES / 128, 2), 256, 0, stream>>>(h, W_g + (size_t)l * HID * HID, nullptr, m, HID, HID);
        k_agg<<<N_NODES, 256, 0, stream>>>(m, rowp, col, agg);
        k_gemm<1><<<dim3(N_NODES / 128, 6), 256, 0, stream>>>(agg, W_ih, b_ih, gi, HID, 768);
        k_gemm<1><<<dim3(N_NODES / 128, 6), 256, 0, stream>>>(h, W_hh, b_hh, gh, HID, 768);
        k_gru<<<N_NODES, 256, 0, stream>>>(h, gi, gh);
    }

    // ---- conv head: Z path (concat [h|x], H=1024) ----
    k_conv1<<<dim3(G_GRAPHS, 16), 256, 0, stream>>>(h, x, Wc1, bc1, C1Z, 1024);
    k_pool1<<<dim3(G_GRAPHS, 50), 256, 0, stream>>>(C1Z, P1Z, 1024, 511);
    k_c2p2<<<dim3(G_GRAPHS, 20), 256, 0, stream>>>(P1Z, Wc2, bc2, P2Z, 511, 255);
    k_fc<<<G_GRAPHS, 256, 0, stream>>>(P2Z, Wf1, bf1, zb, 20 * 255);

    // ---- conv head: Y path (h only, H=256) ----
    k_conv1<<<dim3(G_GRAPHS, 4), 256, 0, stream>>>(h, x, Wc1, bc1, C1Y, 256);
    k_pool1<<<dim3(G_GRAPHS, 50), 256, 0, stream>>>(C1Y, P1Y, 256, 127);
    k_c2p2<<<dim3(G_GRAPHS, 20), 256, 0, stream>>>(P1Y, Wc2, bc2, P2Y, 127, 63);
    k_fc<<<G_GRAPHS, 256, 0, stream>>>(P2Y, Wf2, bf2, yb, 20 * 63);

    // ---- final ----
    k_final<<<1, 256, 0, stream>>>(zb, yb, (float*)d_out);
}

// Round 2
// 5351.353 us; speedup vs baseline: 1.7933x; 1.7933x over previous
//
#include <hip/hip_runtime.h>
#include <math.h>

#define N_NODES 51200
#define N_EDGES 409600
#define FEAT    768
#define HID     256
#define NPG     200
#define G_GRAPHS 256

// ---------------- CSR build ----------------
__global__ __launch_bounds__(256) void k_deg(const int* __restrict__ ei, int* __restrict__ deg) {
    int e = blockIdx.x * 256 + threadIdx.x;
    if (e < N_EDGES) atomicAdd(&deg[ei[N_EDGES + e]], 1);
}

__global__ __launch_bounds__(1024) void k_scan(const int* __restrict__ deg, int* __restrict__ rowp) {
    __shared__ int sums[1024];
    int tid = threadIdx.x;
    int base = tid * 50;
    int s = 0;
    for (int j = 0; j < 50; ++j) s += deg[base + j];
    sums[tid] = s;
    __syncthreads();
    for (int off = 1; off < 1024; off <<= 1) {
        int v = 0;
        if (tid >= off) v = sums[tid - off];
        __syncthreads();
        sums[tid] += v;
        __syncthreads();
    }
    int run = sums[tid] - s; // exclusive prefix
    for (int j = 0; j < 50; ++j) { rowp[base + j] = run; run += deg[base + j]; }
    if (tid == 1023) rowp[N_NODES] = run;
}

__global__ __launch_bounds__(256) void k_fill(const int* __restrict__ ei, const int* __restrict__ rowp,
                                              int* __restrict__ fill, int* __restrict__ col) {
    int e = blockIdx.x * 256 + threadIdx.x;
    if (e < N_EDGES) {
        int d = ei[N_EDGES + e];
        int pos = atomicAdd(&fill[d], 1);
        col[rowp[d] + pos] = ei[e];
    }
}

// ---------------- generic fp32 GEMM: C[N,J] = A[N,K] @ op(B) + bias ----------------
// NT=1: B is [J,K] row-major (C = A @ B^T).  NT=0: B is [K,J] row-major (C = A @ B).
// Tile 128x128, BK=16, 256 threads, 8x8 micro-tile in split 4+4 chunks.
template<int NT>
__global__ __launch_bounds__(256) void k_gemm(const float* __restrict__ A, const float* __restrict__ B,
                                              const float* __restrict__ bias, float* __restrict__ C,
                                              int K, int J) {
    __shared__ float As[16][128];
    __shared__ float Bs[16][128];
    int tid = threadIdx.x;
    int mt = tid & 15, nt = tid >> 4;
    int rowBase = blockIdx.x * 128;
    int colBase = blockIdx.y * 128;
    float acc[8][8] = {};
    for (int k0 = 0; k0 < K; k0 += 16) {
        // stage A (transpose to k-major)
        #pragma unroll
        for (int i = 0; i < 2; ++i) {
            int chunk = tid + i * 256;        // 0..511
            int r = chunk >> 2;               // 0..127
            int kc = (chunk & 3) << 2;        // 0,4,8,12
            const float4 v = *(const float4*)&A[(size_t)(rowBase + r) * K + k0 + kc];
            As[kc + 0][r] = v.x; As[kc + 1][r] = v.y; As[kc + 2][r] = v.z; As[kc + 3][r] = v.w;
        }
        if (NT) {
            #pragma unroll
            for (int i = 0; i < 2; ++i) {
                int chunk = tid + i * 256;
                int r = chunk >> 2;
                int kc = (chunk & 3) << 2;
                const float4 v = *(const float4*)&B[(size_t)(colBase + r) * K + k0 + kc];
                Bs[kc + 0][r] = v.x; Bs[kc + 1][r] = v.y; Bs[kc + 2][r] = v.z; Bs[kc + 3][r] = v.w;
            }
        } else {
            #pragma unroll
            for (int i = 0; i < 2; ++i) {
                int chunk = tid + i * 256;
                int kr = chunk >> 5;              // 0..15
                int jc = (chunk & 31) << 2;       // 0..124
                *(float4*)&Bs[kr][jc] = *(const float4*)&B[(size_t)(k0 + kr) * J + colBase + jc];
            }
        }
        __syncthreads();
        #pragma unroll
        for (int k = 0; k < 16; ++k) {
            float4 a0 = *(const float4*)&As[k][mt * 4];
            float4 a1 = *(const float4*)&As[k][mt * 4 + 64];
            float4 b0 = *(const float4*)&Bs[k][nt * 4];
            float4 b1 = *(const float4*)&Bs[k][nt * 4 + 64];
            float a[8] = {a0.x, a0.y, a0.z, a0.w, a1.x, a1.y, a1.z, a1.w};
            float b[8] = {b0.x, b0.y, b0.z, b0.w, b1.x, b1.y, b1.z, b1.w};
            #pragma unroll
            for (int i = 0; i < 8; ++i)
                #pragma unroll
                for (int j = 0; j < 8; ++j)
                    acc[i][j] = fmaf(a[i], b[j], acc[i][j]);
        }
        __syncthreads();
    }
    #pragma unroll
    for (int i = 0; i < 8; ++i) {
        int rloc = (i < 4) ? (mt * 4 + i) : (64 + mt * 4 + (i - 4));
        size_t row = (size_t)(rowBase + rloc);
        #pragma unroll
        for (int half = 0; half < 2; ++half) {
            int c = colBase + nt * 4 + half * 64;
            float4 v;
            v.x = acc[i][half * 4 + 0]; v.y = acc[i][half * 4 + 1];
            v.z = acc[i][half * 4 + 2]; v.w = acc[i][half * 4 + 3];
            if (bias) {
                const float4 bv = *(const float4*)&bias[c];
                v.x += bv.x; v.y += bv.y; v.z += bv.z; v.w += bv.w;
            }
            *(float4*)&C[row * J + c] = v;
        }
    }
}

// ---------------- per-node gather-sum (segment_sum via CSR) ----------------
__global__ __launch_bounds__(256) void k_agg(const float* __restrict__ m, const int* __restrict__ rowp,
                                             const int* __restrict__ col, float* __restrict__ agg) {
    int v = blockIdx.x;
    int f = threadIdx.x;
    int beg = rowp[v], end = rowp[v + 1];
    float s = 0.f;
    for (int i = beg; i < end; ++i)
        s += m[(size_t)col[i] * HID + f];
    agg[(size_t)v * HID + f] = s;
}

// ---------------- GRU elementwise update (in-place on h) ----------------
__global__ __launch_bounds__(256) void k_gru(float* __restrict__ h, const float* __restrict__ gi,
                                             const float* __restrict__ gh) {
    size_t idx = (size_t)blockIdx.x * 256 + threadIdx.x;   // < N*HID
    int n = (int)(idx >> 8);
    int c = (int)(idx & 255);
    size_t b = (size_t)n * 768;
    float ir = gi[b + c], iz = gi[b + 256 + c], inn = gi[b + 512 + c];
    float hr = gh[b + c], hz = gh[b + 256 + c], hnn = gh[b + 512 + c];
    float hv = h[idx];
    float r = 1.f / (1.f + expf(-(ir + hr)));
    float z = 1.f / (1.f + expf(-(iz + hz)));
    float ng = tanhf(inn + r * hnn);
    h[idx] = (1.f - z) * ng + z * hv;
}

// ---------------- conv1 (in=NPG channels over length H, k=3 pad 1) + ReLU ----------------
// input(t) = t<HID ? h[node][t] : x[node][t-HID]; node = g*NPG + c
// 256 threads: t4 = tid&15 (4 t each), og = tid>>4; o = og + 16*i, i fully unrolled,
// weight tile zero-padded to o<64 so acc[][] is compile-time indexed (registers).
__global__ __launch_bounds__(256) void k_conv1(const float* __restrict__ h, const float* __restrict__ x,
                                               const float* __restrict__ Wc1, const float* __restrict__ bc1,
                                               float* __restrict__ out, int H) {
    __shared__ float inL[25][68];
    __shared__ float wL[25][64][4];
    int g = blockIdx.x;
    int t0 = blockIdx.y * 64;
    int tid = threadIdx.x;
    int t4 = tid & 15, og = tid >> 4;
    float acc[4][4] = {};
    for (int cc0 = 0; cc0 < NPG; cc0 += 25) {
        // stage input stripe [25 channels][66 positions]
        for (int l = tid; l < 25 * 66; l += 256) {
            int r = l / 66, lc = l - r * 66;
            int t = t0 - 1 + lc;
            int node = g * NPG + cc0 + r;
            float v = 0.f;
            if (t >= 0 && t < H)
                v = (t < HID) ? h[(size_t)node * HID + t] : x[(size_t)node * FEAT + (t - HID)];
            inL[r][lc] = v;
        }
        // stage weights, zero-filled for o in [50,64)
        for (int l = tid; l < 25 * 64; l += 256) {
            int cc = l >> 6, o = l & 63;
            float4 wv = {0.f, 0.f, 0.f, 0.f};
            if (o < 50) {
                const float* wp = &Wc1[o * (NPG * 3) + (cc0 + cc) * 3];
                wv.x = wp[0]; wv.y = wp[1]; wv.z = wp[2];
            }
            *(float4*)&wL[cc][o][0] = wv;
        }
        __syncthreads();
        #pragma unroll 2
        for (int cc = 0; cc < 25; ++cc) {
            float4 va = *(const float4*)&inL[cc][t4 * 4];
            float2 vb = *(const float2*)&inL[cc][t4 * 4 + 4];
            float i0 = va.x, i1 = va.y, i2 = va.z, i3 = va.w, i4 = vb.x, i5 = vb.y;
            #pragma unroll
            for (int i = 0; i < 4; ++i) {
                float4 w = *(const float4*)&wL[cc][og + 16 * i][0];
                acc[i][0] = fmaf(w.x, i0, acc[i][0]);
                acc[i][0] = fmaf(w.y, i1, acc[i][0]);
                acc[i][0] = fmaf(w.z, i2, acc[i][0]);
                acc[i][1] = fmaf(w.x, i1, acc[i][1]);
                acc[i][1] = fmaf(w.y, i2, acc[i][1]);
                acc[i][1] = fmaf(w.z, i3, acc[i][1]);
                acc[i][2] = fmaf(w.x, i2, acc[i][2]);
                acc[i][2] = fmaf(w.y, i3, acc[i][2]);
                acc[i][2] = fmaf(w.z, i4, acc[i][2]);
                acc[i][3] = fmaf(w.x, i3, acc[i][3]);
                acc[i][3] = fmaf(w.y, i4, acc[i][3]);
                acc[i][3] = fmaf(w.z, i5, acc[i][3]);
            }
        }
        __syncthreads();
    }
    #pragma unroll
    for (int i = 0; i < 4; ++i) {
        int o = og + 16 * i;
        if (o < 50) {
            float b = bc1[o];
            float4 v;
            float r0 = acc[i][0] + b, r1 = acc[i][1] + b, r2 = acc[i][2] + b, r3 = acc[i][3] + b;
            v.x = r0 > 0.f ? r0 : 0.f; v.y = r1 > 0.f ? r1 : 0.f;
            v.z = r2 > 0.f ? r2 : 0.f; v.w = r3 > 0.f ? r3 : 0.f;
            size_t base = (size_t)g * 50 * H + (size_t)o * H + t0 + t4 * 4;
            *(float4*)&out[base] = v;
        }
    }
}

// ---------------- maxpool1d k=3 s=2 ----------------
__global__ __launch_bounds__(256) void k_pool1(const float* __restrict__ in, float* __restrict__ out,
                                               int H, int U) {
    int g = blockIdx.x, o = blockIdx.y;
    const float* p = in + ((size_t)g * 50 + o) * H;
    float* q = out + ((size_t)g * 50 + o) * U;
    for (int u = threadIdx.x; u < U; u += 256) {
        float a = p[2 * u], b = p[2 * u + 1], c = p[2 * u + 2];
        float mm = a > b ? a : b;
        q[u] = mm > c ? mm : c;
    }
}

// ---------------- conv2 (k=1) + maxpool k=2 s=2 ----------------
__global__ __launch_bounds__(256) void k_c2p2(const float* __restrict__ P1, const float* __restrict__ Wc2,
                                              const float* __restrict__ bc2, float* __restrict__ out,
                                              int U, int U2) {
    int g = blockIdx.x, o2 = blockIdx.y;
    float b = bc2[o2];
    for (int u2 = threadIdx.x; u2 < U2; u2 += 256) {
        float a0 = b, a1 = b;
        #pragma unroll 5
        for (int i = 0; i < 50; ++i) {
            float wv = Wc2[o2 * 50 + i];
            const float* p = P1 + ((size_t)g * 50 + i) * U + 2 * u2;
            a0 = fmaf(p[0], wv, a0);
            a1 = fmaf(p[1], wv, a1);
        }
        out[((size_t)g * 20 + o2) * U2 + u2] = a0 > a1 ? a0 : a1;
    }
}

// ---------------- fully-connected (per-graph dot) ----------------
__global__ __launch_bounds__(256) void k_fc(const float* __restrict__ P2, const float* __restrict__ Wf,
                                            const float* __restrict__ bf, float* __restrict__ out, int len) {
    __shared__ float red[256];
    int g = blockIdx.x, tid = threadIdx.x;
    const float* p = P2 + (size_t)g * len;
    float s = 0.f;
    for (int i = tid; i < len; i += 256) s = fmaf(p[i], Wf[i], s);
    red[tid] = s;
    __syncthreads();
    for (int off = 128; off > 0; off >>= 1) {
        if (tid < off) red[tid] += red[tid + off];
        __syncthreads();
    }
    if (tid == 0) out[g] = red[0] + bf[0];
}

// ---------------- final: sigmoid(z*y) -> clip -> logit -> [0, z1] ----------------
__global__ __launch_bounds__(256) void k_final(const float* __restrict__ z, const float* __restrict__ y,
                                               float* __restrict__ out) {
    int g = threadIdx.x;
    float t = z[g] * y[g];
    float p = 1.f / (1.f + expf(-t));
    p = fminf(fmaxf(p, 1e-6f), 1.f - 1e-6f);
    float z1 = logf(p / (1.f - p));
    out[2 * g] = 0.f;
    out[2 * g + 1] = z1;
}

extern "C" void kernel_launch(void* const* d_in, const int* in_sizes, int n_in,
                              void* d_out, int out_size, void* d_ws, size_t ws_size,
                              hipStream_t stream) {
    const float* x     = (const float*)d_in[0];
    const int*   ei    = (const int*)d_in[1];
    const float* W_in  = (const float*)d_in[2];
    const float* b_in  = (const float*)d_in[3];
    const float* W_g   = (const float*)d_in[4];
    const float* W_ih  = (const float*)d_in[5];
    const float* W_hh  = (const float*)d_in[6];
    const float* b_ih  = (const float*)d_in[7];
    const float* b_hh  = (const float*)d_in[8];
    const float* Wc1   = (const float*)d_in[9];
    const float* bc1   = (const float*)d_in[10];
    const float* Wc2   = (const float*)d_in[11];
    const float* bc2   = (const float*)d_in[12];
    const float* Wf1   = (const float*)d_in[13];
    const float* bf1   = (const float*)d_in[14];
    const float* Wf2   = (const float*)d_in[15];
    const float* bf2   = (const float*)d_in[16];

    float* ws = (float*)d_ws;
    const size_t F_H   = 0;
    const size_t F_B   = (size_t)N_NODES * HID;                 // region B
    const size_t F_C   = F_B + (size_t)N_NODES * 768;           // region C
    const size_t F_AGG = F_C + (size_t)N_NODES * 768;
    const size_t F_INT = F_AGG + (size_t)N_NODES * HID;

    float* h   = ws + F_H;
    float* m   = ws + F_B;
    float* gi  = ws + F_B;
    float* gh  = ws + F_C;
    float* agg = ws + F_AGG;

    int* deg  = (int*)(ws + F_INT);
    int* fill = deg + N_NODES;
    int* rowp = fill + N_NODES;
    int* col  = rowp + (N_NODES + 1);
    float* zb = (float*)(col + N_EDGES);
    float* yb = zb + 256;

    // conv-phase aliases (GGNN scratch is dead by then)
    float* C1Z = ws + F_B;
    float* P1Z = ws + F_B + 16777216;
    float* P2Z = ws + F_C;
    float* C1Y = ws + F_B;
    float* P1Y = ws + F_B + 8388608;
    float* P2Y = ws + F_C + 4194304;

    // ---- CSR build ----
    hipMemsetAsync(deg, 0, N_NODES * sizeof(int), stream);
    hipMemsetAsync(fill, 0, N_NODES * sizeof(int), stream);
    k_deg<<<N_EDGES / 256, 256, 0, stream>>>(ei, deg);
    k_scan<<<1, 1024, 0, stream>>>(deg, rowp);
    k_fill<<<N_EDGES / 256, 256, 0, stream>>>(ei, rowp, fill, col);

    // ---- h0 = x @ W_in^T + b_in ----
    k_gemm<1><<<dim3(N_NODES / 128, 2), 256, 0, stream>>>(x, W_in, b_in, h, FEAT, HID);

    // ---- GGNN layers ----
    for (int l = 0; l < 6; ++l) {
        k_gemm<0><<<dim3(N_NODES / 128, 2), 256, 0, stream>>>(h, W_g + (size_t)l * HID * HID, nullptr, m, HID, HID);
        k_agg<<<N_NODES, 256, 0, stream>>>(m, rowp, col, agg);
        k_gemm<1><<<dim3(N_NODES / 128, 6), 256, 0, stream>>>(agg, W_ih, b_ih, gi, HID, 768);
        k_gemm<1><<<dim3(N_NODES / 128, 6), 256, 0, stream>>>(h, W_hh, b_hh, gh, HID, 768);
        k_gru<<<N_NODES, 256, 0, stream>>>(h, gi, gh);
    }

    // ---- conv head: Z path (concat [h|x], H=1024) ----
    k_conv1<<<dim3(G_GRAPHS, 16), 256, 0, stream>>>(h, x, Wc1, bc1, C1Z, 1024);
    k_pool1<<<dim3(G_GRAPHS, 50), 256, 0, stream>>>(C1Z, P1Z, 1024, 511);
    k_c2p2<<<dim3(G_GRAPHS, 20), 256, 0, stream>>>(P1Z, Wc2, bc2, P2Z, 511, 255);
    k_fc<<<G_GRAPHS, 256, 0, stream>>>(P2Z, Wf1, bf1, zb, 20 * 255);

    // ---- conv head: Y path (h only, H=256) ----
    k_conv1<<<dim3(G_GRAPHS, 4), 256, 0, stream>>>(h, x, Wc1, bc1, C1Y, 256);
    k_pool1<<<dim3(G_GRAPHS, 50), 256, 0, stream>>>(C1Y, P1Y, 256, 127);
    k_c2p2<<<dim3(G_GRAPHS, 20), 256, 0, stream>>>(P1Y, Wc2, bc2, P2Y, 127, 63);
    k_fc<<<G_GRAPHS, 256, 0, stream>>>(P2Y, Wf2, bf2, yb, 20 * 63);

    // ---- final ----
    k_final<<<1, 256, 0, stream>>>(zb, yb, (float*)d_out);
}

// Round 3
// 2721.757 us; speedup vs baseline: 3.5259x; 1.9661x over previous
//
#include <hip/hip_runtime.h>
#include <math.h>

#define N_NODES 51200
#define N_EDGES 409600
#define FEAT    768
#define HID     256
#define NPG     200
#define G_GRAPHS 256

typedef _Float16 f16x8 __attribute__((ext_vector_type(8)));
typedef _Float16 f16x4 __attribute__((ext_vector_type(4)));
typedef float    f32x4 __attribute__((ext_vector_type(4)));

// ---------------- CSR build ----------------
__global__ __launch_bounds__(256) void k_deg(const int* __restrict__ ei, int* __restrict__ deg) {
    int e = blockIdx.x * 256 + threadIdx.x;
    if (e < N_EDGES) atomicAdd(&deg[ei[N_EDGES + e]], 1);
}

__global__ __launch_bounds__(1024) void k_scan(const int* __restrict__ deg, int* __restrict__ rowp) {
    __shared__ int sums[1024];
    int tid = threadIdx.x;
    int base = tid * 50;
    int s = 0;
    for (int j = 0; j < 50; ++j) s += deg[base + j];
    sums[tid] = s;
    __syncthreads();
    for (int off = 1; off < 1024; off <<= 1) {
        int v = 0;
        if (tid >= off) v = sums[tid - off];
        __syncthreads();
        sums[tid] += v;
        __syncthreads();
    }
    int run = sums[tid] - s; // exclusive prefix
    for (int j = 0; j < 50; ++j) { rowp[base + j] = run; run += deg[base + j]; }
    if (tid == 1023) rowp[N_NODES] = run;
}

__global__ __launch_bounds__(256) void k_fill(const int* __restrict__ ei, const int* __restrict__ rowp,
                                              int* __restrict__ fill, int* __restrict__ col) {
    int e = blockIdx.x * 256 + threadIdx.x;
    if (e < N_EDGES) {
        int d = ei[N_EDGES + e];
        int pos = atomicAdd(&fill[d], 1);
        col[rowp[d] + pos] = ei[e];
    }
}

// ---------------- weight converts ----------------
__global__ __launch_bounds__(256) void k_cvt(const float* __restrict__ in, _Float16* __restrict__ out, int n4) {
    int i = blockIdx.x * 256 + threadIdx.x;
    if (i < n4) {
        float4 v = *(const float4*)&in[i * 4];
        f16x4 h;
        h[0] = (_Float16)v.x; h[1] = (_Float16)v.y; h[2] = (_Float16)v.z; h[3] = (_Float16)v.w;
        *(f16x4*)&out[i * 4] = h;
    }
}

// W_g [6][256][256] (k-major) -> fp16 [6][256][256] (j-major, i.e. transposed)
__global__ __launch_bounds__(256) void k_cvtT(const float* __restrict__ in, _Float16* __restrict__ out) {
    int id = blockIdx.x * 256 + threadIdx.x;
    int l = id >> 16, r = id & 65535;
    int j = r >> 8, k = r & 255;
    out[(l << 16) + (j << 8) + k] = (_Float16)in[(l << 16) + (k << 8) + j];
}

// ---------------- fp16 MFMA GEMM (NT): C[M,J] = A_f32[M,K] @ B_f16[J,K]^T + bias ----------------
// 128x128 tile, BK=64, 4 waves (2x2 of 64x64), 16x16x32_f16 MFMA, fp32 accumulate.
// LDS tiles [128][64] f16 with 16B-slot XOR swizzle (slot ^= row&7) => conflict-free b128.
__global__ __launch_bounds__(256) void k_gemm_h(const float* __restrict__ A, const _Float16* __restrict__ B,
                                                const float* __restrict__ bias, float* __restrict__ C,
                                                int K, int J) {
    __shared__ _Float16 As[128 * 64];
    __shared__ _Float16 Bs[128 * 64];
    int tid = threadIdx.x;
    int lane = tid & 63;
    int wid = tid >> 6;
    int wr = wid >> 1, wc = wid & 1;
    int rowBase = blockIdx.x * 128, colBase = blockIdx.y * 128;
    f32x4 acc[4][4] = {};
    for (int k0 = 0; k0 < K; k0 += 64) {
        __syncthreads();
        #pragma unroll
        for (int p = 0; p < 4; ++p) {
            int c = p * 256 + tid;          // 16B chunk id, 1024 per tile
            int row = c >> 3, slot = c & 7; // 8 chunks per 128B row
            int dst = row * 64 + ((slot ^ (row & 7)) * 8);
            const float* srcA = A + (size_t)(rowBase + row) * K + k0 + slot * 8;
            float4 f0 = *(const float4*)srcA;
            float4 f1 = *(const float4*)(srcA + 4);
            f16x8 hv;
            hv[0] = (_Float16)f0.x; hv[1] = (_Float16)f0.y; hv[2] = (_Float16)f0.z; hv[3] = (_Float16)f0.w;
            hv[4] = (_Float16)f1.x; hv[5] = (_Float16)f1.y; hv[6] = (_Float16)f1.z; hv[7] = (_Float16)f1.w;
            *(f16x8*)&As[dst] = hv;
            const _Float16* srcB = B + (size_t)(colBase + row) * K + k0 + slot * 8;
            *(f16x8*)&Bs[dst] = *(const f16x8*)srcB;
        }
        __syncthreads();
        #pragma unroll
        for (int ks = 0; ks < 2; ++ks) {
            f16x8 af[4], bf[4];
            #pragma unroll
            for (int mi = 0; mi < 4; ++mi) {
                int row = wr * 64 + mi * 16 + (lane & 15);
                int slot = (lane >> 4) + ks * 4;
                af[mi] = *(const f16x8*)&As[row * 64 + ((slot ^ (row & 7)) * 8)];
            }
            #pragma unroll
            for (int nj = 0; nj < 4; ++nj) {
                int row = wc * 64 + nj * 16 + (lane & 15);
                int slot = (lane >> 4) + ks * 4;
                bf[nj] = *(const f16x8*)&Bs[row * 64 + ((slot ^ (row & 7)) * 8)];
            }
            #pragma unroll
            for (int mi = 0; mi < 4; ++mi)
                #pragma unroll
                for (int nj = 0; nj < 4; ++nj)
                    acc[mi][nj] = __builtin_amdgcn_mfma_f32_16x16x32_f16(af[mi], bf[nj], acc[mi][nj], 0, 0, 0);
        }
    }
    #pragma unroll
    for (int mi = 0; mi < 4; ++mi) {
        #pragma unroll
        for (int nj = 0; nj < 4; ++nj) {
            int col = colBase + wc * 64 + nj * 16 + (lane & 15);
            float bv = bias ? bias[col] : 0.f;
            #pragma unroll
            for (int r = 0; r < 4; ++r) {
                int row = rowBase + wr * 64 + mi * 16 + (lane >> 4) * 4 + r;
                C[(size_t)row * J + col] = acc[mi][nj][r] + bv;
            }
        }
    }
}

// ---------------- per-node gather-sum (segment_sum via CSR) ----------------
__global__ __launch_bounds__(256) void k_agg(const float* __restrict__ m, const int* __restrict__ rowp,
                                             const int* __restrict__ col, float* __restrict__ agg) {
    int v = blockIdx.x;
    int f = threadIdx.x;
    int beg = rowp[v], end = rowp[v + 1];
    float s = 0.f;
    for (int i = beg; i < end; ++i)
        s += m[(size_t)col[i] * HID + f];
    agg[(size_t)v * HID + f] = s;
}

// ---------------- GRU elementwise update (in-place on h) ----------------
__global__ __launch_bounds__(256) void k_gru(float* __restrict__ h, const float* __restrict__ gi,
                                             const float* __restrict__ gh) {
    size_t idx = (size_t)blockIdx.x * 256 + threadIdx.x;   // < N*HID
    int n = (int)(idx >> 8);
    int c = (int)(idx & 255);
    size_t b = (size_t)n * 768;
    float ir = gi[b + c], iz = gi[b + 256 + c], inn = gi[b + 512 + c];
    float hr = gh[b + c], hz = gh[b + 256 + c], hnn = gh[b + 512 + c];
    float hv = h[idx];
    float r = 1.f / (1.f + expf(-(ir + hr)));
    float z = 1.f / (1.f + expf(-(iz + hz)));
    float ng = tanhf(inn + r * hnn);
    h[idx] = (1.f - z) * ng + z * hv;
}

// ---------------- conv1 (in=NPG channels over length H, k=3 pad 1) + ReLU ----------------
// SoA weight LDS (stride-1 stores = conflict-free; reads broadcast).
__global__ __launch_bounds__(256) void k_conv1(const float* __restrict__ h, const float* __restrict__ x,
                                               const float* __restrict__ Wc1, const float* __restrict__ bc1,
                                               float* __restrict__ out, int H) {
    __shared__ float inL[25][68];
    __shared__ float wx[25][64], wy[25][64], wz[25][64];
    int g = blockIdx.x;
    int t0 = blockIdx.y * 64;
    int tid = threadIdx.x;
    int t4 = tid & 15, og = tid >> 4;
    float acc[4][4] = {};
    for (int cc0 = 0; cc0 < NPG; cc0 += 25) {
        for (int l = tid; l < 25 * 66; l += 256) {
            int r = l / 66, lc = l - r * 66;
            int t = t0 - 1 + lc;
            int node = g * NPG + cc0 + r;
            float v = 0.f;
            if (t >= 0 && t < H)
                v = (t < HID) ? h[(size_t)node * HID + t] : x[(size_t)node * FEAT + (t - HID)];
            inL[r][lc] = v;
        }
        for (int l = tid; l < 25 * 64; l += 256) {
            int cc = l >> 6, o = l & 63;
            float a = 0.f, b = 0.f, c = 0.f;
            if (o < 50) {
                const float* wp = &Wc1[o * (NPG * 3) + (cc0 + cc) * 3];
                a = wp[0]; b = wp[1]; c = wp[2];
            }
            wx[cc][o] = a; wy[cc][o] = b; wz[cc][o] = c;
        }
        __syncthreads();
        #pragma unroll 2
        for (int cc = 0; cc < 25; ++cc) {
            float4 va = *(const float4*)&inL[cc][t4 * 4];
            float2 vb = *(const float2*)&inL[cc][t4 * 4 + 4];
            float i0 = va.x, i1 = va.y, i2 = va.z, i3 = va.w, i4 = vb.x, i5 = vb.y;
            #pragma unroll
            for (int i = 0; i < 4; ++i) {
                float w0 = wx[cc][og + 16 * i], w1 = wy[cc][og + 16 * i], w2 = wz[cc][og + 16 * i];
                acc[i][0] = fmaf(w0, i0, acc[i][0]);
                acc[i][0] = fmaf(w1, i1, acc[i][0]);
                acc[i][0] = fmaf(w2, i2, acc[i][0]);
                acc[i][1] = fmaf(w0, i1, acc[i][1]);
                acc[i][1] = fmaf(w1, i2, acc[i][1]);
                acc[i][1] = fmaf(w2, i3, acc[i][1]);
                acc[i][2] = fmaf(w0, i2, acc[i][2]);
                acc[i][2] = fmaf(w1, i3, acc[i][2]);
                acc[i][2] = fmaf(w2, i4, acc[i][2]);
                acc[i][3] = fmaf(w0, i3, acc[i][3]);
                acc[i][3] = fmaf(w1, i4, acc[i][3]);
                acc[i][3] = fmaf(w2, i5, acc[i][3]);
            }
        }
        __syncthreads();
    }
    #pragma unroll
    for (int i = 0; i < 4; ++i) {
        int o = og + 16 * i;
        if (o < 50) {
            float b = bc1[o];
            float4 v;
            float r0 = acc[i][0] + b, r1 = acc[i][1] + b, r2 = acc[i][2] + b, r3 = acc[i][3] + b;
            v.x = r0 > 0.f ? r0 : 0.f; v.y = r1 > 0.f ? r1 : 0.f;
            v.z = r2 > 0.f ? r2 : 0.f; v.w = r3 > 0.f ? r3 : 0.f;
            size_t base = (size_t)g * 50 * H + (size_t)o * H + t0 + t4 * 4;
            *(float4*)&out[base] = v;
        }
    }
}

// ---------------- maxpool1d k=3 s=2 ----------------
__global__ __launch_bounds__(256) void k_pool1(const float* __restrict__ in, float* __restrict__ out,
                                               int H, int U) {
    int g = blockIdx.x, o = blockIdx.y;
    const float* p = in + ((size_t)g * 50 + o) * H;
    float* q = out + ((size_t)g * 50 + o) * U;
    for (int u = threadIdx.x; u < U; u += 256) {
        float a = p[2 * u], b = p[2 * u + 1], c = p[2 * u + 2];
        float mm = a > b ? a : b;
        q[u] = mm > c ? mm : c;
    }
}

// ---------------- conv2 (k=1) + maxpool k=2 s=2 ----------------
__global__ __launch_bounds__(256) void k_c2p2(const float* __restrict__ P1, const float* __restrict__ Wc2,
                                              const float* __restrict__ bc2, float* __restrict__ out,
                                              int U, int U2) {
    int g = blockIdx.x, o2 = blockIdx.y;
    float b = bc2[o2];
    for (int u2 = threadIdx.x; u2 < U2; u2 += 256) {
        float a0 = b, a1 = b;
        #pragma unroll 5
        for (int i = 0; i < 50; ++i) {
            float wv = Wc2[o2 * 50 + i];
            const float* p = P1 + ((size_t)g * 50 + i) * U + 2 * u2;
            a0 = fmaf(p[0], wv, a0);
            a1 = fmaf(p[1], wv, a1);
        }
        out[((size_t)g * 20 + o2) * U2 + u2] = a0 > a1 ? a0 : a1;
    }
}

// ---------------- fully-connected (per-graph dot) ----------------
__global__ __launch_bounds__(256) void k_fc(const float* __restrict__ P2, const float* __restrict__ Wf,
                                            const float* __restrict__ bf, float* __restrict__ out, int len) {
    __shared__ float red[256];
    int g = blockIdx.x, tid = threadIdx.x;
    const float* p = P2 + (size_t)g * len;
    float s = 0.f;
    for (int i = tid; i < len; i += 256) s = fmaf(p[i], Wf[i], s);
    red[tid] = s;
    __syncthreads();
    for (int off = 128; off > 0; off >>= 1) {
        if (tid < off) red[tid] += red[tid + off];
        __syncthreads();
    }
    if (tid == 0) out[g] = red[0] + bf[0];
}

// ---------------- final: sigmoid(z*y) -> clip -> logit -> [0, z1] ----------------
__global__ __launch_bounds__(256) void k_final(const float* __restrict__ z, const float* __restrict__ y,
                                               float* __restrict__ out) {
    int g = threadIdx.x;
    float t = z[g] * y[g];
    float p = 1.f / (1.f + expf(-t));
    p = fminf(fmaxf(p, 1e-6f), 1.f - 1e-6f);
    float z1 = logf(p / (1.f - p));
    out[2 * g] = 0.f;
    out[2 * g + 1] = z1;
}

extern "C" void kernel_launch(void* const* d_in, const int* in_sizes, int n_in,
                              void* d_out, int out_size, void* d_ws, size_t ws_size,
                              hipStream_t stream) {
    const float* x     = (const float*)d_in[0];
    const int*   ei    = (const int*)d_in[1];
    const float* W_in  = (const float*)d_in[2];
    const float* b_in  = (const float*)d_in[3];
    const float* W_g   = (const float*)d_in[4];
    const float* W_ih  = (const float*)d_in[5];
    const float* W_hh  = (const float*)d_in[6];
    const float* b_ih  = (const float*)d_in[7];
    const float* b_hh  = (const float*)d_in[8];
    const float* Wc1   = (const float*)d_in[9];
    const float* bc1   = (const float*)d_in[10];
    const float* Wc2   = (const float*)d_in[11];
    const float* bc2   = (const float*)d_in[12];
    const float* Wf1   = (const float*)d_in[13];
    const float* bf1   = (const float*)d_in[14];
    const float* Wf2   = (const float*)d_in[15];
    const float* bf2   = (const float*)d_in[16];

    float* ws = (float*)d_ws;
    const size_t F_B   = (size_t)N_NODES * HID;        // region B (m / gi)
    const size_t F_C   = F_B + (size_t)N_NODES * 768;  // region C (gh)
    const size_t F_AGG = F_C + (size_t)N_NODES * 768;  // agg
    const size_t F_INT = F_AGG + (size_t)N_NODES * HID; // = N*2048, 16B-aligned

    float* h   = ws;
    float* m   = ws + F_B;
    float* gi  = ws + F_B;
    float* gh  = ws + F_C;
    float* agg = ws + F_AGG;

    _Float16* Win_h = (_Float16*)(ws + F_INT);   // 256*768
    _Float16* Wih_h = Win_h + 196608;            // 768*256
    _Float16* Whh_h = Wih_h + 196608;            // 768*256
    _Float16* WgT_h = Whh_h + 196608;            // 6*256*256
    int* deg  = (int*)(WgT_h + 393216);
    int* fill = deg + N_NODES;
    int* rowp = fill + N_NODES;
    int* col  = rowp + (N_NODES + 1);
    float* zb = (float*)(col + N_EDGES);
    float* yb = zb + 256;

    // conv-phase aliases (GGNN scratch is dead by then)
    float* C1Z = ws + F_B;
    float* P1Z = ws + F_B + 16777216;
    float* P2Z = ws + F_C;
    float* C1Y = ws + F_B;
    float* P1Y = ws + F_B + 8388608;
    float* P2Y = ws + F_C + 4194304;

    // ---- weight fp16 conversion ----
    k_cvt<<<192, 256, 0, stream>>>(W_in, Win_h, 49152);
    k_cvt<<<192, 256, 0, stream>>>(W_ih, Wih_h, 49152);
    k_cvt<<<192, 256, 0, stream>>>(W_hh, Whh_h, 49152);
    k_cvtT<<<1536, 256, 0, stream>>>(W_g, WgT_h);

    // ---- CSR build ----
    hipMemsetAsync(deg, 0, N_NODES * sizeof(int), stream);
    hipMemsetAsync(fill, 0, N_NODES * sizeof(int), stream);
    k_deg<<<N_EDGES / 256, 256, 0, stream>>>(ei, deg);
    k_scan<<<1, 1024, 0, stream>>>(deg, rowp);
    k_fill<<<N_EDGES / 256, 256, 0, stream>>>(ei, rowp, fill, col);

    // ---- h0 = x @ W_in^T + b_in ----
    k_gemm_h<<<dim3(N_NODES / 128, 2), 256, 0, stream>>>(x, Win_h, b_in, h, FEAT, HID);

    // ---- GGNN layers ----
    for (int l = 0; l < 6; ++l) {
        k_gemm_h<<<dim3(N_NODES / 128, 2), 256, 0, stream>>>(h, WgT_h + (size_t)l * 65536, nullptr, m, HID, HID);
        k_agg<<<N_NODES, 256, 0, stream>>>(m, rowp, col, agg);
        k_gemm_h<<<dim3(N_NODES / 128, 6), 256, 0, stream>>>(agg, Wih_h, b_ih, gi, HID, 768);
        k_gemm_h<<<dim3(N_NODES / 128, 6), 256, 0, stream>>>(h, Whh_h, b_hh, gh, HID, 768);
        k_gru<<<N_NODES, 256, 0, stream>>>(h, gi, gh);
    }

    // ---- conv head: Z path (concat [h|x], H=1024) ----
    k_conv1<<<dim3(G_GRAPHS, 16), 256, 0, stream>>>(h, x, Wc1, bc1, C1Z, 1024);
    k_pool1<<<dim3(G_GRAPHS, 50), 256, 0, stream>>>(C1Z, P1Z, 1024, 511);
    k_c2p2<<<dim3(G_GRAPHS, 20), 256, 0, stream>>>(P1Z, Wc2, bc2, P2Z, 511, 255);
    k_fc<<<G_GRAPHS, 256, 0, stream>>>(P2Z, Wf1, bf1, zb, 20 * 255);

    // ---- conv head: Y path (h only, H=256) ----
    k_conv1<<<dim3(G_GRAPHS, 4), 256, 0, stream>>>(h, x, Wc1, bc1, C1Y, 256);
    k_pool1<<<dim3(G_GRAPHS, 50), 256, 0, stream>>>(C1Y, P1Y, 256, 127);
    k_c2p2<<<dim3(G_GRAPHS, 20), 256, 0, stream>>>(P1Y, Wc2, bc2, P2Y, 127, 63);
    k_fc<<<G_GRAPHS, 256, 0, stream>>>(P2Y, Wf2, bf2, yb, 20 * 63);

    // ---- final ----
    k_final<<<1, 256, 0, stream>>>(zb, yb, (float*)d_out);
}

// Round 5
// 2272.206 us; speedup vs baseline: 4.2235x; 1.1978x over previous
//
#include <hip/hip_runtime.h>
#include <math.h>

#define N_NODES 51200
#define N_EDGES 409600
#define FEAT    768
#define HID     256
#define NPG     200
#define G_GRAPHS 256

typedef _Float16 f16x8 __attribute__((ext_vector_type(8)));
typedef _Float16 f16x4 __attribute__((ext_vector_type(4)));
typedef float    f32x4 __attribute__((ext_vector_type(4)));

// ---------------- CSR build ----------------
__global__ __launch_bounds__(256) void k_deg(const int* __restrict__ ei, int* __restrict__ deg) {
    int e = blockIdx.x * 256 + threadIdx.x;
    if (e < N_EDGES) atomicAdd(&deg[ei[N_EDGES + e]], 1);
}

__global__ __launch_bounds__(1024) void k_scan(const int* __restrict__ deg, int* __restrict__ rowp) {
    __shared__ int sums[1024];
    int tid = threadIdx.x;
    int base = tid * 50;
    int s = 0;
    for (int j = 0; j < 50; ++j) s += deg[base + j];
    sums[tid] = s;
    __syncthreads();
    for (int off = 1; off < 1024; off <<= 1) {
        int v = 0;
        if (tid >= off) v = sums[tid - off];
        __syncthreads();
        sums[tid] += v;
        __syncthreads();
    }
    int run = sums[tid] - s; // exclusive prefix
    for (int j = 0; j < 50; ++j) { rowp[base + j] = run; run += deg[base + j]; }
    if (tid == 1023) rowp[N_NODES] = run;
}

__global__ __launch_bounds__(256) void k_fill(const int* __restrict__ ei, const int* __restrict__ rowp,
                                              int* __restrict__ fill, int* __restrict__ col) {
    int e = blockIdx.x * 256 + threadIdx.x;
    if (e < N_EDGES) {
        int d = ei[N_EDGES + e];
        int pos = atomicAdd(&fill[d], 1);
        col[rowp[d] + pos] = ei[e];
    }
}

// ---------------- weight prep ----------------
__global__ __launch_bounds__(256) void k_cvt(const float* __restrict__ in, _Float16* __restrict__ out, int n4) {
    int i = blockIdx.x * 256 + threadIdx.x;
    if (i < n4) {
        float4 v = *(const float4*)&in[i * 4];
        f16x4 h;
        h[0] = (_Float16)v.x; h[1] = (_Float16)v.y; h[2] = (_Float16)v.z; h[3] = (_Float16)v.w;
        *(f16x4*)&out[i * 4] = h;
    }
}

// W_g [6][256][256] (k-major) -> fp16 [6][256][256] (j-major, i.e. transposed)
__global__ __launch_bounds__(256) void k_cvtT(const float* __restrict__ in, _Float16* __restrict__ out) {
    int id = blockIdx.x * 256 + threadIdx.x;
    int l = id >> 16, r = id & 65535;
    int j = r >> 8, k = r & 255;
    out[(l << 16) + (j << 8) + k] = (_Float16)in[(l << 16) + (k << 8) + j];
}

// Wrz[j][k], j<512, k<512: k<256 -> W_ih[j][k], else W_hh[j][k-256]
__global__ __launch_bounds__(256) void k_wrz(const float* __restrict__ Wih, const float* __restrict__ Whh,
                                             _Float16* __restrict__ out) {
    int id = blockIdx.x * 256 + threadIdx.x;   // < 512*512
    int j = id >> 9, k = id & 511;
    float v = (k < 256) ? Wih[j * 256 + k] : Whh[j * 256 + (k - 256)];
    out[id] = (_Float16)v;
}

__global__ __launch_bounds__(256) void k_bias(const float* __restrict__ bih, const float* __restrict__ bhh,
                                              float* __restrict__ brz) {
    int i = blockIdx.x * 256 + threadIdx.x;   // < 512
    if (i < 512) brz[i] = bih[i] + bhh[i];
}

// ---------------- fp16 MFMA GEMM (NT): C[M,J] = A[M,K] @ B_f16[J,K]^T + bias ----------------
// 128x128 tile, BK=64, 4 waves (2x2 of 64x64), 16x16x32_f16 MFMA, fp32 accumulate.
// LDS tiles [128][64] f16, 16B-slot XOR swizzle (slot ^= row&7) => conflict-free b128.
// AF16: A is fp16 (else fp32, converted in staging). OUT: 0=f32, 1=f16, 2=dual(f32 C + f16 C2).
// Grid = 400*COLB; block id decoded so the COLB col-blocks of one row-block run
// consecutively on ONE XCD (assuming XCD = wg%8) -> A tile L2-resident across col-blocks.
template<int AF16, int OUT, int COLB>
__global__ __launch_bounds__(256) void k_gemm2(const void* __restrict__ Av, int lda,
                                               const _Float16* __restrict__ B,
                                               const float* __restrict__ bias,
                                               void* __restrict__ Cv, int ldc,
                                               _Float16* __restrict__ C2, int ldc2,
                                               int K) {
    __shared__ _Float16 As[128 * 64];
    __shared__ _Float16 Bs[128 * 64];
    int wg = blockIdx.x;
    int xcd = wg & 7, t = wg >> 3;
    int cb = t % COLB, gidx = t / COLB;
    int rowBase = (gidx * 8 + xcd) * 128;
    int colBase = cb * 128;
    int tid = threadIdx.x;
    int lane = tid & 63;
    int wid = tid >> 6;
    int wr = wid >> 1, wc = wid & 1;
    f32x4 acc[4][4] = {};
    for (int k0 = 0; k0 < K; k0 += 64) {
        __syncthreads();
        #pragma unroll
        for (int p = 0; p < 4; ++p) {
            int c = p * 256 + tid;          // 16B chunk id, 1024 per tile
            int row = c >> 3, slot = c & 7; // 8 chunks per row (64 f16)
            int dst = row * 64 + ((slot ^ (row & 7)) * 8);
            if (AF16) {
                const _Float16* srcA = (const _Float16*)Av + (size_t)(rowBase + row) * lda + k0 + slot * 8;
                *(f16x8*)&As[dst] = *(const f16x8*)srcA;
            } else {
                const float* srcA = (const float*)Av + (size_t)(rowBase + row) * lda + k0 + slot * 8;
                float4 f0 = *(const float4*)srcA;
                float4 f1 = *(const float4*)(srcA + 4);
                f16x8 hv;
                hv[0] = (_Float16)f0.x; hv[1] = (_Float16)f0.y; hv[2] = (_Float16)f0.z; hv[3] = (_Float16)f0.w;
                hv[4] = (_Float16)f1.x; hv[5] = (_Float16)f1.y; hv[6] = (_Float16)f1.z; hv[7] = (_Float16)f1.w;
                *(f16x8*)&As[dst] = hv;
            }
            const _Float16* srcB = B + (size_t)(colBase + row) * K + k0 + slot * 8;
            *(f16x8*)&Bs[dst] = *(const f16x8*)srcB;
        }
        __syncthreads();
        #pragma unroll
        for (int ks = 0; ks < 2; ++ks) {
            f16x8 af[4], bf[4];
            #pragma unroll
            for (int mi = 0; mi < 4; ++mi) {
                int row = wr * 64 + mi * 16 + (lane & 15);
                int slot = (lane >> 4) + ks * 4;
                af[mi] = *(const f16x8*)&As[row * 64 + ((slot ^ (row & 7)) * 8)];
            }
            #pragma unroll
            for (int nj = 0; nj < 4; ++nj) {
                int row = wc * 64 + nj * 16 + (lane & 15);
                int slot = (lane >> 4) + ks * 4;
                bf[nj] = *(const f16x8*)&Bs[row * 64 + ((slot ^ (row & 7)) * 8)];
            }
            #pragma unroll
            for (int mi = 0; mi < 4; ++mi)
                #pragma unroll
                for (int nj = 0; nj < 4; ++nj)
                    acc[mi][nj] = __builtin_amdgcn_mfma_f32_16x16x32_f16(af[mi], bf[nj], acc[mi][nj], 0, 0, 0);
        }
    }
    #pragma unroll
    for (int mi = 0; mi < 4; ++mi) {
        #pragma unroll
        for (int nj = 0; nj < 4; ++nj) {
            int col = colBase + wc * 64 + nj * 16 + (lane & 15);
            float bv = bias ? bias[col] : 0.f;
            #pragma unroll
            for (int r = 0; r < 4; ++r) {
                int row = rowBase + wr * 64 + mi * 16 + (lane >> 4) * 4 + r;
                float val = acc[mi][nj][r] + bv;
                if (OUT == 0) {
                    ((float*)Cv)[(size_t)row * ldc + col] = val;
                } else if (OUT == 1) {
                    ((_Float16*)Cv)[(size_t)row * ldc + col] = (_Float16)val;
                } else {
                    ((float*)Cv)[(size_t)row * ldc + col] = val;
                    C2[(size_t)row * ldc2 + col] = (_Float16)val;
                }
            }
        }
    }
}

// ---------------- per-node gather-sum (fp16 m -> fp16 AG agg-half, fp32 acc) ----------------
__global__ __launch_bounds__(256) void k_agg2(const _Float16* __restrict__ m, const int* __restrict__ rowp,
                                              const int* __restrict__ col, _Float16* __restrict__ AG) {
    int v = blockIdx.x;
    int f = threadIdx.x;
    int beg = rowp[v], end = rowp[v + 1];
    float s = 0.f;
    for (int i = beg; i < end; ++i)
        s += (float)m[(size_t)col[i] * HID + f];
    AG[(size_t)v * 512 + f] = (_Float16)s;
}

// ---------------- GRU elementwise update ----------------
// rz[n*512+c]=r-pre, rz[n*512+256+c]=z-pre; nn[n*512+c]=i_n, nn[n*512+256+c]=h_n
__global__ __launch_bounds__(256) void k_gru2(float* __restrict__ h, const float* __restrict__ rz,
                                              const float* __restrict__ nn, _Float16* __restrict__ AG) {
    size_t idx = (size_t)blockIdx.x * 256 + threadIdx.x;   // < N*HID
    int n = (int)(idx >> 8);
    int c = (int)(idx & 255);
    size_t b = (size_t)n * 512;
    float r = 1.f / (1.f + expf(-rz[b + c]));
    float z = 1.f / (1.f + expf(-rz[b + 256 + c]));
    float ng = tanhf(nn[b + c] + r * nn[b + 256 + c]);
    float hv = h[idx];
    float out = (1.f - z) * ng + z * hv;
    h[idx] = out;
    AG[b + 256 + c] = (_Float16)out;
}

// ---------------- conv1 (in=NPG channels over length H, k=3 pad 1) + ReLU ----------------
__global__ __launch_bounds__(256) void k_conv1(const float* __restrict__ h, const float* __restrict__ x,
                                               const float* __restrict__ Wc1, const float* __restrict__ bc1,
                                               float* __restrict__ out, int H) {
    __shared__ float inL[25][68];
    __shared__ float wx[25][64], wy[25][64], wz[25][64];
    int g = blockIdx.x;
    int t0 = blockIdx.y * 64;
    int tid = threadIdx.x;
    int t4 = tid & 15, og = tid >> 4;
    float acc[4][4] = {};
    for (int cc0 = 0; cc0 < NPG; cc0 += 25) {
        for (int l = tid; l < 25 * 66; l += 256) {
            int r = l / 66, lc = l - r * 66;
            int t = t0 - 1 + lc;
            int node = g * NPG + cc0 + r;
            float v = 0.f;
            if (t >= 0 && t < H)
                v = (t < HID) ? h[(size_t)node * HID + t] : x[(size_t)node * FEAT + (t - HID)];
            inL[r][lc] = v;
        }
        for (int l = tid; l < 25 * 64; l += 256) {
            int cc = l >> 6, o = l & 63;
            float a = 0.f, b = 0.f, c = 0.f;
            if (o < 50) {
                const float* wp = &Wc1[o * (NPG * 3) + (cc0 + cc) * 3];
                a = wp[0]; b = wp[1]; c = wp[2];
            }
            wx[cc][o] = a; wy[cc][o] = b; wz[cc][o] = c;
        }
        __syncthreads();
        #pragma unroll 2
        for (int cc = 0; cc < 25; ++cc) {
            float4 va = *(const float4*)&inL[cc][t4 * 4];
            float2 vb = *(const float2*)&inL[cc][t4 * 4 + 4];
            float i0 = va.x, i1 = va.y, i2 = va.z, i3 = va.w, i4 = vb.x, i5 = vb.y;
            #pragma unroll
            for (int i = 0; i < 4; ++i) {
                float w0 = wx[cc][og + 16 * i], w1 = wy[cc][og + 16 * i], w2 = wz[cc][og + 16 * i];
                acc[i][0] = fmaf(w0, i0, acc[i][0]);
                acc[i][0] = fmaf(w1, i1, acc[i][0]);
                acc[i][0] = fmaf(w2, i2, acc[i][0]);
                acc[i][1] = fmaf(w0, i1, acc[i][1]);
                acc[i][1] = fmaf(w1, i2, acc[i][1]);
                acc[i][1] = fmaf(w2, i3, acc[i][1]);
                acc[i][2] = fmaf(w0, i2, acc[i][2]);
                acc[i][2] = fmaf(w1, i3, acc[i][2]);
                acc[i][2] = fmaf(w2, i4, acc[i][2]);
                acc[i][3] = fmaf(w0, i3, acc[i][3]);
                acc[i][3] = fmaf(w1, i4, acc[i][3]);
                acc[i][3] = fmaf(w2, i5, acc[i][3]);
            }
        }
        __syncthreads();
    }
    #pragma unroll
    for (int i = 0; i < 4; ++i) {
        int o = og + 16 * i;
        if (o < 50) {
            float b = bc1[o];
            float4 v;
            float r0 = acc[i][0] + b, r1 = acc[i][1] + b, r2 = acc[i][2] + b, r3 = acc[i][3] + b;
            v.x = r0 > 0.f ? r0 : 0.f; v.y = r1 > 0.f ? r1 : 0.f;
            v.z = r2 > 0.f ? r2 : 0.f; v.w = r3 > 0.f ? r3 : 0.f;
            size_t base = (size_t)g * 50 * H + (size_t)o * H + t0 + t4 * 4;
            *(float4*)&out[base] = v;
        }
    }
}

// ---------------- maxpool1d k=3 s=2 ----------------
__global__ __launch_bounds__(256) void k_pool1(const float* __restrict__ in, float* __restrict__ out,
                                               int H, int U) {
    int g = blockIdx.x, o = blockIdx.y;
    const float* p = in + ((size_t)g * 50 + o) * H;
    float* q = out + ((size_t)g * 50 + o) * U;
    for (int u = threadIdx.x; u < U; u += 256) {
        float a = p[2 * u], b = p[2 * u + 1], c = p[2 * u + 2];
        float mm = a > b ? a : b;
        q[u] = mm > c ? mm : c;
    }
}

// ---------------- conv2 (k=1) + maxpool k=2 s=2 ----------------
__global__ __launch_bounds__(256) void k_c2p2(const float* __restrict__ P1, const float* __restrict__ Wc2,
                                              const float* __restrict__ bc2, float* __restrict__ out,
                                              int U, int U2) {
    int g = blockIdx.x, o2 = blockIdx.y;
    float b = bc2[o2];
    for (int u2 = threadIdx.x; u2 < U2; u2 += 256) {
        float a0 = b, a1 = b;
        #pragma unroll 5
        for (int i = 0; i < 50; ++i) {
            float wv = Wc2[o2 * 50 + i];
            const float* p = P1 + ((size_t)g * 50 + i) * U + 2 * u2;
            a0 = fmaf(p[0], wv, a0);
            a1 = fmaf(p[1], wv, a1);
        }
        out[((size_t)g * 20 + o2) * U2 + u2] = a0 > a1 ? a0 : a1;
    }
}

// ---------------- fully-connected (per-graph dot) ----------------
__global__ __launch_bounds__(256) void k_fc(const float* __restrict__ P2, const float* __restrict__ Wf,
                                            const float* __restrict__ bf, float* __restrict__ out, int len) {
    __shared__ float red[256];
    int g = blockIdx.x, tid = threadIdx.x;
    const float* p = P2 + (size_t)g * len;
    float s = 0.f;
    for (int i = tid; i < len; i += 256) s = fmaf(p[i], Wf[i], s);
    red[tid] = s;
    __syncthreads();
    for (int off = 128; off > 0; off >>= 1) {
        if (tid < off) red[tid] += red[tid + off];
        __syncthreads();
    }
    if (tid == 0) out[g] = red[0] + bf[0];
}

// ---------------- final: sigmoid(z*y) -> clip -> logit -> [0, z1] ----------------
__global__ __launch_bounds__(256) void k_final(const float* __restrict__ z, const float* __restrict__ y,
                                               float* __restrict__ out) {
    int g = threadIdx.x;
    float t = z[g] * y[g];
    float p = 1.f / (1.f + expf(-t));
    p = fminf(fmaxf(p, 1e-6f), 1.f - 1e-6f);
    float z1 = logf(p / (1.f - p));
    out[2 * g] = 0.f;
    out[2 * g + 1] = z1;
}

extern "C" void kernel_launch(void* const* d_in, const int* in_sizes, int n_in,
                              void* d_out, int out_size, void* d_ws, size_t ws_size,
                              hipStream_t stream) {
    const float* x     = (const float*)d_in[0];
    const int*   ei    = (const int*)d_in[1];
    const float* W_in  = (const float*)d_in[2];
    const float* b_in  = (const float*)d_in[3];
    const float* W_g   = (const float*)d_in[4];
    const float* W_ih  = (const float*)d_in[5];
    const float* W_hh  = (const float*)d_in[6];
    const float* b_ih  = (const float*)d_in[7];
    const float* b_hh  = (const float*)d_in[8];
    const float* Wc1   = (const float*)d_in[9];
    const float* bc1   = (const float*)d_in[10];
    const float* Wc2   = (const float*)d_in[11];
    const float* bc2   = (const float*)d_in[12];
    const float* Wf1   = (const float*)d_in[13];
    const float* bf1   = (const float*)d_in[14];
    const float* Wf2   = (const float*)d_in[15];
    const float* bf2   = (const float*)d_in[16];

    float* ws = (float*)d_ws;
    // layout (float units). mf is [N,256] f16 = 6,553,600 floats (NOT 13.1M — round-4 bug).
    const size_t OFF_H   = 0;                    // h fp32 [N,256]            -> 13,107,200
    const size_t OFF_RZ  = 13107200;             // rz fp32 [N,512]           -> 39,321,600
    const size_t OFF_NN  = 39321600;             // nn fp32 [N,512]           -> 65,536,000
    const size_t OFF_AG  = 65536000;             // AG f16 [N,512]            -> 78,643,200
    const size_t OFF_MF  = 78643200;             // mf f16 [N,256]            -> 85,196,800
    const size_t OFF_W   = 85196800;             // f16 weights (491,520 f)   -> 85,688,320
    const size_t OFF_BRZ = 85688320;             // brz [512]                 -> 85,688,832
    const size_t OFF_INT = 85688832;             // ints (~563k)              -> ~86,252,100
    const size_t OFF_ZB  = 86260000;             // zb/yb

    float* h  = ws + OFF_H;
    float* rz = ws + OFF_RZ;
    float* nn = ws + OFF_NN;
    _Float16* AG = (_Float16*)(ws + OFF_AG);
    _Float16* mf = (_Float16*)(ws + OFF_MF);

    _Float16* Win_h = (_Float16*)(ws + OFF_W);   // [256][768] = 196,608 f16
    _Float16* Wrz_h = Win_h + 196608;            // [512][512] = 262,144 f16
    _Float16* Wni_h = Wrz_h + 262144;            // [256][256] = 65,536 f16
    _Float16* Wnh_h = Wni_h + 65536;             // [256][256]
    _Float16* WgT_h = Wnh_h + 65536;             // [6][256][256] = 393,216 f16
    float* brz = ws + OFF_BRZ;

    int* deg  = (int*)(ws + OFF_INT);
    int* fill = deg + N_NODES;
    int* rowp = fill + N_NODES;
    int* col  = rowp + (N_NODES + 1);
    float* zb = ws + OFF_ZB;
    float* yb = zb + 256;

    // conv-phase aliases (rz/nn dead by then; h still live)
    float* C1Z = rz;                 // needs 13.1M (rz is 26.2M)
    float* C1Y = rz + 14000000;      // needs 3.28M
    float* P1Z = nn;                 // needs 6.55M (nn is 26.2M)
    float* P1Y = nn + 7000000;       // needs 1.63M
    float* P2Z = nn + 9000000;       // needs 1.31M
    float* P2Y = nn + 11000000;      // needs 0.33M

    // ---- weight prep ----
    k_cvt<<<192, 256, 0, stream>>>(W_in, Win_h, 49152);          // Win [256,768]
    k_wrz<<<1024, 256, 0, stream>>>(W_ih, W_hh, Wrz_h);          // Wrz [512,512]
    k_cvt<<<64, 256, 0, stream>>>(W_ih + 512 * 256, Wni_h, 16384);
    k_cvt<<<64, 256, 0, stream>>>(W_hh + 512 * 256, Wnh_h, 16384);
    k_cvtT<<<1536, 256, 0, stream>>>(W_g, WgT_h);
    k_bias<<<2, 256, 0, stream>>>(b_ih, b_hh, brz);

    // ---- CSR build ----
    hipMemsetAsync(deg, 0, N_NODES * sizeof(int), stream);
    hipMemsetAsync(fill, 0, N_NODES * sizeof(int), stream);
    k_deg<<<N_EDGES / 256, 256, 0, stream>>>(ei, deg);
    k_scan<<<1, 1024, 0, stream>>>(deg, rowp);
    k_fill<<<N_EDGES / 256, 256, 0, stream>>>(ei, rowp, fill, col);

    // ---- h0 = x @ W_in^T + b_in -> h (fp32) + AG h-half (fp16) ----
    k_gemm2<0, 2, 2><<<800, 256, 0, stream>>>(x, FEAT, Win_h, b_in, h, HID, AG + 256, 512, FEAT);

    // ---- GGNN layers ----
    for (int l = 0; l < 6; ++l) {
        // m = h @ Wg[l] (fp16 out)
        k_gemm2<1, 1, 2><<<800, 256, 0, stream>>>(AG + 256, 512, WgT_h + (size_t)l * 65536,
                                                  nullptr, mf, HID, nullptr, 0, HID);
        // agg (fp16 gather-sum) -> AG agg-half
        k_agg2<<<N_NODES, 256, 0, stream>>>(mf, rowp, col, AG);
        // rz = [agg|h] @ Wrz^T + brz   (K=512, J=512)
        k_gemm2<1, 0, 4><<<1600, 256, 0, stream>>>(AG, 512, Wrz_h, brz, rz, 512, nullptr, 0, 512);
        // i_n = agg @ Wni^T + b_ih_n ; h_n = h @ Wnh^T + b_hh_n
        k_gemm2<1, 0, 2><<<800, 256, 0, stream>>>(AG, 512, Wni_h, b_ih + 512, nn, 512, nullptr, 0, HID);
        k_gemm2<1, 0, 2><<<800, 256, 0, stream>>>(AG + 256, 512, Wnh_h, b_hh + 512, nn + 256, 512, nullptr, 0, HID);
        // GRU update
        k_gru2<<<N_NODES, 256, 0, stream>>>(h, rz, nn, AG);
    }

    // ---- conv head: Z path (concat [h|x], H=1024) ----
    k_conv1<<<dim3(G_GRAPHS, 16), 256, 0, stream>>>(h, x, Wc1, bc1, C1Z, 1024);
    k_pool1<<<dim3(G_GRAPHS, 50), 256, 0, stream>>>(C1Z, P1Z, 1024, 511);
    k_c2p2<<<dim3(G_GRAPHS, 20), 256, 0, stream>>>(P1Z, Wc2, bc2, P2Z, 511, 255);
    k_fc<<<G_GRAPHS, 256, 0, stream>>>(P2Z, Wf1, bf1, zb, 20 * 255);

    // ---- conv head: Y path (h only, H=256) ----
    k_conv1<<<dim3(G_GRAPHS, 4), 256, 0, stream>>>(h, x, Wc1, bc1, C1Y, 256);
    k_pool1<<<dim3(G_GRAPHS, 50), 256, 0, stream>>>(C1Y, P1Y, 256, 127);
    k_c2p2<<<dim3(G_GRAPHS, 20), 256, 0, stream>>>(P1Y, Wc2, bc2, P2Y, 127, 63);
    k_fc<<<G_GRAPHS, 256, 0, stream>>>(P2Y, Wf2, bf2, yb, 20 * 63);

    // ---- final ----
    k_final<<<1, 256, 0, stream>>>(zb, yb, (float*)d_out);
}

// Round 6
// 1819.525 us; speedup vs baseline: 5.2743x; 1.2488x over previous
//
#include <hip/hip_runtime.h>
#include <math.h>

#define N_NODES 51200
#define N_EDGES 409600
#define FEAT    768
#define HID     256
#define NPG     200
#define G_GRAPHS 256

typedef _Float16 f16x8 __attribute__((ext_vector_type(8)));
typedef _Float16 f16x4 __attribute__((ext_vector_type(4)));
typedef _Float16 f16x2 __attribute__((ext_vector_type(2)));
typedef float    f32x4 __attribute__((ext_vector_type(4)));

// ---------------- CSR build ----------------
__global__ __launch_bounds__(256) void k_deg(const int* __restrict__ ei, int* __restrict__ deg) {
    int e = blockIdx.x * 256 + threadIdx.x;
    if (e < N_EDGES) atomicAdd(&deg[ei[N_EDGES + e]], 1);
}

__global__ __launch_bounds__(1024) void k_scan(const int* __restrict__ deg, int* __restrict__ rowp) {
    __shared__ int sums[1024];
    int tid = threadIdx.x;
    int base = tid * 50;
    int s = 0;
    for (int j = 0; j < 50; ++j) s += deg[base + j];
    sums[tid] = s;
    __syncthreads();
    for (int off = 1; off < 1024; off <<= 1) {
        int v = 0;
        if (tid >= off) v = sums[tid - off];
        __syncthreads();
        sums[tid] += v;
        __syncthreads();
    }
    int run = sums[tid] - s; // exclusive prefix
    for (int j = 0; j < 50; ++j) { rowp[base + j] = run; run += deg[base + j]; }
    if (tid == 1023) rowp[N_NODES] = run;
}

__global__ __launch_bounds__(256) void k_fill(const int* __restrict__ ei, const int* __restrict__ rowp,
                                              int* __restrict__ fill, int* __restrict__ col) {
    int e = blockIdx.x * 256 + threadIdx.x;
    if (e < N_EDGES) {
        int d = ei[N_EDGES + e];
        int pos = atomicAdd(&fill[d], 1);
        col[rowp[d] + pos] = ei[e];
    }
}

// ---------------- weight prep ----------------
__global__ __launch_bounds__(256) void k_cvt(const float* __restrict__ in, _Float16* __restrict__ out, int n4) {
    int i = blockIdx.x * 256 + threadIdx.x;
    if (i < n4) {
        float4 v = *(const float4*)&in[i * 4];
        f16x4 h;
        h[0] = (_Float16)v.x; h[1] = (_Float16)v.y; h[2] = (_Float16)v.z; h[3] = (_Float16)v.w;
        *(f16x4*)&out[i * 4] = h;
    }
}

__global__ __launch_bounds__(256) void k_bias(const float* __restrict__ bih, const float* __restrict__ bhh,
                                              float* __restrict__ brz) {
    int i = blockIdx.x * 256 + threadIdx.x;
    if (i < 512) brz[i] = bih[i] + bhh[i];
}

// conv1 weight pack: Wp[ch][o][dk*64+cc] = Wc1[o][ch*64+cc][dk], zero-padded (o<64, 4*64 ch)
__global__ __launch_bounds__(256) void k_wpack(const float* __restrict__ Wc1, _Float16* __restrict__ Wp) {
    int id = blockIdx.x * 256 + threadIdx.x;   // < 4*64*192 = 49152
    int ch = id / 12288, r = id - ch * 12288;
    int o = r / 192, k = r - o * 192;
    int dk = k >> 6, cc = k & 63;
    int c = ch * 64 + cc;
    float v = 0.f;
    if (o < 50 && c < NPG) v = Wc1[(o * NPG + c) * 3 + dk];
    Wp[id] = (_Float16)v;
}

// Wrz2 right halves: Wrz2[l][j][256+c] = Whh[j][c]  (j<512, c<256, all 6 layers)
__global__ __launch_bounds__(256) void k_wcopyrz(const _Float16* __restrict__ Whh, _Float16* __restrict__ Wrz2) {
    int id = blockIdx.x * 256 + threadIdx.x;   // < 6*512*256 = 786432
    int l = id >> 17, r = id & 131071;
    int j = r >> 8, c = r & 255;
    Wrz2[(size_t)l * 262144 + j * 512 + 256 + c] = Whh[j * 256 + c];
}

// ---------------- fp16 MFMA GEMM (NT): C[M,*] = A[M,K] @ B_f16[J,K]^T + bias ----------------
// 128x128 tile, BK=64, 4 waves (2x2 of 64x64), 16x16x32_f16 MFMA, fp32 accumulate.
// LDS tiles [128][64] f16, 16B-slot XOR swizzle (slot ^= row&7) => conflict-free b128.
// AF16: A fp16 (else fp32 converted in staging). OUT: 0=f32, 1=f16, 2=dual(f32 C + f16 C2).
// SWZ=1: XCD-aware decode (grid = (M/128)/... *8*COLB); SWZ=0: plain (grid = (M/128)*COLB).
template<int AF16, int OUT, int COLB, int SWZ>
__global__ __launch_bounds__(256) void k_gemm2(const void* __restrict__ Av, int lda,
                                               const _Float16* __restrict__ B,
                                               const float* __restrict__ bias,
                                               void* __restrict__ Cv, int ldc,
                                               _Float16* __restrict__ C2, int ldc2,
                                               int K) {
    __shared__ _Float16 As[128 * 64];
    __shared__ _Float16 Bs[128 * 64];
    int wg = blockIdx.x;
    int rowBase, colBase;
    if (SWZ) {
        int xcd = wg & 7, t = wg >> 3;
        int cb = t % COLB, gidx = t / COLB;
        rowBase = (gidx * 8 + xcd) * 128;
        colBase = cb * 128;
    } else {
        rowBase = (wg / COLB) * 128;
        colBase = (wg % COLB) * 128;
    }
    int tid = threadIdx.x;
    int lane = tid & 63;
    int wid = tid >> 6;
    int wr = wid >> 1, wc = wid & 1;
    f32x4 acc[4][4] = {};
    for (int k0 = 0; k0 < K; k0 += 64) {
        __syncthreads();
        #pragma unroll
        for (int p = 0; p < 4; ++p) {
            int c = p * 256 + tid;          // 16B chunk id, 1024 per tile
            int row = c >> 3, slot = c & 7;
            int dst = row * 64 + ((slot ^ (row & 7)) * 8);
            if (AF16) {
                const _Float16* srcA = (const _Float16*)Av + (size_t)(rowBase + row) * lda + k0 + slot * 8;
                *(f16x8*)&As[dst] = *(const f16x8*)srcA;
            } else {
                const float* srcA = (const float*)Av + (size_t)(rowBase + row) * lda + k0 + slot * 8;
                float4 f0 = *(const float4*)srcA;
                float4 f1 = *(const float4*)(srcA + 4);
                f16x8 hv;
                hv[0] = (_Float16)f0.x; hv[1] = (_Float16)f0.y; hv[2] = (_Float16)f0.z; hv[3] = (_Float16)f0.w;
                hv[4] = (_Float16)f1.x; hv[5] = (_Float16)f1.y; hv[6] = (_Float16)f1.z; hv[7] = (_Float16)f1.w;
                *(f16x8*)&As[dst] = hv;
            }
            const _Float16* srcB = B + (size_t)(colBase + row) * K + k0 + slot * 8;
            *(f16x8*)&Bs[dst] = *(const f16x8*)srcB;
        }
        __syncthreads();
        #pragma unroll
        for (int ks = 0; ks < 2; ++ks) {
            f16x8 af[4], bf[4];
            #pragma unroll
            for (int mi = 0; mi < 4; ++mi) {
                int row = wr * 64 + mi * 16 + (lane & 15);
                int slot = (lane >> 4) + ks * 4;
                af[mi] = *(const f16x8*)&As[row * 64 + ((slot ^ (row & 7)) * 8)];
            }
            #pragma unroll
            for (int nj = 0; nj < 4; ++nj) {
                int row = wc * 64 + nj * 16 + (lane & 15);
                int slot = (lane >> 4) + ks * 4;
                bf[nj] = *(const f16x8*)&Bs[row * 64 + ((slot ^ (row & 7)) * 8)];
            }
            #pragma unroll
            for (int mi = 0; mi < 4; ++mi)
                #pragma unroll
                for (int nj = 0; nj < 4; ++nj)
                    acc[mi][nj] = __builtin_amdgcn_mfma_f32_16x16x32_f16(af[mi], bf[nj], acc[mi][nj], 0, 0, 0);
        }
    }
    #pragma unroll
    for (int mi = 0; mi < 4; ++mi) {
        #pragma unroll
        for (int nj = 0; nj < 4; ++nj) {
            int col = colBase + wc * 64 + nj * 16 + (lane & 15);
            float bv = bias ? bias[col] : 0.f;
            #pragma unroll
            for (int r = 0; r < 4; ++r) {
                int row = rowBase + wr * 64 + mi * 16 + (lane >> 4) * 4 + r;
                float val = acc[mi][nj][r] + bv;
                if (OUT == 0) {
                    ((float*)Cv)[(size_t)row * ldc + col] = val;
                } else if (OUT == 1) {
                    ((_Float16*)Cv)[(size_t)row * ldc + col] = (_Float16)val;
                } else {
                    ((float*)Cv)[(size_t)row * ldc + col] = val;
                    C2[(size_t)row * ldc2 + col] = (_Float16)val;
                }
            }
        }
    }
}

// ---------------- gather-sum of h (S_v = sum of AG h-half over in-edges) ----------------
__global__ __launch_bounds__(256) void k_agg3(const int* __restrict__ rowp, const int* __restrict__ col,
                                              _Float16* __restrict__ AG) {
    int v = blockIdx.x;
    int f = threadIdx.x;
    int beg = rowp[v], end = rowp[v + 1];
    float s = 0.f;
    for (int i = beg; i < end; ++i)
        s += (float)AG[(size_t)col[i] * 512 + 256 + f];
    AG[(size_t)v * 512 + f] = (_Float16)s;
}

// ---------------- GRU elementwise update (gates fp16 [N][1024]: r|z|i_n|h_n) ----------------
__global__ __launch_bounds__(256) void k_gru3(float* __restrict__ h, const _Float16* __restrict__ gates,
                                              _Float16* __restrict__ AG) {
    int idx = blockIdx.x * 256 + threadIdx.x;   // < N*128
    int n = idx >> 7;
    int c2 = (idx & 127) << 1;
    size_t b = (size_t)n * 1024;
    f16x2 rp = *(const f16x2*)&gates[b + c2];
    f16x2 zp = *(const f16x2*)&gates[b + 256 + c2];
    f16x2 ip = *(const f16x2*)&gates[b + 512 + c2];
    f16x2 hp = *(const f16x2*)&gates[b + 768 + c2];
    float2 hv = *(const float2*)&h[(size_t)n * 256 + c2];
    float r0 = 1.f / (1.f + expf(-(float)rp[0]));
    float r1 = 1.f / (1.f + expf(-(float)rp[1]));
    float z0 = 1.f / (1.f + expf(-(float)zp[0]));
    float z1 = 1.f / (1.f + expf(-(float)zp[1]));
    float n0 = tanhf((float)ip[0] + r0 * (float)hp[0]);
    float n1 = tanhf((float)ip[1] + r1 * (float)hp[1]);
    float o0 = (1.f - z0) * n0 + z0 * hv.x;
    float o1 = (1.f - z1) * n1 + z1 * hv.y;
    float2 ov2; ov2.x = o0; ov2.y = o1;
    *(float2*)&h[(size_t)n * 256 + c2] = ov2;
    f16x2 ov; ov[0] = (_Float16)o0; ov[1] = (_Float16)o1;
    *(f16x2*)&AG[(size_t)n * 512 + 256 + c2] = ov;
}

// ---------------- conv1 as MFMA implicit GEMM ----------------
// Per block: graph g, t-tile of 256. M=64 (o, 50 padded), N=256 (t, 4 waves x 64),
// K = 4 chunks x (64 ch x 3 taps = 192). XT[258][64] f16 (transposed input window,
// XOR-swizzled 16B slots), WL[64][192] f16 (swizzled). fp32 accumulate, bias+ReLU epilogue.
__global__ __launch_bounds__(256, 2) void k_conv1m(const float* __restrict__ h, const float* __restrict__ x,
                                                   const _Float16* __restrict__ Wp, const float* __restrict__ bc1,
                                                   float* __restrict__ out, int H, int TBLK) {
    __shared__ _Float16 XT[258 * 64];
    __shared__ _Float16 WL[64 * 192];
    int g = blockIdx.x / TBLK;
    int tb = blockIdx.x - g * TBLK;
    int t0 = tb * 256;
    int tid = threadIdx.x;
    int lane = tid & 63;
    int wn = (tid >> 6) * 64;
    f32x4 acc[4][4] = {};
    for (int ch = 0; ch < 4; ++ch) {
        __syncthreads();
        // stage weights (swizzled: slot' = (sk&0x18)|((sk&7)^(o&7)))
        #pragma unroll
        for (int i = 0; i < 6; ++i) {
            int q = i * 256 + tid;            // < 1536 chunks of 16B
            int o = q / 24, sk = q - o * 24;
            int skp = (sk & 0x18) | ((sk & 7) ^ (o & 7));
            *(f16x8*)&WL[o * 192 + skp * 8] = *(const f16x8*)&Wp[ch * 12288 + o * 192 + sk * 8];
        }
        // stage input window transposed: XT[t][c], t in [t0-1, t0+257)
        for (int idx = tid; idx < 258 * 64; idx += 256) {
            int t = idx >> 6, c = idx & 63;
            int gt = t0 - 1 + t;
            int cg = ch * 64 + c;
            float v = 0.f;
            if (cg < NPG && gt >= 0 && gt < H) {
                int node = g * NPG + cg;
                v = (gt < HID) ? h[(size_t)node * HID + gt] : x[(size_t)node * FEAT + (gt - HID)];
            }
            XT[t * 64 + ((((c >> 3) ^ (t & 7)) << 3) | (c & 7))] = (_Float16)v;
        }
        __syncthreads();
        #pragma unroll
        for (int ks = 0; ks < 6; ++ks) {
            int dk = ks >> 1, cs0 = (ks & 1) << 2;   // k-local = dk*64 + cc, cc0 = (ks&1)*32
            f16x8 af[4], bf[4];
            #pragma unroll
            for (int mi = 0; mi < 4; ++mi) {
                int o = mi * 16 + (lane & 15);
                int sk = ks * 4 + (lane >> 4);
                int skp = (sk & 0x18) | ((sk & 7) ^ (o & 7));
                af[mi] = *(const f16x8*)&WL[o * 192 + skp * 8];
            }
            #pragma unroll
            for (int nj = 0; nj < 4; ++nj) {
                int tw = wn + nj * 16 + (lane & 15) + dk;   // window idx = t_local + dk
                int sp = (cs0 + (lane >> 4)) ^ (tw & 7);
                bf[nj] = *(const f16x8*)&XT[tw * 64 + sp * 8];
            }
            #pragma unroll
            for (int mi = 0; mi < 4; ++mi)
                #pragma unroll
                for (int nj = 0; nj < 4; ++nj)
                    acc[mi][nj] = __builtin_amdgcn_mfma_f32_16x16x32_f16(af[mi], bf[nj], acc[mi][nj], 0, 0, 0);
        }
    }
    #pragma unroll
    for (int mi = 0; mi < 4; ++mi) {
        #pragma unroll
        for (int r = 0; r < 4; ++r) {
            int o = mi * 16 + (lane >> 4) * 4 + r;
            if (o < 50) {
                float b = bc1[o];
                #pragma unroll
                for (int nj = 0; nj < 4; ++nj) {
                    int t = t0 + wn + nj * 16 + (lane & 15);
                    float v = acc[mi][nj][r] + b;
                    out[(size_t)g * 50 * H + (size_t)o * H + t] = v > 0.f ? v : 0.f;
                }
            }
        }
    }
}

// ---------------- maxpool1d k=3 s=2 ----------------
__global__ __launch_bounds__(256) void k_pool1(const float* __restrict__ in, float* __restrict__ out,
                                               int H, int U) {
    int g = blockIdx.x, o = blockIdx.y;
    const float* p = in + ((size_t)g * 50 + o) * H;
    float* q = out + ((size_t)g * 50 + o) * U;
    for (int u = threadIdx.x; u < U; u += 256) {
        float a = p[2 * u], b = p[2 * u + 1], c = p[2 * u + 2];
        float mm = a > b ? a : b;
        q[u] = mm > c ? mm : c;
    }
}

// ---------------- conv2 (k=1) + maxpool k=2 s=2 ----------------
__global__ __launch_bounds__(256) void k_c2p2(const float* __restrict__ P1, const float* __restrict__ Wc2,
                                              const float* __restrict__ bc2, float* __restrict__ out,
                                              int U, int U2) {
    int g = blockIdx.x, o2 = blockIdx.y;
    float b = bc2[o2];
    for (int u2 = threadIdx.x; u2 < U2; u2 += 256) {
        float a0 = b, a1 = b;
        #pragma unroll 5
        for (int i = 0; i < 50; ++i) {
            float wv = Wc2[o2 * 50 + i];
            const float* p = P1 + ((size_t)g * 50 + i) * U + 2 * u2;
            a0 = fmaf(p[0], wv, a0);
            a1 = fmaf(p[1], wv, a1);
        }
        out[((size_t)g * 20 + o2) * U2 + u2] = a0 > a1 ? a0 : a1;
    }
}

// ---------------- fully-connected (per-graph dot) ----------------
__global__ __launch_bounds__(256) void k_fc(const float* __restrict__ P2, const float* __restrict__ Wf,
                                            const float* __restrict__ bf, float* __restrict__ out, int len) {
    __shared__ float red[256];
    int g = blockIdx.x, tid = threadIdx.x;
    const float* p = P2 + (size_t)g * len;
    float s = 0.f;
    for (int i = tid; i < len; i += 256) s = fmaf(p[i], Wf[i], s);
    red[tid] = s;
    __syncthreads();
    for (int off = 128; off > 0; off >>= 1) {
        if (tid < off) red[tid] += red[tid + off];
        __syncthreads();
    }
    if (tid == 0) out[g] = red[0] + bf[0];
}

// ---------------- final: sigmoid(z*y) -> clip -> logit -> [0, z1] ----------------
__global__ __launch_bounds__(256) void k_final(const float* __restrict__ z, const float* __restrict__ y,
                                               float* __restrict__ out) {
    int g = threadIdx.x;
    float t = z[g] * y[g];
    float p = 1.f / (1.f + expf(-t));
    p = fminf(fmaxf(p, 1e-6f), 1.f - 1e-6f);
    float z1 = logf(p / (1.f - p));
    out[2 * g] = 0.f;
    out[2 * g + 1] = z1;
}

extern "C" void kernel_launch(void* const* d_in, const int* in_sizes, int n_in,
                              void* d_out, int out_size, void* d_ws, size_t ws_size,
                              hipStream_t stream) {
    const float* x     = (const float*)d_in[0];
    const int*   ei    = (const int*)d_in[1];
    const float* W_in  = (const float*)d_in[2];
    const float* b_in  = (const float*)d_in[3];
    const float* W_g   = (const float*)d_in[4];
    const float* W_ih  = (const float*)d_in[5];
    const float* W_hh  = (const float*)d_in[6];
    const float* b_ih  = (const float*)d_in[7];
    const float* b_hh  = (const float*)d_in[8];
    const float* Wc1   = (const float*)d_in[9];
    const float* bc1   = (const float*)d_in[10];
    const float* Wc2   = (const float*)d_in[11];
    const float* bc2   = (const float*)d_in[12];
    const float* Wf1   = (const float*)d_in[13];
    const float* bf1   = (const float*)d_in[14];
    const float* Wf2   = (const float*)d_in[15];
    const float* bf2   = (const float*)d_in[16];

    float* ws = (float*)d_ws;
    // layout (float units)
    const size_t OFF_H     = 0;          // h fp32 [N,256]              -> 13,107,200
    const size_t OFF_AG    = 13107200;   // AG f16 [N,512] (S|h)        -> 26,214,400
    const size_t OFF_GATES = 26214400;   // gates f16 [N,1024]          -> 52,428,800
    const size_t OFF_WF    = 52428800;   // f16 weight arena (2,998,272 f16 = 1,499,136 fl)
    const size_t OFF_BRZ   = 53927936;   // brz [512]
    const size_t OFF_INT   = 53928448;   // ints (563,201)
    const size_t OFF_ZB    = 54491904;   // zb/yb

    float* h = ws + OFF_H;
    _Float16* AG      = (_Float16*)(ws + OFF_AG);
    _Float16* gates16 = (_Float16*)(ws + OFF_GATES);

    _Float16* Win_h = (_Float16*)(ws + OFF_WF);  // [256][768]
    _Float16* Wih_h = Win_h + 196608;            // [768][256]
    _Float16* Whh_h = Wih_h + 196608;            // [768][256]
    _Float16* Wg_h  = Whh_h + 196608;            // [6][256][256] (native d-major)
    _Float16* Wrz2  = Wg_h  + 393216;            // [6][512][512]
    _Float16* Wni2  = Wrz2  + 1572864;           // [6][256][256]
    _Float16* Wp    = Wni2  + 393216;            // [4][64][192]
    float* brz = ws + OFF_BRZ;

    int* deg  = (int*)(ws + OFF_INT);
    int* fill = deg + N_NODES;
    int* rowp = fill + N_NODES;
    int* col  = rowp + (N_NODES + 1);
    float* zb = ws + OFF_ZB;
    float* yb = zb + 256;

    // conv-phase aliases (gates & AG dead after GGNN loop; h still live)
    float* C1Z = ws + OFF_GATES;              // 13.1M
    float* C1Y = ws + OFF_GATES + 13107200;   // 3.28M
    float* P1Z = ws + OFF_AG;                 // 6.54M
    float* P1Y = ws + OFF_AG + 7000000;       // 1.63M
    float* P2Z = ws + OFF_AG + 9000000;       // 1.31M
    float* P2Y = ws + OFF_AG + 11000000;      // 0.33M

    // ---- weight prep ----
    k_cvt<<<192, 256, 0, stream>>>(W_in, Win_h, 49152);
    k_cvt<<<192, 256, 0, stream>>>(W_ih, Wih_h, 49152);
    k_cvt<<<192, 256, 0, stream>>>(W_hh, Whh_h, 49152);
    k_cvt<<<384, 256, 0, stream>>>(W_g, Wg_h, 98304);
    k_bias<<<2, 256, 0, stream>>>(b_ih, b_hh, brz);
    k_wpack<<<192, 256, 0, stream>>>(Wc1, Wp);
    // fold Wg into gate weights: Wrz2[l][:, :256] = Wih[0:512] @ Wg[l]^T(d-major), Wni2[l] = Wih[512:768] @ ...
    for (int l = 0; l < 6; ++l) {
        k_gemm2<1, 1, 2, 0><<<8, 256, 0, stream>>>(Wih_h, 256, Wg_h + l * 65536, nullptr,
                                                   Wrz2 + (size_t)l * 262144, 512, nullptr, 0, 256);
        k_gemm2<1, 1, 2, 0><<<4, 256, 0, stream>>>(Wih_h + 512 * 256, 256, Wg_h + l * 65536, nullptr,
                                                   Wni2 + (size_t)l * 65536, 256, nullptr, 0, 256);
    }
    k_wcopyrz<<<3072, 256, 0, stream>>>(Whh_h, Wrz2);

    // ---- CSR build ----
    hipMemsetAsync(deg, 0, N_NODES * sizeof(int), stream);
    hipMemsetAsync(fill, 0, N_NODES * sizeof(int), stream);
    k_deg<<<N_EDGES / 256, 256, 0, stream>>>(ei, deg);
    k_scan<<<1, 1024, 0, stream>>>(deg, rowp);
    k_fill<<<N_EDGES / 256, 256, 0, stream>>>(ei, rowp, fill, col);

    // ---- h0 = x @ W_in^T + b_in -> h fp32 + AG h-half fp16 ----
    k_gemm2<0, 2, 2, 1><<<800, 256, 0, stream>>>(x, FEAT, Win_h, b_in, h, HID, AG + 256, 512, FEAT);

    // ---- GGNN layers (m-GEMM folded into gate weights) ----
    for (int l = 0; l < 6; ++l) {
        k_agg3<<<N_NODES, 256, 0, stream>>>(rowp, col, AG);
        k_gemm2<1, 1, 4, 1><<<1600, 256, 0, stream>>>(AG, 512, Wrz2 + (size_t)l * 262144, brz,
                                                      gates16, 1024, nullptr, 0, 512);
        k_gemm2<1, 1, 2, 1><<<800, 256, 0, stream>>>(AG, 512, Wni2 + (size_t)l * 65536, b_ih + 512,
                                                     gates16 + 512, 1024, nullptr, 0, 256);
        k_gemm2<1, 1, 2, 1><<<800, 256, 0, stream>>>(AG + 256, 512, Whh_h + 512 * 256, b_hh + 512,
                                                     gates16 + 768, 1024, nullptr, 0, 256);
        k_gru3<<<25600, 256, 0, stream>>>(h, gates16, AG);
    }

    // ---- conv head: Z path (concat [h|x], H=1024) ----
    k_conv1m<<<1024, 256, 0, stream>>>(h, x, Wp, bc1, C1Z, 1024, 4);
    k_pool1<<<dim3(G_GRAPHS, 50), 256, 0, stream>>>(C1Z, P1Z, 1024, 511);
    k_c2p2<<<dim3(G_GRAPHS, 20), 256, 0, stream>>>(P1Z, Wc2, bc2, P2Z, 511, 255);
    k_fc<<<G_GRAPHS, 256, 0, stream>>>(P2Z, Wf1, bf1, zb, 20 * 255);

    // ---- conv head: Y path (h only, H=256) ----
    k_conv1m<<<256, 256, 0, stream>>>(h, x, Wp, bc1, C1Y, 256, 1);
    k_pool1<<<dim3(G_GRAPHS, 50), 256, 0, stream>>>(C1Y, P1Y, 256, 127);
    k_c2p2<<<dim3(G_GRAPHS, 20), 256, 0, stream>>>(P1Y, Wc2, bc2, P2Y, 127, 63);
    k_fc<<<G_GRAPHS, 256, 0, stream>>>(P2Y, Wf2, bf2, yb, 20 * 63);

    // ---- final ----
    k_final<<<1, 256, 0, stream>>>(zb, yb, (float*)d_out);
}

// Round 7
// 1598.570 us; speedup vs baseline: 6.0033x; 1.1382x over previous
//
#include <hip/hip_runtime.h>
#include <math.h>

#define N_NODES 51200
#define N_EDGES 409600
#define FEAT    768
#define HID     256
#define NPG     200
#define G_GRAPHS 256

typedef _Float16 f16x8 __attribute__((ext_vector_type(8)));
typedef _Float16 f16x4 __attribute__((ext_vector_type(4)));
typedef _Float16 f16x2 __attribute__((ext_vector_type(2)));
typedef float    f32x4 __attribute__((ext_vector_type(4)));

// ---------------- CSR build ----------------
__global__ __launch_bounds__(256) void k_deg(const int* __restrict__ ei, int* __restrict__ deg) {
    int e = blockIdx.x * 256 + threadIdx.x;
    if (e < N_EDGES) atomicAdd(&deg[ei[N_EDGES + e]], 1);
}

__global__ __launch_bounds__(1024) void k_scan(const int* __restrict__ deg, int* __restrict__ rowp) {
    __shared__ int sums[1024];
    int tid = threadIdx.x;
    int base = tid * 50;
    int s = 0;
    for (int j = 0; j < 50; ++j) s += deg[base + j];
    sums[tid] = s;
    __syncthreads();
    for (int off = 1; off < 1024; off <<= 1) {
        int v = 0;
        if (tid >= off) v = sums[tid - off];
        __syncthreads();
        sums[tid] += v;
        __syncthreads();
    }
    int run = sums[tid] - s; // exclusive prefix
    for (int j = 0; j < 50; ++j) { rowp[base + j] = run; run += deg[base + j]; }
    if (tid == 1023) rowp[N_NODES] = run;
}

__global__ __launch_bounds__(256) void k_fill(const int* __restrict__ ei, const int* __restrict__ rowp,
                                              int* __restrict__ fill, int* __restrict__ col) {
    int e = blockIdx.x * 256 + threadIdx.x;
    if (e < N_EDGES) {
        int d = ei[N_EDGES + e];
        int pos = atomicAdd(&fill[d], 1);
        col[rowp[d] + pos] = ei[e];
    }
}

// ---------------- weight prep ----------------
__global__ __launch_bounds__(256) void k_cvt(const float* __restrict__ in, _Float16* __restrict__ out, int n4) {
    int i = blockIdx.x * 256 + threadIdx.x;
    if (i < n4) {
        float4 v = *(const float4*)&in[i * 4];
        f16x4 h;
        h[0] = (_Float16)v.x; h[1] = (_Float16)v.y; h[2] = (_Float16)v.z; h[3] = (_Float16)v.w;
        *(f16x4*)&out[i * 4] = h;
    }
}

__global__ __launch_bounds__(256) void k_bias(const float* __restrict__ bih, const float* __restrict__ bhh,
                                              float* __restrict__ brz) {
    int i = blockIdx.x * 256 + threadIdx.x;
    if (i < 512) brz[i] = bih[i] + bhh[i];
}

// conv1 weight pack: Wp[ch][o][dk*64+cc] = Wc1[o][ch*64+cc][dk], zero-padded (o<64, 4*64 ch)
__global__ __launch_bounds__(256) void k_wpack(const float* __restrict__ Wc1, _Float16* __restrict__ Wp) {
    int id = blockIdx.x * 256 + threadIdx.x;   // < 4*64*192 = 49152
    int ch = id / 12288, r = id - ch * 12288;
    int o = r / 192, k = r - o * 192;
    int dk = k >> 6, cc = k & 63;
    int c = ch * 64 + cc;
    float v = 0.f;
    if (o < 50 && c < NPG) v = Wc1[(o * NPG + c) * 3 + dk];
    Wp[id] = (_Float16)v;
}

// Wrz2 right halves: Wrz2[l][j][256+c] = Whh[j][c]  (j<512, c<256, all 6 layers)
__global__ __launch_bounds__(256) void k_wcopyrz(const _Float16* __restrict__ Whh, _Float16* __restrict__ Wrz2) {
    int id = blockIdx.x * 256 + threadIdx.x;   // < 6*512*256 = 786432
    int l = id >> 17, r = id & 131071;
    int j = r >> 8, c = r & 255;
    Wrz2[(size_t)l * 262144 + j * 512 + 256 + c] = Whh[j * 256 + c];
}

// ---------------- fp16 MFMA GEMM (NT): C[M,*] = A[M,K] @ B_f16[J,K]^T + bias ----------------
// 128x128 tile, BK=64, 4 waves (2x2 of 64x64), 16x16x32_f16 MFMA, fp32 accumulate.
// LDS tiles [128][64] f16, 16B-slot XOR swizzle (slot ^= row&7) => conflict-free b128.
// AF16: A fp16 (else fp32 converted in staging). OUT: 0=f32, 1=f16, 2=dual(f32 C + f16 C2).
// SWZ=1: XCD-aware decode. Batch support: l = blockIdx.x / wgPerL picks B/C layer offsets.
template<int AF16, int OUT, int COLB, int SWZ>
__global__ __launch_bounds__(256) void k_gemm2(const void* __restrict__ Av, int lda,
                                               const _Float16* __restrict__ B,
                                               const float* __restrict__ bias,
                                               void* __restrict__ Cv, int ldc,
                                               _Float16* __restrict__ C2, int ldc2,
                                               int K, int wgPerL, int bLStride, int cLStride) {
    __shared__ _Float16 As[128 * 64];
    __shared__ _Float16 Bs[128 * 64];
    int wg = blockIdx.x;
    int l = wg / wgPerL; wg -= l * wgPerL;
    B += (size_t)l * bLStride;
    if (OUT == 1) Cv = (void*)((_Float16*)Cv + (size_t)l * cLStride);
    else          Cv = (void*)((float*)Cv + (size_t)l * cLStride);
    int rowBase, colBase;
    if (SWZ) {
        int xcd = wg & 7, t = wg >> 3;
        int cb = t % COLB, gidx = t / COLB;
        rowBase = (gidx * 8 + xcd) * 128;
        colBase = cb * 128;
    } else {
        rowBase = (wg / COLB) * 128;
        colBase = (wg % COLB) * 128;
    }
    int tid = threadIdx.x;
    int lane = tid & 63;
    int wid = tid >> 6;
    int wr = wid >> 1, wc = wid & 1;
    f32x4 acc[4][4] = {};
    for (int k0 = 0; k0 < K; k0 += 64) {
        __syncthreads();
        #pragma unroll
        for (int p = 0; p < 4; ++p) {
            int c = p * 256 + tid;          // 16B chunk id, 1024 per tile
            int row = c >> 3, slot = c & 7;
            int dst = row * 64 + ((slot ^ (row & 7)) * 8);
            if (AF16) {
                const _Float16* srcA = (const _Float16*)Av + (size_t)(rowBase + row) * lda + k0 + slot * 8;
                *(f16x8*)&As[dst] = *(const f16x8*)srcA;
            } else {
                const float* srcA = (const float*)Av + (size_t)(rowBase + row) * lda + k0 + slot * 8;
                float4 f0 = *(const float4*)srcA;
                float4 f1 = *(const float4*)(srcA + 4);
                f16x8 hv;
                hv[0] = (_Float16)f0.x; hv[1] = (_Float16)f0.y; hv[2] = (_Float16)f0.z; hv[3] = (_Float16)f0.w;
                hv[4] = (_Float16)f1.x; hv[5] = (_Float16)f1.y; hv[6] = (_Float16)f1.z; hv[7] = (_Float16)f1.w;
                *(f16x8*)&As[dst] = hv;
            }
            const _Float16* srcB = B + (size_t)(colBase + row) * K + k0 + slot * 8;
            *(f16x8*)&Bs[dst] = *(const f16x8*)srcB;
        }
        __syncthreads();
        #pragma unroll
        for (int ks = 0; ks < 2; ++ks) {
            f16x8 af[4], bf[4];
            #pragma unroll
            for (int mi = 0; mi < 4; ++mi) {
                int row = wr * 64 + mi * 16 + (lane & 15);
                int slot = (lane >> 4) + ks * 4;
                af[mi] = *(const f16x8*)&As[row * 64 + ((slot ^ (row & 7)) * 8)];
            }
            #pragma unroll
            for (int nj = 0; nj < 4; ++nj) {
                int row = wc * 64 + nj * 16 + (lane & 15);
                int slot = (lane >> 4) + ks * 4;
                bf[nj] = *(const f16x8*)&Bs[row * 64 + ((slot ^ (row & 7)) * 8)];
            }
            #pragma unroll
            for (int mi = 0; mi < 4; ++mi)
                #pragma unroll
                for (int nj = 0; nj < 4; ++nj)
                    acc[mi][nj] = __builtin_amdgcn_mfma_f32_16x16x32_f16(af[mi], bf[nj], acc[mi][nj], 0, 0, 0);
        }
    }
    #pragma unroll
    for (int mi = 0; mi < 4; ++mi) {
        #pragma unroll
        for (int nj = 0; nj < 4; ++nj) {
            int col = colBase + wc * 64 + nj * 16 + (lane & 15);
            float bv = bias ? bias[col] : 0.f;
            #pragma unroll
            for (int r = 0; r < 4; ++r) {
                int row = rowBase + wr * 64 + mi * 16 + (lane >> 4) * 4 + r;
                float val = acc[mi][nj][r] + bv;
                if (OUT == 0) {
                    ((float*)Cv)[(size_t)row * ldc + col] = val;
                } else if (OUT == 1) {
                    ((_Float16*)Cv)[(size_t)row * ldc + col] = (_Float16)val;
                } else {
                    ((float*)Cv)[(size_t)row * ldc + col] = val;
                    C2[(size_t)row * ldc2 + col] = (_Float16)val;
                }
            }
        }
    }
}

// ---------------- gather-sum of h (S_v = sum of AG h-half over in-edges) ----------------
__global__ __launch_bounds__(256) void k_agg3(const int* __restrict__ rowp, const int* __restrict__ col,
                                              _Float16* __restrict__ AG) {
    int v = blockIdx.x;
    int f = threadIdx.x;
    int beg = rowp[v], end = rowp[v + 1];
    float s = 0.f;
    for (int i = beg; i < end; ++i)
        s += (float)AG[(size_t)col[i] * 512 + 256 + f];
    AG[(size_t)v * 512 + f] = (_Float16)s;
}

// ---------------- GRU elementwise update (gates fp16 [N][1024]: r|z|i_n|h_n) ----------------
__global__ __launch_bounds__(256) void k_gru3(float* __restrict__ h, const _Float16* __restrict__ gates,
                                              _Float16* __restrict__ AG) {
    int idx = blockIdx.x * 256 + threadIdx.x;   // < N*128
    int n = idx >> 7;
    int c2 = (idx & 127) << 1;
    size_t b = (size_t)n * 1024;
    f16x2 rp = *(const f16x2*)&gates[b + c2];
    f16x2 zp = *(const f16x2*)&gates[b + 256 + c2];
    f16x2 ip = *(const f16x2*)&gates[b + 512 + c2];
    f16x2 hp = *(const f16x2*)&gates[b + 768 + c2];
    float2 hv = *(const float2*)&h[(size_t)n * 256 + c2];
    float r0 = 1.f / (1.f + expf(-(float)rp[0]));
    float r1 = 1.f / (1.f + expf(-(float)rp[1]));
    float z0 = 1.f / (1.f + expf(-(float)zp[0]));
    float z1 = 1.f / (1.f + expf(-(float)zp[1]));
    float n0 = tanhf((float)ip[0] + r0 * (float)hp[0]);
    float n1 = tanhf((float)ip[1] + r1 * (float)hp[1]);
    float o0 = (1.f - z0) * n0 + z0 * hv.x;
    float o1 = (1.f - z1) * n1 + z1 * hv.y;
    float2 ov2; ov2.x = o0; ov2.y = o1;
    *(float2*)&h[(size_t)n * 256 + c2] = ov2;
    f16x2 ov; ov[0] = (_Float16)o0; ov[1] = (_Float16)o1;
    *(f16x2*)&AG[(size_t)n * 512 + 256 + c2] = ov;
}

// ---------------- conv1 as MFMA implicit GEMM (coalesced f16 staging + reg transpose) ----------------
// Per block: graph g, t-tile of 256. M=64 (o, 50 padded), N=256 (t, 4 waves x 64),
// K = 4 chunks x (64 ch x 3 taps). XT[272][64] f16 covers gpos in [t0-8, t0+264);
// swizzle key = (p&7)^((p>>3)&7) -> conflict-free b128 on write AND read.
// Inputs read fp16: hf = AG h-half (stride 512), xf = XF [N,768].
__global__ __launch_bounds__(256, 2) void k_conv1m(const _Float16* __restrict__ hf, const _Float16* __restrict__ xf,
                                                   const _Float16* __restrict__ Wp, const float* __restrict__ bc1,
                                                   float* __restrict__ out, int H, int TBLK) {
    __shared__ _Float16 XT[272 * 64];
    __shared__ _Float16 WL[64 * 192];
    int g = blockIdx.x / TBLK;
    int tb = blockIdx.x - g * TBLK;
    int t0 = tb * 256;
    int tid = threadIdx.x;
    int lane = tid & 63;
    int wn = (tid >> 6) * 64;
    f32x4 acc[4][4] = {};
    for (int ch = 0; ch < 4; ++ch) {
        __syncthreads();
        // stage weights (swizzled: slot' = (sk&0x18)|((sk&7)^(o&7)))
        #pragma unroll
        for (int i = 0; i < 6; ++i) {
            int q = i * 256 + tid;            // < 1536 chunks of 16B
            int o = q / 24, sk = q - o * 24;
            int skp = (sk & 0x18) | ((sk & 7) ^ (o & 7));
            *(f16x8*)&WL[o * 192 + skp * 8] = *(const f16x8*)&Wp[ch * 12288 + o * 192 + sk * 8];
        }
        // stage input: coalesced f16x8 row reads, 8x8 register transpose, b128 LDS writes
        for (int u = tid; u < 272; u += 256) {
            int r8 = u / 34, pc = u - r8 * 34;       // rowgroup 0..7, poschunk 0..33
            int gstart = t0 - 8 + pc * 8;
            int c0 = r8 * 8;
            f16x8 zv;
            #pragma unroll
            for (int q = 0; q < 8; ++q) zv[q] = (_Float16)0.f;
            f16x8 rows[8];
            if (gstart < 0 || gstart >= H) {
                #pragma unroll
                for (int j = 0; j < 8; ++j) rows[j] = zv;
            } else {
                const _Float16* base;
                int stride;
                if (gstart < HID) { base = hf + gstart; stride = 512; }
                else              { base = xf + (gstart - HID); stride = 768; }
                int node0 = g * NPG + ch * 64 + c0;
                #pragma unroll
                for (int j = 0; j < 8; ++j) {
                    int cg = ch * 64 + c0 + j;
                    rows[j] = (cg < NPG) ? *(const f16x8*)&base[(size_t)(node0 + j) * stride] : zv;
                }
            }
            #pragma unroll
            for (int jj = 0; jj < 8; ++jj) {
                f16x8 w;
                #pragma unroll
                for (int j = 0; j < 8; ++j) w[j] = rows[j][jj];
                int p = pc * 8 + jj;
                int slot = r8 ^ jj ^ (pc & 7);       // r8 ^ (p&7) ^ ((p>>3)&7)
                *(f16x8*)&XT[p * 64 + slot * 8] = w;
            }
        }
        __syncthreads();
        #pragma unroll
        for (int ks = 0; ks < 6; ++ks) {
            int dk = ks >> 1, cs0 = (ks & 1) << 2;
            f16x8 af[4], bf[4];
            #pragma unroll
            for (int mi = 0; mi < 4; ++mi) {
                int o = mi * 16 + (lane & 15);
                int sk = ks * 4 + (lane >> 4);
                int skp = (sk & 0x18) | ((sk & 7) ^ (o & 7));
                af[mi] = *(const f16x8*)&WL[o * 192 + skp * 8];
            }
            #pragma unroll
            for (int nj = 0; nj < 4; ++nj) {
                int tw = wn + nj * 16 + (lane & 15) + dk + 7;   // window row
                int sp = (cs0 + (lane >> 4)) ^ (tw & 7) ^ ((tw >> 3) & 7);
                bf[nj] = *(const f16x8*)&XT[tw * 64 + sp * 8];
            }
            #pragma unroll
            for (int mi = 0; mi < 4; ++mi)
                #pragma unroll
                for (int nj = 0; nj < 4; ++nj)
                    acc[mi][nj] = __builtin_amdgcn_mfma_f32_16x16x32_f16(af[mi], bf[nj], acc[mi][nj], 0, 0, 0);
        }
    }
    #pragma unroll
    for (int mi = 0; mi < 4; ++mi) {
        #pragma unroll
        for (int r = 0; r < 4; ++r) {
            int o = mi * 16 + (lane >> 4) * 4 + r;
            if (o < 50) {
                float b = bc1[o];
                #pragma unroll
                for (int nj = 0; nj < 4; ++nj) {
                    int t = t0 + wn + nj * 16 + (lane & 15);
                    float v = acc[mi][nj][r] + b;
                    out[(size_t)g * 50 * H + (size_t)o * H + t] = v > 0.f ? v : 0.f;
                }
            }
        }
    }
}

// ---------------- maxpool1d k=3 s=2 ----------------
__global__ __launch_bounds__(256) void k_pool1(const float* __restrict__ in, float* __restrict__ out,
                                               int H, int U) {
    int g = blockIdx.x, o = blockIdx.y;
    const float* p = in + ((size_t)g * 50 + o) * H;
    float* q = out + ((size_t)g * 50 + o) * U;
    for (int u = threadIdx.x; u < U; u += 256) {
        float a = p[2 * u], b = p[2 * u + 1], c = p[2 * u + 2];
        float mm = a > b ? a : b;
        q[u] = mm > c ? mm : c;
    }
}

// ---------------- conv2 (k=1) + maxpool k=2 s=2 ----------------
__global__ __launch_bounds__(256) void k_c2p2(const float* __restrict__ P1, const float* __restrict__ Wc2,
                                              const float* __restrict__ bc2, float* __restrict__ out,
                                              int U, int U2) {
    int g = blockIdx.x, o2 = blockIdx.y;
    float b = bc2[o2];
    for (int u2 = threadIdx.x; u2 < U2; u2 += 256) {
        float a0 = b, a1 = b;
        #pragma unroll 5
        for (int i = 0; i < 50; ++i) {
            float wv = Wc2[o2 * 50 + i];
            const float* p = P1 + ((size_t)g * 50 + i) * U + 2 * u2;
            a0 = fmaf(p[0], wv, a0);
            a1 = fmaf(p[1], wv, a1);
        }
        out[((size_t)g * 20 + o2) * U2 + u2] = a0 > a1 ? a0 : a1;
    }
}

// ---------------- fully-connected (per-graph dot) ----------------
__global__ __launch_bounds__(256) void k_fc(const float* __restrict__ P2, const float* __restrict__ Wf,
                                            const float* __restrict__ bf, float* __restrict__ out, int len) {
    __shared__ float red[256];
    int g = blockIdx.x, tid = threadIdx.x;
    const float* p = P2 + (size_t)g * len;
    float s = 0.f;
    for (int i = tid; i < len; i += 256) s = fmaf(p[i], Wf[i], s);
    red[tid] = s;
    __syncthreads();
    for (int off = 128; off > 0; off >>= 1) {
        if (tid < off) red[tid] += red[tid + off];
        __syncthreads();
    }
    if (tid == 0) out[g] = red[0] + bf[0];
}

// ---------------- final: sigmoid(z*y) -> clip -> logit -> [0, z1] ----------------
__global__ __launch_bounds__(256) void k_final(const float* __restrict__ z, const float* __restrict__ y,
                                               float* __restrict__ out) {
    int g = threadIdx.x;
    float t = z[g] * y[g];
    float p = 1.f / (1.f + expf(-t));
    p = fminf(fmaxf(p, 1e-6f), 1.f - 1e-6f);
    float z1 = logf(p / (1.f - p));
    out[2 * g] = 0.f;
    out[2 * g + 1] = z1;
}

extern "C" void kernel_launch(void* const* d_in, const int* in_sizes, int n_in,
                              void* d_out, int out_size, void* d_ws, size_t ws_size,
                              hipStream_t stream) {
    const float* x     = (const float*)d_in[0];
    const int*   ei    = (const int*)d_in[1];
    const float* W_in  = (const float*)d_in[2];
    const float* b_in  = (const float*)d_in[3];
    const float* W_g   = (const float*)d_in[4];
    const float* W_ih  = (const float*)d_in[5];
    const float* W_hh  = (const float*)d_in[6];
    const float* b_ih  = (const float*)d_in[7];
    const float* b_hh  = (const float*)d_in[8];
    const float* Wc1   = (const float*)d_in[9];
    const float* bc1   = (const float*)d_in[10];
    const float* Wc2   = (const float*)d_in[11];
    const float* bc2   = (const float*)d_in[12];
    const float* Wf1   = (const float*)d_in[13];
    const float* bf1   = (const float*)d_in[14];
    const float* Wf2   = (const float*)d_in[15];
    const float* bf2   = (const float*)d_in[16];

    float* ws = (float*)d_ws;
    // layout (float units)
    const size_t OFF_H     = 0;          // h fp32 [N,256]              -> 13,107,200
    const size_t OFF_AG    = 13107200;   // AG f16 [N,512] (S|h)        -> 26,214,400
    const size_t OFF_GATES = 26214400;   // gates f16 [N,1024]          -> 52,428,800
    const size_t OFF_WF    = 52428800;   // f16 weight arena            -> 53,927,936
    const size_t OFF_BRZ   = 53927936;   // brz [512]
    const size_t OFF_INT   = 53928448;   // ints (563,201)
    const size_t OFF_ZB    = 54491904;   // zb/yb (512)
    const size_t OFF_XF    = 54492416;   // XF f16 [N,768] (9,830,400 fl) -> 64,322,816

    float* h = ws + OFF_H;
    _Float16* AG      = (_Float16*)(ws + OFF_AG);
    _Float16* gates16 = (_Float16*)(ws + OFF_GATES);
    _Float16* XF      = (_Float16*)(ws + OFF_XF);

    _Float16* Win_h = (_Float16*)(ws + OFF_WF);  // [256][768]
    _Float16* Wih_h = Win_h + 196608;            // [768][256]
    _Float16* Whh_h = Wih_h + 196608;            // [768][256]
    _Float16* Wg_h  = Whh_h + 196608;            // [6][256][256] (native d-major)
    _Float16* Wrz2  = Wg_h  + 393216;            // [6][512][512]
    _Float16* Wni2  = Wrz2  + 1572864;           // [6][256][256]
    _Float16* Wp    = Wni2  + 393216;            // [4][64][192]
    float* brz = ws + OFF_BRZ;

    int* deg  = (int*)(ws + OFF_INT);
    int* fill = deg + N_NODES;
    int* rowp = fill + N_NODES;
    int* col  = rowp + (N_NODES + 1);
    float* zb = ws + OFF_ZB;
    float* yb = zb + 256;

    // conv-phase aliases (gates & AG-S dead after GGNN loop)
    float* C1Z = ws + OFF_GATES;              // 13.1M
    float* C1Y = ws + OFF_GATES + 13107200;   // 3.28M
    float* P1Z = ws + OFF_H;                  // 6.54M (h fp32 dead in conv phase)
    float* P1Y = ws + OFF_H + 7000000;        // 1.63M
    float* P2Z = ws + OFF_H + 9000000;        // 1.31M
    float* P2Y = ws + OFF_H + 11000000;       // 0.33M

    // ---- weight prep ----
    k_cvt<<<192, 256, 0, stream>>>(W_in, Win_h, 49152);
    k_cvt<<<192, 256, 0, stream>>>(W_ih, Wih_h, 49152);
    k_cvt<<<192, 256, 0, stream>>>(W_hh, Whh_h, 49152);
    k_cvt<<<384, 256, 0, stream>>>(W_g, Wg_h, 98304);
    k_cvt<<<38400, 256, 0, stream>>>(x, XF, 9830400);     // XF = fp16 copy of x
    k_bias<<<2, 256, 0, stream>>>(b_ih, b_hh, brz);
    k_wpack<<<192, 256, 0, stream>>>(Wc1, Wp);
    // fold Wg into gate weights, batched over all 6 layers (2 launches)
    k_gemm2<1, 1, 2, 0><<<48, 256, 0, stream>>>(Wih_h, 256, Wg_h, nullptr,
                                                Wrz2, 512, nullptr, 0, 256, 8, 65536, 262144);
    k_gemm2<1, 1, 2, 0><<<24, 256, 0, stream>>>(Wih_h + 512 * 256, 256, Wg_h, nullptr,
                                                Wni2, 256, nullptr, 0, 256, 4, 65536, 65536);
    k_wcopyrz<<<3072, 256, 0, stream>>>(Whh_h, Wrz2);

    // ---- CSR build ----
    hipMemsetAsync(deg, 0, N_NODES * sizeof(int), stream);
    hipMemsetAsync(fill, 0, N_NODES * sizeof(int), stream);
    k_deg<<<N_EDGES / 256, 256, 0, stream>>>(ei, deg);
    k_scan<<<1, 1024, 0, stream>>>(deg, rowp);
    k_fill<<<N_EDGES / 256, 256, 0, stream>>>(ei, rowp, fill, col);

    // ---- h0 = x @ W_in^T + b_in -> h fp32 + AG h-half fp16 ----
    k_gemm2<0, 2, 2, 1><<<800, 256, 0, stream>>>(x, FEAT, Win_h, b_in, h, HID, AG + 256, 512,
                                                 FEAT, 800, 0, 0);

    // ---- GGNN layers (m-GEMM folded into gate weights) ----
    for (int l = 0; l < 6; ++l) {
        k_agg3<<<N_NODES, 256, 0, stream>>>(rowp, col, AG);
        k_gemm2<1, 1, 4, 1><<<1600, 256, 0, stream>>>(AG, 512, Wrz2 + (size_t)l * 262144, brz,
                                                      gates16, 1024, nullptr, 0, 512, 1600, 0, 0);
        k_gemm2<1, 1, 2, 1><<<800, 256, 0, stream>>>(AG, 512, Wni2 + (size_t)l * 65536, b_ih + 512,
                                                     gates16 + 512, 1024, nullptr, 0, 256, 800, 0, 0);
        k_gemm2<1, 1, 2, 1><<<800, 256, 0, stream>>>(AG + 256, 512, Whh_h + 512 * 256, b_hh + 512,
                                                     gates16 + 768, 1024, nullptr, 0, 256, 800, 0, 0);
        k_gru3<<<25600, 256, 0, stream>>>(h, gates16, AG);
    }

    // ---- conv head: Z path (concat [h|x], H=1024) ----
    k_conv1m<<<1024, 256, 0, stream>>>(AG + 256, XF, Wp, bc1, C1Z, 1024, 4);
    k_pool1<<<dim3(G_GRAPHS, 50), 256, 0, stream>>>(C1Z, P1Z, 1024, 511);
    k_c2p2<<<dim3(G_GRAPHS, 20), 256, 0, stream>>>(P1Z, Wc2, bc2, P2Z, 511, 255);
    k_fc<<<G_GRAPHS, 256, 0, stream>>>(P2Z, Wf1, bf1, zb, 20 * 255);

    // ---- conv head: Y path (h only, H=256) ----
    k_conv1m<<<256, 256, 0, stream>>>(AG + 256, XF, Wp, bc1, C1Y, 256, 1);
    k_pool1<<<dim3(G_GRAPHS, 50), 256, 0, stream>>>(C1Y, P1Y, 256, 127);
    k_c2p2<<<dim3(G_GRAPHS, 20), 256, 0, stream>>>(P1Y, Wc2, bc2, P2Y, 127, 63);
    k_fc<<<G_GRAPHS, 256, 0, stream>>>(P2Y, Wf2, bf2, yb, 20 * 63);

    // ---- final ----
    k_final<<<1, 256, 0, stream>>>(zb, yb, (float*)d_out);
}

// Round 9
// 1223.371 us; speedup vs baseline: 7.8445x; 1.3067x over previous
//
#include <hip/hip_runtime.h>
#include <math.h>

#define N_NODES 51200
#define N_EDGES 409600
#define FEAT    768
#define HID     256
#define NPG     200
#define G_GRAPHS 256

typedef _Float16 f16x8 __attribute__((ext_vector_type(8)));
typedef _Float16 f16x4 __attribute__((ext_vector_type(4)));
typedef _Float16 f16x2 __attribute__((ext_vector_type(2)));
typedef float    f32x4 __attribute__((ext_vector_type(4)));

// ---------------- CSR build ----------------
__global__ __launch_bounds__(256) void k_deg(const int* __restrict__ ei, int* __restrict__ deg) {
    int e = blockIdx.x * 256 + threadIdx.x;
    if (e < N_EDGES) atomicAdd(&deg[ei[N_EDGES + e]], 1);
}

__global__ __launch_bounds__(1024) void k_scan(const int* __restrict__ deg, int* __restrict__ rowp) {
    __shared__ int sums[1024];
    int tid = threadIdx.x;
    int base = tid * 50;
    int s = 0;
    for (int j = 0; j < 50; ++j) s += deg[base + j];
    sums[tid] = s;
    __syncthreads();
    for (int off = 1; off < 1024; off <<= 1) {
        int v = 0;
        if (tid >= off) v = sums[tid - off];
        __syncthreads();
        sums[tid] += v;
        __syncthreads();
    }
    int run = sums[tid] - s; // exclusive prefix
    for (int j = 0; j < 50; ++j) { rowp[base + j] = run; run += deg[base + j]; }
    if (tid == 1023) rowp[N_NODES] = run;
}

__global__ __launch_bounds__(256) void k_fill(const int* __restrict__ ei, const int* __restrict__ rowp,
                                              int* __restrict__ fill, int* __restrict__ col) {
    int e = blockIdx.x * 256 + threadIdx.x;
    if (e < N_EDGES) {
        int d = ei[N_EDGES + e];
        int pos = atomicAdd(&fill[d], 1);
        col[rowp[d] + pos] = ei[e];
    }
}

// ---------------- weight prep ----------------
__global__ __launch_bounds__(256) void k_cvt(const float* __restrict__ in, _Float16* __restrict__ out, int n4) {
    int i = blockIdx.x * 256 + threadIdx.x;
    if (i < n4) {
        float4 v = *(const float4*)&in[i * 4];
        f16x4 h;
        h[0] = (_Float16)v.x; h[1] = (_Float16)v.y; h[2] = (_Float16)v.z; h[3] = (_Float16)v.w;
        *(f16x4*)&out[i * 4] = h;
    }
}

__global__ __launch_bounds__(256) void k_bias(const float* __restrict__ bih, const float* __restrict__ bhh,
                                              float* __restrict__ brz) {
    int i = blockIdx.x * 256 + threadIdx.x;
    if (i < 512) brz[i] = bih[i] + bhh[i];
}

// bnn: [b_ih[512:768] | b_hh[512:768]]
__global__ __launch_bounds__(256) void k_bnn(const float* __restrict__ bih, const float* __restrict__ bhh,
                                             float* __restrict__ bnn) {
    int i = blockIdx.x * 256 + threadIdx.x;
    if (i < 512) bnn[i] = (i < 256) ? bih[512 + i] : bhh[512 + (i - 256)];
}

// conv1 weight pack: Wp[ch][o][dk*64+cc] = Wc1[o][ch*64+cc][dk], zero-padded (o<64, 4*64 ch)
__global__ __launch_bounds__(256) void k_wpack(const float* __restrict__ Wc1, _Float16* __restrict__ Wp) {
    int id = blockIdx.x * 256 + threadIdx.x;   // < 4*64*192 = 49152
    int ch = id / 12288, r = id - ch * 12288;
    int o = r / 192, k = r - o * 192;
    int dk = k >> 6, cc = k & 63;
    int c = ch * 64 + cc;
    float v = 0.f;
    if (o < 50 && c < NPG) v = Wc1[(o * NPG + c) * 3 + dk];
    Wp[id] = (_Float16)v;
}

// Wrz2 right halves: Wrz2[l][j][256+c] = Whh[j][c]  (j<512, c<256, all 6 layers)
__global__ __launch_bounds__(256) void k_wcopyrz(const _Float16* __restrict__ Whh, _Float16* __restrict__ Wrz2) {
    int id = blockIdx.x * 256 + threadIdx.x;   // < 6*512*256 = 786432
    int l = id >> 17, r = id & 131071;
    int j = r >> 8, c = r & 255;
    Wrz2[(size_t)l * 262144 + j * 512 + 256 + c] = Whh[j * 256 + c];
}

// Wnn[l][1] = Whh rows 512..767 (all 6 layers)
__global__ __launch_bounds__(256) void k_wcopynn(const _Float16* __restrict__ Whh, _Float16* __restrict__ Wnn) {
    int id = blockIdx.x * 256 + threadIdx.x;   // < 6*65536
    int l = id >> 16, r = id & 65535;
    Wnn[(size_t)l * 131072 + 65536 + r] = Whh[512 * 256 + r];
}

// ---------------- fp16 MFMA GEMM (NT): C[M,*] = A[M,K] @ B_f16[J,K]^T + bias ----------------
// 128x128 tile, BK=64, 4 waves (2x2 of 64x64), 16x16x32_f16 MFMA, fp32 accumulate.
// LDS tiles [128][64] f16, 16B-slot XOR swizzle (slot ^= row&7) => conflict-free b128.
// AF16: A fp16 (else fp32, converted in staging). OUT: 0=f32, 1=f16, 2=dual.
// SWZ=1: XCD-aware decode. Batch: l = blockIdx.x / wgPerL offsets A/B/C/bias.
template<int AF16, int OUT, int COLB, int SWZ>
__global__ __launch_bounds__(256) void k_gemm2(const void* __restrict__ Av, int lda,
                                               const _Float16* __restrict__ B,
                                               const float* __restrict__ bias,
                                               void* __restrict__ Cv, int ldc,
                                               _Float16* __restrict__ C2, int ldc2,
                                               int K, int wgPerL, int aLStride, int bLStride,
                                               int cLStride, int biasStride) {
    __shared__ _Float16 As[128 * 64];
    __shared__ _Float16 Bs[128 * 64];
    int wg = blockIdx.x;
    int l = wg / wgPerL; wg -= l * wgPerL;
    if (AF16) Av = (const void*)((const _Float16*)Av + (size_t)l * aLStride);
    else      Av = (const void*)((const float*)Av + (size_t)l * aLStride);
    B += (size_t)l * bLStride;
    if (bias) bias += (size_t)l * biasStride;
    if (OUT == 1) Cv = (void*)((_Float16*)Cv + (size_t)l * cLStride);
    else          Cv = (void*)((float*)Cv + (size_t)l * cLStride);
    int rowBase, colBase;
    if (SWZ) {
        int xcd = wg & 7, t = wg >> 3;
        int cb = t % COLB, gidx = t / COLB;
        rowBase = (gidx * 8 + xcd) * 128;
        colBase = cb * 128;
    } else {
        rowBase = (wg / COLB) * 128;
        colBase = (wg % COLB) * 128;
    }
    int tid = threadIdx.x;
    int lane = tid & 63;
    int wid = tid >> 6;
    int wr = wid >> 1, wc = wid & 1;
    f32x4 acc[4][4] = {};
    for (int k0 = 0; k0 < K; k0 += 64) {
        __syncthreads();
        #pragma unroll
        for (int p = 0; p < 4; ++p) {
            int c = p * 256 + tid;          // 16B chunk id, 1024 per tile
            int row = c >> 3, slot = c & 7;
            int dst = row * 64 + ((slot ^ (row & 7)) * 8);
            if (AF16) {
                const _Float16* srcA = (const _Float16*)Av + (size_t)(rowBase + row) * lda + k0 + slot * 8;
                *(f16x8*)&As[dst] = *(const f16x8*)srcA;
            } else {
                const float* srcA = (const float*)Av + (size_t)(rowBase + row) * lda + k0 + slot * 8;
                float4 f0 = *(const float4*)srcA;
                float4 f1 = *(const float4*)(srcA + 4);
                f16x8 hv;
                hv[0] = (_Float16)f0.x; hv[1] = (_Float16)f0.y; hv[2] = (_Float16)f0.z; hv[3] = (_Float16)f0.w;
                hv[4] = (_Float16)f1.x; hv[5] = (_Float16)f1.y; hv[6] = (_Float16)f1.z; hv[7] = (_Float16)f1.w;
                *(f16x8*)&As[dst] = hv;
            }
            const _Float16* srcB = B + (size_t)(colBase + row) * K + k0 + slot * 8;
            *(f16x8*)&Bs[dst] = *(const f16x8*)srcB;
        }
        __syncthreads();
        #pragma unroll
        for (int ks = 0; ks < 2; ++ks) {
            f16x8 af[4], bf[4];
            #pragma unroll
            for (int mi = 0; mi < 4; ++mi) {
                int row = wr * 64 + mi * 16 + (lane & 15);
                int slot = (lane >> 4) + ks * 4;
                af[mi] = *(const f16x8*)&As[row * 64 + ((slot ^ (row & 7)) * 8)];
            }
            #pragma unroll
            for (int nj = 0; nj < 4; ++nj) {
                int row = wc * 64 + nj * 16 + (lane & 15);
                int slot = (lane >> 4) + ks * 4;
                bf[nj] = *(const f16x8*)&Bs[row * 64 + ((slot ^ (row & 7)) * 8)];
            }
            #pragma unroll
            for (int mi = 0; mi < 4; ++mi)
                #pragma unroll
                for (int nj = 0; nj < 4; ++nj)
                    acc[mi][nj] = __builtin_amdgcn_mfma_f32_16x16x32_f16(af[mi], bf[nj], acc[mi][nj], 0, 0, 0);
        }
    }
    #pragma unroll
    for (int mi = 0; mi < 4; ++mi) {
        #pragma unroll
        for (int nj = 0; nj < 4; ++nj) {
            int col = colBase + wc * 64 + nj * 16 + (lane & 15);
            float bv = bias ? bias[col] : 0.f;
            #pragma unroll
            for (int r = 0; r < 4; ++r) {
                int row = rowBase + wr * 64 + mi * 16 + (lane >> 4) * 4 + r;
                float val = acc[mi][nj][r] + bv;
                if (OUT == 0) {
                    ((float*)Cv)[(size_t)row * ldc + col] = val;
                } else if (OUT == 1) {
                    ((_Float16*)Cv)[(size_t)row * ldc + col] = (_Float16)val;
                } else {
                    ((float*)Cv)[(size_t)row * ldc + col] = val;
                    C2[(size_t)row * ldc2 + col] = (_Float16)val;
                }
            }
        }
    }
}

// ---------------- gather-sum of h: wave-per-node, b64 loads ----------------
__global__ __launch_bounds__(256) void k_agg4(const int* __restrict__ rowp, const int* __restrict__ col,
                                              _Float16* __restrict__ AG) {
    int v = blockIdx.x * 4 + (threadIdx.x >> 6);
    int lane = threadIdx.x & 63;
    int beg = rowp[v], end = rowp[v + 1];
    const _Float16* hf = AG + 256 + lane * 4;
    float a0 = 0.f, a1 = 0.f, a2 = 0.f, a3 = 0.f;
    int i = beg;
    for (; i + 1 < end; i += 2) {
        f16x4 u = *(const f16x4*)&hf[(size_t)col[i] * 512];
        f16x4 w = *(const f16x4*)&hf[(size_t)col[i + 1] * 512];
        a0 += (float)u[0] + (float)w[0];
        a1 += (float)u[1] + (float)w[1];
        a2 += (float)u[2] + (float)w[2];
        a3 += (float)u[3] + (float)w[3];
    }
    if (i < end) {
        f16x4 u = *(const f16x4*)&hf[(size_t)col[i] * 512];
        a0 += (float)u[0]; a1 += (float)u[1]; a2 += (float)u[2]; a3 += (float)u[3];
    }
    f16x4 o;
    o[0] = (_Float16)a0; o[1] = (_Float16)a1; o[2] = (_Float16)a2; o[3] = (_Float16)a3;
    *(f16x4*)&AG[(size_t)v * 512 + lane * 4] = o;
}

// ---------------- GRU elementwise update, fp16 carry (gates [N][1024]: r|z|i_n|h_n) ----------------
__global__ __launch_bounds__(256) void k_gru4(const _Float16* __restrict__ gates, _Float16* __restrict__ AG) {
    int idx = blockIdx.x * 256 + threadIdx.x;   // < N*32
    int n = idx >> 5;
    int c8 = (idx & 31) << 3;
    size_t b = (size_t)n * 1024;
    f16x8 rp = *(const f16x8*)&gates[b + c8];
    f16x8 zp = *(const f16x8*)&gates[b + 256 + c8];
    f16x8 ip = *(const f16x8*)&gates[b + 512 + c8];
    f16x8 hp = *(const f16x8*)&gates[b + 768 + c8];
    f16x8 hv = *(const f16x8*)&AG[(size_t)n * 512 + 256 + c8];
    f16x8 ov;
    #pragma unroll
    for (int q = 0; q < 8; ++q) {
        float r = 1.f / (1.f + expf(-(float)rp[q]));
        float z = 1.f / (1.f + expf(-(float)zp[q]));
        float ng = tanhf((float)ip[q] + r * (float)hp[q]);
        float o = (1.f - z) * ng + z * (float)hv[q];
        ov[q] = (_Float16)o;
    }
    *(f16x8*)&AG[(size_t)n * 512 + 256 + c8] = ov;
}

// ---------------- conv1 as MFMA implicit GEMM (coalesced f16 staging + reg transpose) ----------------
__global__ __launch_bounds__(256, 2) void k_conv1m(const _Float16* __restrict__ hf, const _Float16* __restrict__ xf,
                                                   const _Float16* __restrict__ Wp, const float* __restrict__ bc1,
                                                   float* __restrict__ out, int H, int TBLK) {
    __shared__ _Float16 XT[272 * 64];
    __shared__ _Float16 WL[64 * 192];
    int g = blockIdx.x / TBLK;
    int tb = blockIdx.x - g * TBLK;
    int t0 = tb * 256;
    int tid = threadIdx.x;
    int lane = tid & 63;
    int wn = (tid >> 6) * 64;
    f32x4 acc[4][4] = {};
    for (int ch = 0; ch < 4; ++ch) {
        __syncthreads();
        #pragma unroll
        for (int i = 0; i < 6; ++i) {
            int q = i * 256 + tid;
            int o = q / 24, sk = q - o * 24;
            int skp = (sk & 0x18) | ((sk & 7) ^ (o & 7));
            *(f16x8*)&WL[o * 192 + skp * 8] = *(const f16x8*)&Wp[ch * 12288 + o * 192 + sk * 8];
        }
        for (int u = tid; u < 272; u += 256) {
            int r8 = u / 34, pc = u - r8 * 34;
            int gstart = t0 - 8 + pc * 8;
            int c0 = r8 * 8;
            f16x8 zv;
            #pragma unroll
            for (int q = 0; q < 8; ++q) zv[q] = (_Float16)0.f;
            f16x8 rows[8];
            if (gstart < 0 || gstart >= H) {
                #pragma unroll
                for (int j = 0; j < 8; ++j) rows[j] = zv;
            } else {
                const _Float16* base;
                int stride;
                if (gstart < HID) { base = hf + gstart; stride = 512; }
                else              { base = xf + (gstart - HID); stride = 768; }
                int node0 = g * NPG + ch * 64 + c0;
                #pragma unroll
                for (int j = 0; j < 8; ++j) {
                    int cg = ch * 64 + c0 + j;
                    rows[j] = (cg < NPG) ? *(const f16x8*)&base[(size_t)(node0 + j) * stride] : zv;
                }
            }
            #pragma unroll
            for (int jj = 0; jj < 8; ++jj) {
                f16x8 w;
                #pragma unroll
                for (int j = 0; j < 8; ++j) w[j] = rows[j][jj];
                int p = pc * 8 + jj;
                int slot = r8 ^ jj ^ (pc & 7);
                *(f16x8*)&XT[p * 64 + slot * 8] = w;
            }
        }
        __syncthreads();
        #pragma unroll
        for (int ks = 0; ks < 6; ++ks) {
            int dk = ks >> 1, cs0 = (ks & 1) << 2;
            f16x8 af[4], bf[4];
            #pragma unroll
            for (int mi = 0; mi < 4; ++mi) {
                int o = mi * 16 + (lane & 15);
                int sk = ks * 4 + (lane >> 4);
                int skp = (sk & 0x18) | ((sk & 7) ^ (o & 7));
                af[mi] = *(const f16x8*)&WL[o * 192 + skp * 8];
            }
            #pragma unroll
            for (int nj = 0; nj < 4; ++nj) {
                int tw = wn + nj * 16 + (lane & 15) + dk + 7;
                int sp = (cs0 + (lane >> 4)) ^ (tw & 7) ^ ((tw >> 3) & 7);
                bf[nj] = *(const f16x8*)&XT[tw * 64 + sp * 8];
            }
            #pragma unroll
            for (int mi = 0; mi < 4; ++mi)
                #pragma unroll
                for (int nj = 0; nj < 4; ++nj)
                    acc[mi][nj] = __builtin_amdgcn_mfma_f32_16x16x32_f16(af[mi], bf[nj], acc[mi][nj], 0, 0, 0);
        }
    }
    #pragma unroll
    for (int mi = 0; mi < 4; ++mi) {
        #pragma unroll
        for (int r = 0; r < 4; ++r) {
            int o = mi * 16 + (lane >> 4) * 4 + r;
            if (o < 50) {
                float b = bc1[o];
                #pragma unroll
                for (int nj = 0; nj < 4; ++nj) {
                    int t = t0 + wn + nj * 16 + (lane & 15);
                    float v = acc[mi][nj][r] + b;
                    out[(size_t)g * 50 * H + (size_t)o * H + t] = v > 0.f ? v : 0.f;
                }
            }
        }
    }
}

// ---------------- maxpool1d k=3 s=2 ----------------
__global__ __launch_bounds__(256) void k_pool1(const float* __restrict__ in, float* __restrict__ out,
                                               int H, int U) {
    int g = blockIdx.x, o = blockIdx.y;
    const float* p = in + ((size_t)g * 50 + o) * H;
    float* q = out + ((size_t)g * 50 + o) * U;
    for (int u = threadIdx.x; u < U; u += 256) {
        float a = p[2 * u], b = p[2 * u + 1], c = p[2 * u + 2];
        float mm = a > b ? a : b;
        q[u] = mm > c ? mm : c;
    }
}

// ---------------- conv2 (k=1) + maxpool k=2 s=2 ----------------
__global__ __launch_bounds__(256) void k_c2p2(const float* __restrict__ P1, const float* __restrict__ Wc2,
                                              const float* __restrict__ bc2, float* __restrict__ out,
                                              int U, int U2) {
    int g = blockIdx.x, o2 = blockIdx.y;
    float b = bc2[o2];
    for (int u2 = threadIdx.x; u2 < U2; u2 += 256) {
        float a0 = b, a1 = b;
        #pragma unroll 5
        for (int i = 0; i < 50; ++i) {
            float wv = Wc2[o2 * 50 + i];
            const float* p = P1 + ((size_t)g * 50 + i) * U + 2 * u2;
            a0 = fmaf(p[0], wv, a0);
            a1 = fmaf(p[1], wv, a1);
        }
        out[((size_t)g * 20 + o2) * U2 + u2] = a0 > a1 ? a0 : a1;
    }
}

// ---------------- fully-connected (per-graph dot) ----------------
__global__ __launch_bounds__(256) void k_fc(const float* __restrict__ P2, const float* __restrict__ Wf,
                                            const float* __restrict__ bf, float* __restrict__ out, int len) {
    __shared__ float red[256];
    int g = blockIdx.x, tid = threadIdx.x;
    const float* p = P2 + (size_t)g * len;
    float s = 0.f;
    for (int i = tid; i < len; i += 256) s = fmaf(p[i], Wf[i], s);
    red[tid] = s;
    __syncthreads();
    for (int off = 128; off > 0; off >>= 1) {
        if (tid < off) red[tid] += red[tid + off];
        __syncthreads();
    }
    if (tid == 0) out[g] = red[0] + bf[0];
}

// ---------------- final: sigmoid(z*y) -> clip -> logit -> [0, z1] ----------------
__global__ __launch_bounds__(256) void k_final(const float* __restrict__ z, const float* __restrict__ y,
                                               float* __restrict__ out) {
    int g = threadIdx.x;
    float t = z[g] * y[g];
    float p = 1.f / (1.f + expf(-t));
    p = fminf(fmaxf(p, 1e-6f), 1.f - 1e-6f);
    float z1 = logf(p / (1.f - p));
    out[2 * g] = 0.f;
    out[2 * g + 1] = z1;
}

extern "C" void kernel_launch(void* const* d_in, const int* in_sizes, int n_in,
                              void* d_out, int out_size, void* d_ws, size_t ws_size,
                              hipStream_t stream) {
    const float* x     = (const float*)d_in[0];
    const int*   ei    = (const int*)d_in[1];
    const float* W_in  = (const float*)d_in[2];
    const float* b_in  = (const float*)d_in[3];
    const float* W_g   = (const float*)d_in[4];
    const float* W_ih  = (const float*)d_in[5];
    const float* W_hh  = (const float*)d_in[6];
    const float* b_ih  = (const float*)d_in[7];
    const float* b_hh  = (const float*)d_in[8];
    const float* Wc1   = (const float*)d_in[9];
    const float* bc1   = (const float*)d_in[10];
    const float* Wc2   = (const float*)d_in[11];
    const float* bc2   = (const float*)d_in[12];
    const float* Wf1   = (const float*)d_in[13];
    const float* bf1   = (const float*)d_in[14];
    const float* Wf2   = (const float*)d_in[15];
    const float* bf2   = (const float*)d_in[16];

    float* ws = (float*)d_ws;
    // layout (float units). XF is [N,768] f16 = 39,321,600 f16 = 19,660,800 FLOATS (round-8 bug:
    // was sized 9.83M floats, overlapping weights/ints — everything now placed past its true end).
    const size_t OFF_AG    = 0;          // AG f16 [N,512] (S|h)   -> 13,107,200
    const size_t OFF_GATES = 13107200;   // gates f16 [N,1024]     -> 39,321,600
    const size_t OFF_XF    = 39321600;   // XF f16 [N,768] = 19,660,800 fl -> 58,982,400
    const size_t OFF_WF    = 58982400;   // f16 weight arena (3,391,488 f16 = 1,695,744 fl) -> 60,678,144
    const size_t OFF_BRZ   = 60678144;   // brz [512] -> 60,678,656
    const size_t OFF_BNN   = 60678656;   // bnn [512] -> 60,679,168
    const size_t OFF_INT   = 60679168;   // ints (563,201) -> 61,242,369
    const size_t OFF_ZB    = 61242400;   // zb/yb (512)
    const size_t OFF_P2Z   = 61250000;   // P2Z (1,305,600) -> 62,555,600
    const size_t OFF_P2Y   = 62600000;   // P2Y (322,560)   -> 62,922,560

    _Float16* AG      = (_Float16*)(ws + OFF_AG);
    _Float16* gates16 = (_Float16*)(ws + OFF_GATES);
    _Float16* XF      = (_Float16*)(ws + OFF_XF);

    _Float16* Win_h = (_Float16*)(ws + OFF_WF);  // [256][768] = 196,608
    _Float16* Wih_h = Win_h + 196608;            // [768][256]
    _Float16* Whh_h = Wih_h + 196608;            // [768][256]
    _Float16* Wg_h  = Whh_h + 196608;            // [6][256][256] = 393,216
    _Float16* Wrz2  = Wg_h  + 393216;            // [6][512][512] = 1,572,864
    _Float16* Wnn   = Wrz2  + 1572864;           // [6][2][256][256] = 786,432
    _Float16* Wp    = Wnn   + 786432;            // [4][64][192] = 49,152
    float* brz = ws + OFF_BRZ;
    float* bnn = ws + OFF_BNN;

    int* deg  = (int*)(ws + OFF_INT);
    int* fill = deg + N_NODES;
    int* rowp = fill + N_NODES;
    int* col  = rowp + (N_NODES + 1);
    float* zb = ws + OFF_ZB;
    float* yb = zb + 256;

    // conv-phase scratch inside the dead gates region (AG h-half at 0..13.1M and XF at 39.3M+ stay live)
    float* C1Z = ws + OFF_GATES;              // 13,107,200 fl -> abs 26,214,400
    float* P1Z = ws + OFF_GATES + 13200000;   // 6,540,800  -> abs 32,848,000
    float* C1Y = ws + OFF_GATES + 20000000;   // 3,276,800  -> abs 36,384,000
    float* P1Y = ws + OFF_GATES + 23400000;   // 1,625,600  -> abs 38,132,800 (< OFF_XF)
    float* P2Z = ws + OFF_P2Z;
    float* P2Y = ws + OFF_P2Y;

    // ---- weight prep ----
    k_cvt<<<192, 256, 0, stream>>>(W_in, Win_h, 49152);
    k_cvt<<<192, 256, 0, stream>>>(W_ih, Wih_h, 49152);
    k_cvt<<<192, 256, 0, stream>>>(W_hh, Whh_h, 49152);
    k_cvt<<<384, 256, 0, stream>>>(W_g, Wg_h, 98304);
    k_cvt<<<38400, 256, 0, stream>>>(x, XF, 9830400);     // XF = fp16 copy of x
    k_bias<<<2, 256, 0, stream>>>(b_ih, b_hh, brz);
    k_bnn<<<2, 256, 0, stream>>>(b_ih, b_hh, bnn);
    k_wpack<<<192, 256, 0, stream>>>(Wc1, Wp);
    // fold Wg: Wrz2[l][:, :256] = Wih[0:512] @ Wg[l]^T ; Wnn[l][0] = Wih[512:768] @ Wg[l]^T
    k_gemm2<1, 1, 2, 0><<<48, 256, 0, stream>>>(Wih_h, 256, Wg_h, nullptr,
                                                Wrz2, 512, nullptr, 0, 256, 8, 0, 65536, 262144, 0);
    k_gemm2<1, 1, 2, 0><<<24, 256, 0, stream>>>(Wih_h + 512 * 256, 256, Wg_h, nullptr,
                                                Wnn, 256, nullptr, 0, 256, 4, 0, 65536, 131072, 0);
    k_wcopyrz<<<3072, 256, 0, stream>>>(Whh_h, Wrz2);
    k_wcopynn<<<1536, 256, 0, stream>>>(Whh_h, Wnn);

    // ---- CSR build ----
    hipMemsetAsync(deg, 0, N_NODES * sizeof(int), stream);
    hipMemsetAsync(fill, 0, N_NODES * sizeof(int), stream);
    k_deg<<<N_EDGES / 256, 256, 0, stream>>>(ei, deg);
    k_scan<<<1, 1024, 0, stream>>>(deg, rowp);
    k_fill<<<N_EDGES / 256, 256, 0, stream>>>(ei, rowp, fill, col);

    // ---- h0 = x @ W_in^T + b_in -> AG h-half (f16) ----
    k_gemm2<0, 1, 2, 1><<<800, 256, 0, stream>>>(x, FEAT, Win_h, b_in, AG + 256, 512,
                                                 nullptr, 0, FEAT, 800, 0, 0, 0, 0);

    // ---- GGNN layers ----
    for (int l = 0; l < 6; ++l) {
        k_agg4<<<12800, 256, 0, stream>>>(rowp, col, AG);
        k_gemm2<1, 1, 4, 1><<<1600, 256, 0, stream>>>(AG, 512, Wrz2 + (size_t)l * 262144, brz,
                                                      gates16, 1024, nullptr, 0, 512, 1600, 0, 0, 0, 0);
        // batched i_n (sub 0: A=S, B=Wnn[l][0]) and h_n (sub 1: A=h, B=Wnn[l][1])
        k_gemm2<1, 1, 2, 1><<<1600, 256, 0, stream>>>(AG, 512, Wnn + (size_t)l * 131072, bnn,
                                                      gates16 + 512, 1024, nullptr, 0, 256,
                                                      800, 256, 65536, 256, 256);
        k_gru4<<<6400, 256, 0, stream>>>(gates16, AG);
    }

    // ---- conv head: Z path (concat [h|x], H=1024) ----
    k_conv1m<<<1024, 256, 0, stream>>>(AG + 256, XF, Wp, bc1, C1Z, 1024, 4);
    k_pool1<<<dim3(G_GRAPHS, 50), 256, 0, stream>>>(C1Z, P1Z, 1024, 511);
    k_c2p2<<<dim3(G_GRAPHS, 20), 256, 0, stream>>>(P1Z, Wc2, bc2, P2Z, 511, 255);
    k_fc<<<G_GRAPHS, 256, 0, stream>>>(P2Z, Wf1, bf1, zb, 20 * 255);

    // ---- conv head: Y path (h only, H=256) ----
    k_conv1m<<<256, 256, 0, stream>>>(AG + 256, XF, Wp, bc1, C1Y, 256, 1);
    k_pool1<<<dim3(G_GRAPHS, 50), 256, 0, stream>>>(C1Y, P1Y, 256, 127);
    k_c2p2<<<dim3(G_GRAPHS, 20), 256, 0, stream>>>(P1Y, Wc2, bc2, P2Y, 127, 63);
    k_fc<<<G_GRAPHS, 256, 0, stream>>>(P2Y, Wf2, bf2, yb, 20 * 63);

    // ---- final ----
    k_final<<<1, 256, 0, stream>>>(zb, yb, (float*)d_out);
}

// Round 10
// 1212.835 us; speedup vs baseline: 7.9127x; 1.0087x over previous
//
#include <hip/hip_runtime.h>
#include <math.h>

#define N_NODES 51200
#define N_EDGES 409600
#define FEAT    768
#define HID     256
#define NPG     200
#define G_GRAPHS 256

typedef _Float16 f16x8 __attribute__((ext_vector_type(8)));
typedef _Float16 f16x4 __attribute__((ext_vector_type(4)));
typedef float    f32x4 __attribute__((ext_vector_type(4)));

// ---------------- CSR build ----------------
__global__ __launch_bounds__(256) void k_deg(const int* __restrict__ ei, int* __restrict__ deg) {
    int e = blockIdx.x * 256 + threadIdx.x;
    if (e < N_EDGES) atomicAdd(&deg[ei[N_EDGES + e]], 1);
}

__global__ __launch_bounds__(1024) void k_scan(const int* __restrict__ deg, int* __restrict__ rowp) {
    __shared__ int sums[1024];
    int tid = threadIdx.x;
    int base = tid * 50;
    int s = 0;
    for (int j = 0; j < 50; ++j) s += deg[base + j];
    sums[tid] = s;
    __syncthreads();
    for (int off = 1; off < 1024; off <<= 1) {
        int v = 0;
        if (tid >= off) v = sums[tid - off];
        __syncthreads();
        sums[tid] += v;
        __syncthreads();
    }
    int run = sums[tid] - s; // exclusive prefix
    for (int j = 0; j < 50; ++j) { rowp[base + j] = run; run += deg[base + j]; }
    if (tid == 1023) rowp[N_NODES] = run;
}

__global__ __launch_bounds__(256) void k_fill(const int* __restrict__ ei, const int* __restrict__ rowp,
                                              int* __restrict__ fill, int* __restrict__ col) {
    int e = blockIdx.x * 256 + threadIdx.x;
    if (e < N_EDGES) {
        int d = ei[N_EDGES + e];
        int pos = atomicAdd(&fill[d], 1);
        col[rowp[d] + pos] = ei[e];
    }
}

// ---------------- weight prep ----------------
__global__ __launch_bounds__(256) void k_cvt(const float* __restrict__ in, _Float16* __restrict__ out, int n4) {
    int i = blockIdx.x * 256 + threadIdx.x;
    if (i < n4) {
        float4 v = *(const float4*)&in[i * 4];
        f16x4 h;
        h[0] = (_Float16)v.x; h[1] = (_Float16)v.y; h[2] = (_Float16)v.z; h[3] = (_Float16)v.w;
        *(f16x4*)&out[i * 4] = h;
    }
}

__global__ __launch_bounds__(256) void k_bias(const float* __restrict__ bih, const float* __restrict__ bhh,
                                              float* __restrict__ brz) {
    int i = blockIdx.x * 256 + threadIdx.x;
    if (i < 512) brz[i] = bih[i] + bhh[i];
}

// bnn: [b_ih[512:768] | b_hh[512:768]]
__global__ __launch_bounds__(256) void k_bnn(const float* __restrict__ bih, const float* __restrict__ bhh,
                                             float* __restrict__ bnn) {
    int i = blockIdx.x * 256 + threadIdx.x;
    if (i < 512) bnn[i] = (i < 256) ? bih[512 + i] : bhh[512 + (i - 256)];
}

// conv1 weight pack: Wp[ch][o][dk*64+cc] = Wc1[o][ch*64+cc][dk], zero-padded (o<64, 4*64 ch)
__global__ __launch_bounds__(256) void k_wpack(const float* __restrict__ Wc1, _Float16* __restrict__ Wp) {
    int id = blockIdx.x * 256 + threadIdx.x;   // < 4*64*192 = 49152
    int ch = id / 12288, r = id - ch * 12288;
    int o = r / 192, k = r - o * 192;
    int dk = k >> 6, cc = k & 63;
    int c = ch * 64 + cc;
    float v = 0.f;
    if (o < 50 && c < NPG) v = Wc1[(o * NPG + c) * 3 + dk];
    Wp[id] = (_Float16)v;
}

// Wrz2 right halves: Wrz2[l][j][256+c] = Whh[j][c]  (j<512, c<256, all 6 layers)
__global__ __launch_bounds__(256) void k_wcopyrz(const _Float16* __restrict__ Whh, _Float16* __restrict__ Wrz2) {
    int id = blockIdx.x * 256 + threadIdx.x;   // < 6*512*256 = 786432
    int l = id >> 17, r = id & 131071;
    int j = r >> 8, c = r & 255;
    Wrz2[(size_t)l * 262144 + j * 512 + 256 + c] = Whh[j * 256 + c];
}

// ---------------- fp16 MFMA GEMM (NT): C[M,*] = A[M,K] @ B_f16[J,K]^T + bias ----------------
// 128x128 tile, BK=64, 4 waves (2x2), 16x16x32_f16, fp32 acc. XOR-swizzled LDS.
// AF16: A fp16 (else fp32 converted). OUT: 0=f32, 1=f16. SWZ: XCD decode. Batched via wgPerL.
template<int AF16, int OUT, int COLB, int SWZ>
__global__ __launch_bounds__(256) void k_gemm2(const void* __restrict__ Av, int lda,
                                               const _Float16* __restrict__ B,
                                               const float* __restrict__ bias,
                                               void* __restrict__ Cv, int ldc,
                                               int K, int wgPerL, int aLStride, int bLStride,
                                               int cLStride, int biasStride) {
    __shared__ _Float16 As[128 * 64];
    __shared__ _Float16 Bs[128 * 64];
    int wg = blockIdx.x;
    int l = wg / wgPerL; wg -= l * wgPerL;
    if (AF16) Av = (const void*)((const _Float16*)Av + (size_t)l * aLStride);
    else      Av = (const void*)((const float*)Av + (size_t)l * aLStride);
    B += (size_t)l * bLStride;
    if (bias) bias += (size_t)l * biasStride;
    if (OUT == 1) Cv = (void*)((_Float16*)Cv + (size_t)l * cLStride);
    else          Cv = (void*)((float*)Cv + (size_t)l * cLStride);
    int rowBase, colBase;
    if (SWZ) {
        int xcd = wg & 7, t = wg >> 3;
        int cb = t % COLB, gidx = t / COLB;
        rowBase = (gidx * 8 + xcd) * 128;
        colBase = cb * 128;
    } else {
        rowBase = (wg / COLB) * 128;
        colBase = (wg % COLB) * 128;
    }
    int tid = threadIdx.x;
    int lane = tid & 63;
    int wid = tid >> 6;
    int wr = wid >> 1, wc = wid & 1;
    f32x4 acc[4][4] = {};
    for (int k0 = 0; k0 < K; k0 += 64) {
        __syncthreads();
        #pragma unroll
        for (int p = 0; p < 4; ++p) {
            int c = p * 256 + tid;
            int row = c >> 3, slot = c & 7;
            int dst = row * 64 + ((slot ^ (row & 7)) * 8);
            if (AF16) {
                const _Float16* srcA = (const _Float16*)Av + (size_t)(rowBase + row) * lda + k0 + slot * 8;
                *(f16x8*)&As[dst] = *(const f16x8*)srcA;
            } else {
                const float* srcA = (const float*)Av + (size_t)(rowBase + row) * lda + k0 + slot * 8;
                float4 f0 = *(const float4*)srcA;
                float4 f1 = *(const float4*)(srcA + 4);
                f16x8 hv;
                hv[0] = (_Float16)f0.x; hv[1] = (_Float16)f0.y; hv[2] = (_Float16)f0.z; hv[3] = (_Float16)f0.w;
                hv[4] = (_Float16)f1.x; hv[5] = (_Float16)f1.y; hv[6] = (_Float16)f1.z; hv[7] = (_Float16)f1.w;
                *(f16x8*)&As[dst] = hv;
            }
            const _Float16* srcB = B + (size_t)(colBase + row) * K + k0 + slot * 8;
            *(f16x8*)&Bs[dst] = *(const f16x8*)srcB;
        }
        __syncthreads();
        #pragma unroll
        for (int ks = 0; ks < 2; ++ks) {
            f16x8 af[4], bf[4];
            #pragma unroll
            for (int mi = 0; mi < 4; ++mi) {
                int row = wr * 64 + mi * 16 + (lane & 15);
                int slot = (lane >> 4) + ks * 4;
                af[mi] = *(const f16x8*)&As[row * 64 + ((slot ^ (row & 7)) * 8)];
            }
            #pragma unroll
            for (int nj = 0; nj < 4; ++nj) {
                int row = wc * 64 + nj * 16 + (lane & 15);
                int slot = (lane >> 4) + ks * 4;
                bf[nj] = *(const f16x8*)&Bs[row * 64 + ((slot ^ (row & 7)) * 8)];
            }
            #pragma unroll
            for (int mi = 0; mi < 4; ++mi)
                #pragma unroll
                for (int nj = 0; nj < 4; ++nj)
                    acc[mi][nj] = __builtin_amdgcn_mfma_f32_16x16x32_f16(af[mi], bf[nj], acc[mi][nj], 0, 0, 0);
        }
    }
    #pragma unroll
    for (int mi = 0; mi < 4; ++mi) {
        #pragma unroll
        for (int nj = 0; nj < 4; ++nj) {
            int col = colBase + wc * 64 + nj * 16 + (lane & 15);
            float bv = bias ? bias[col] : 0.f;
            #pragma unroll
            for (int r = 0; r < 4; ++r) {
                int row = rowBase + wr * 64 + mi * 16 + (lane >> 4) * 4 + r;
                float val = acc[mi][nj][r] + bv;
                if (OUT == 0) ((float*)Cv)[(size_t)row * ldc + col] = val;
                else          ((_Float16*)Cv)[(size_t)row * ldc + col] = (_Float16)val;
            }
        }
    }
}

// ---------------- rz GEMM: RZ[N,512] = [S|hc] @ Wrz2_l^T + brz (K=512, dual-A) ----------------
__global__ __launch_bounds__(256) void k_gemmrz(const _Float16* __restrict__ S, const _Float16* __restrict__ hc,
                                                const _Float16* __restrict__ B, const float* __restrict__ bias,
                                                _Float16* __restrict__ C) {
    __shared__ _Float16 As[128 * 64];
    __shared__ _Float16 Bs[128 * 64];
    int wg = blockIdx.x;                 // 1600 = 8 * 4 * 50
    int xcd = wg & 7, t = wg >> 3;
    int cb = t % 4, gidx = t / 4;
    int rowBase = (gidx * 8 + xcd) * 128;
    int colBase = cb * 128;
    int tid = threadIdx.x;
    int lane = tid & 63;
    int wid = tid >> 6;
    int wr = wid >> 1, wc = wid & 1;
    f32x4 acc[4][4] = {};
    for (int k0 = 0; k0 < 512; k0 += 64) {
        const _Float16* Abase = (k0 < 256) ? S : hc;
        int kk = k0 & 255;
        __syncthreads();
        #pragma unroll
        for (int p = 0; p < 4; ++p) {
            int c = p * 256 + tid;
            int row = c >> 3, slot = c & 7;
            int dst = row * 64 + ((slot ^ (row & 7)) * 8);
            *(f16x8*)&As[dst] = *(const f16x8*)&Abase[(size_t)(rowBase + row) * 256 + kk + slot * 8];
            *(f16x8*)&Bs[dst] = *(const f16x8*)&B[(size_t)(colBase + row) * 512 + k0 + slot * 8];
        }
        __syncthreads();
        #pragma unroll
        for (int ks = 0; ks < 2; ++ks) {
            f16x8 af[4], bf[4];
            #pragma unroll
            for (int mi = 0; mi < 4; ++mi) {
                int row = wr * 64 + mi * 16 + (lane & 15);
                int slot = (lane >> 4) + ks * 4;
                af[mi] = *(const f16x8*)&As[row * 64 + ((slot ^ (row & 7)) * 8)];
            }
            #pragma unroll
            for (int nj = 0; nj < 4; ++nj) {
                int row = wc * 64 + nj * 16 + (lane & 15);
                int slot = (lane >> 4) + ks * 4;
                bf[nj] = *(const f16x8*)&Bs[row * 64 + ((slot ^ (row & 7)) * 8)];
            }
            #pragma unroll
            for (int mi = 0; mi < 4; ++mi)
                #pragma unroll
                for (int nj = 0; nj < 4; ++nj)
                    acc[mi][nj] = __builtin_amdgcn_mfma_f32_16x16x32_f16(af[mi], bf[nj], acc[mi][nj], 0, 0, 0);
        }
    }
    #pragma unroll
    for (int mi = 0; mi < 4; ++mi) {
        #pragma unroll
        for (int nj = 0; nj < 4; ++nj) {
            int col = colBase + wc * 64 + nj * 16 + (lane & 15);
            float bv = bias[col];
            #pragma unroll
            for (int r = 0; r < 4; ++r) {
                int row = rowBase + wr * 64 + mi * 16 + (lane >> 4) * 4 + r;
                C[(size_t)row * 512 + col] = (_Float16)(acc[mi][nj][r] + bv);
            }
        }
    }
}

// ---------------- fused n-gate GEMMs + GRU: hn = (1-z)*tanh(i_n + r*h_n) + z*hc ----------------
// Dual GEMM (acc_i = S@B0^T, acc_h = hc@B1^T, K=256, J=256), 512 thr (8 waves, 2x4),
// epilogue reads RZ pre-activations + hc, writes hn. No race: hn != hc (ping-pong).
__global__ __launch_bounds__(512) void k_nngru(const _Float16* __restrict__ S, const _Float16* __restrict__ hc,
                                               const _Float16* __restrict__ B0, const _Float16* __restrict__ B1,
                                               const float* __restrict__ bnn, const _Float16* __restrict__ rz,
                                               _Float16* __restrict__ hn) {
    __shared__ _Float16 As0[128 * 64], As1[128 * 64], Bs0[128 * 64], Bs1[128 * 64];
    int wg = blockIdx.x;                 // 800 = 8 * 2 * 50
    int xcd = wg & 7, t = wg >> 3;
    int cb = t % 2, gidx = t / 2;
    int rowBase = (gidx * 8 + xcd) * 128;
    int colBase = cb * 128;
    int tid = threadIdx.x;
    int lane = tid & 63;
    int wid = tid >> 6;                  // 0..7
    int wr = wid >> 2, wc = wid & 3;     // 2 x 4 waves; wave tile 64 rows x 32 cols
    f32x4 acc0[4][2] = {}, acc1[4][2] = {};
    for (int k0 = 0; k0 < 256; k0 += 64) {
        __syncthreads();
        #pragma unroll
        for (int p = 0; p < 8; ++p) {
            int q = p * 512 + tid;       // 0..4095 (4 tiles x 1024 chunks)
            int tile = q >> 10;
            int c = q & 1023;
            int row = c >> 3, slot = c & 7;
            int dst = row * 64 + ((slot ^ (row & 7)) * 8);
            const _Float16* src;
            _Float16* d;
            if (tile == 0)      { src = S  + (size_t)(rowBase + row) * 256 + k0 + slot * 8; d = As0; }
            else if (tile == 1) { src = hc + (size_t)(rowBase + row) * 256 + k0 + slot * 8; d = As1; }
            else if (tile == 2) { src = B0 + (size_t)(colBase + row) * 256 + k0 + slot * 8; d = Bs0; }
            else                { src = B1 + (size_t)(colBase + row) * 256 + k0 + slot * 8; d = Bs1; }
            *(f16x8*)&d[dst] = *(const f16x8*)src;
        }
        __syncthreads();
        #pragma unroll
        for (int ks = 0; ks < 2; ++ks) {
            f16x8 a0[4], a1[4], b0[2], b1[2];
            #pragma unroll
            for (int mi = 0; mi < 4; ++mi) {
                int row = wr * 64 + mi * 16 + (lane & 15);
                int slot = (lane >> 4) + ks * 4;
                int off = row * 64 + ((slot ^ (row & 7)) * 8);
                a0[mi] = *(const f16x8*)&As0[off];
                a1[mi] = *(const f16x8*)&As1[off];
            }
            #pragma unroll
            for (int nj = 0; nj < 2; ++nj) {
                int row = wc * 32 + nj * 16 + (lane & 15);
                int slot = (lane >> 4) + ks * 4;
                int off = row * 64 + ((slot ^ (row & 7)) * 8);
                b0[nj] = *(const f16x8*)&Bs0[off];
                b1[nj] = *(const f16x8*)&Bs1[off];
            }
            #pragma unroll
            for (int mi = 0; mi < 4; ++mi)
                #pragma unroll
                for (int nj = 0; nj < 2; ++nj) {
                    acc0[mi][nj] = __builtin_amdgcn_mfma_f32_16x16x32_f16(a0[mi], b0[nj], acc0[mi][nj], 0, 0, 0);
                    acc1[mi][nj] = __builtin_amdgcn_mfma_f32_16x16x32_f16(a1[mi], b1[nj], acc1[mi][nj], 0, 0, 0);
                }
        }
    }
    #pragma unroll
    for (int mi = 0; mi < 4; ++mi) {
        #pragma unroll
        for (int nj = 0; nj < 2; ++nj) {
            int col = colBase + wc * 32 + nj * 16 + (lane & 15);
            float bi = bnn[col], bh = bnn[256 + col];
            #pragma unroll
            for (int r = 0; r < 4; ++r) {
                int row = rowBase + wr * 64 + mi * 16 + (lane >> 4) * 4 + r;
                float rv = (float)rz[(size_t)row * 512 + col];
                float zv = (float)rz[(size_t)row * 512 + 256 + col];
                float rg = 1.f / (1.f + expf(-rv));
                float zg = 1.f / (1.f + expf(-zv));
                float ng = tanhf((acc0[mi][nj][r] + bi) + rg * (acc1[mi][nj][r] + bh));
                float ho = (float)hc[(size_t)row * 256 + col];
                hn[(size_t)row * 256 + col] = (_Float16)((1.f - zg) * ng + zg * ho);
            }
        }
    }
}

// ---------------- gather-sum of hc into S (wave-per-node, b64 loads) ----------------
__global__ __launch_bounds__(256) void k_agg4(const int* __restrict__ rowp, const int* __restrict__ col,
                                              const _Float16* __restrict__ hc, _Float16* __restrict__ S) {
    int v = blockIdx.x * 4 + (threadIdx.x >> 6);
    int lane = threadIdx.x & 63;
    int beg = rowp[v], end = rowp[v + 1];
    const _Float16* hf = hc + lane * 4;
    float a0 = 0.f, a1 = 0.f, a2 = 0.f, a3 = 0.f;
    int i = beg;
    for (; i + 1 < end; i += 2) {
        f16x4 u = *(const f16x4*)&hf[(size_t)col[i] * 256];
        f16x4 w = *(const f16x4*)&hf[(size_t)col[i + 1] * 256];
        a0 += (float)u[0] + (float)w[0];
        a1 += (float)u[1] + (float)w[1];
        a2 += (float)u[2] + (float)w[2];
        a3 += (float)u[3] + (float)w[3];
    }
    if (i < end) {
        f16x4 u = *(const f16x4*)&hf[(size_t)col[i] * 256];
        a0 += (float)u[0]; a1 += (float)u[1]; a2 += (float)u[2]; a3 += (float)u[3];
    }
    f16x4 o;
    o[0] = (_Float16)a0; o[1] = (_Float16)a1; o[2] = (_Float16)a2; o[3] = (_Float16)a3;
    *(f16x4*)&S[(size_t)v * 256 + lane * 4] = o;
}

// ---------------- conv1 as MFMA implicit GEMM (hf stride 256) ----------------
__global__ __launch_bounds__(256, 2) void k_conv1m(const _Float16* __restrict__ hf, const _Float16* __restrict__ xf,
                                                   const _Float16* __restrict__ Wp, const float* __restrict__ bc1,
                                                   float* __restrict__ out, int H, int TBLK) {
    __shared__ _Float16 XT[272 * 64];
    __shared__ _Float16 WL[64 * 192];
    int g = blockIdx.x / TBLK;
    int tb = blockIdx.x - g * TBLK;
    int t0 = tb * 256;
    int tid = threadIdx.x;
    int lane = tid & 63;
    int wn = (tid >> 6) * 64;
    f32x4 acc[4][4] = {};
    for (int ch = 0; ch < 4; ++ch) {
        __syncthreads();
        #pragma unroll
        for (int i = 0; i < 6; ++i) {
            int q = i * 256 + tid;
            int o = q / 24, sk = q - o * 24;
            int skp = (sk & 0x18) | ((sk & 7) ^ (o & 7));
            *(f16x8*)&WL[o * 192 + skp * 8] = *(const f16x8*)&Wp[ch * 12288 + o * 192 + sk * 8];
        }
        for (int u = tid; u < 272; u += 256) {
            int r8 = u / 34, pc = u - r8 * 34;
            int gstart = t0 - 8 + pc * 8;
            int c0 = r8 * 8;
            f16x8 zv;
            #pragma unroll
            for (int q = 0; q < 8; ++q) zv[q] = (_Float16)0.f;
            f16x8 rows[8];
            if (gstart < 0 || gstart >= H) {
                #pragma unroll
                for (int j = 0; j < 8; ++j) rows[j] = zv;
            } else {
                const _Float16* base;
                int stride;
                if (gstart < HID) { base = hf + gstart; stride = 256; }
                else              { base = xf + (gstart - HID); stride = 768; }
                int node0 = g * NPG + ch * 64 + c0;
                #pragma unroll
                for (int j = 0; j < 8; ++j) {
                    int cg = ch * 64 + c0 + j;
                    rows[j] = (cg < NPG) ? *(const f16x8*)&base[(size_t)(node0 + j) * stride] : zv;
                }
            }
            #pragma unroll
            for (int jj = 0; jj < 8; ++jj) {
                f16x8 w;
                #pragma unroll
                for (int j = 0; j < 8; ++j) w[j] = rows[j][jj];
                int p = pc * 8 + jj;
                int slot = r8 ^ jj ^ (pc & 7);
                *(f16x8*)&XT[p * 64 + slot * 8] = w;
            }
        }
        __syncthreads();
        #pragma unroll
        for (int ks = 0; ks < 6; ++ks) {
            int dk = ks >> 1, cs0 = (ks & 1) << 2;
            f16x8 af[4], bf[4];
            #pragma unroll
            for (int mi = 0; mi < 4; ++mi) {
                int o = mi * 16 + (lane & 15);
                int sk = ks * 4 + (lane >> 4);
                int skp = (sk & 0x18) | ((sk & 7) ^ (o & 7));
                af[mi] = *(const f16x8*)&WL[o * 192 + skp * 8];
            }
            #pragma unroll
            for (int nj = 0; nj < 4; ++nj) {
                int tw = wn + nj * 16 + (lane & 15) + dk + 7;
                int sp = (cs0 + (lane >> 4)) ^ (tw & 7) ^ ((tw >> 3) & 7);
                bf[nj] = *(const f16x8*)&XT[tw * 64 + sp * 8];
            }
            #pragma unroll
            for (int mi = 0; mi < 4; ++mi)
                #pragma unroll
                for (int nj = 0; nj < 4; ++nj)
                    acc[mi][nj] = __builtin_amdgcn_mfma_f32_16x16x32_f16(af[mi], bf[nj], acc[mi][nj], 0, 0, 0);
        }
    }
    #pragma unroll
    for (int mi = 0; mi < 4; ++mi) {
        #pragma unroll
        for (int r = 0; r < 4; ++r) {
            int o = mi * 16 + (lane >> 4) * 4 + r;
            if (o < 50) {
                float b = bc1[o];
                #pragma unroll
                for (int nj = 0; nj < 4; ++nj) {
                    int t = t0 + wn + nj * 16 + (lane & 15);
                    float v = acc[mi][nj][r] + b;
                    out[(size_t)g * 50 * H + (size_t)o * H + t] = v > 0.f ? v : 0.f;
                }
            }
        }
    }
}

// ---------------- maxpool1d k=3 s=2 ----------------
__global__ __launch_bounds__(256) void k_pool1(const float* __restrict__ in, float* __restrict__ out,
                                               int H, int U) {
    int g = blockIdx.x, o = blockIdx.y;
    const float* p = in + ((size_t)g * 50 + o) * H;
    float* q = out + ((size_t)g * 50 + o) * U;
    for (int u = threadIdx.x; u < U; u += 256) {
        float a = p[2 * u], b = p[2 * u + 1], c = p[2 * u + 2];
        float mm = a > b ? a : b;
        q[u] = mm > c ? mm : c;
    }
}

// ---------------- conv2 (k=1) + maxpool k=2 s=2 ----------------
__global__ __launch_bounds__(256) void k_c2p2(const float* __restrict__ P1, const float* __restrict__ Wc2,
                                              const float* __restrict__ bc2, float* __restrict__ out,
                                              int U, int U2) {
    int g = blockIdx.x, o2 = blockIdx.y;
    float b = bc2[o2];
    for (int u2 = threadIdx.x; u2 < U2; u2 += 256) {
        float a0 = b, a1 = b;
        #pragma unroll 5
        for (int i = 0; i < 50; ++i) {
            float wv = Wc2[o2 * 50 + i];
            const float* p = P1 + ((size_t)g * 50 + i) * U + 2 * u2;
            a0 = fmaf(p[0], wv, a0);
            a1 = fmaf(p[1], wv, a1);
        }
        out[((size_t)g * 20 + o2) * U2 + u2] = a0 > a1 ? a0 : a1;
    }
}

// ---------------- fully-connected (per-graph dot) ----------------
__global__ __launch_bounds__(256) void k_fc(const float* __restrict__ P2, const float* __restrict__ Wf,
                                            const float* __restrict__ bf, float* __restrict__ out, int len) {
    __shared__ float red[256];
    int g = blockIdx.x, tid = threadIdx.x;
    const float* p = P2 + (size_t)g * len;
    float s = 0.f;
    for (int i = tid; i < len; i += 256) s = fmaf(p[i], Wf[i], s);
    red[tid] = s;
    __syncthreads();
    for (int off = 128; off > 0; off >>= 1) {
        if (tid < off) red[tid] += red[tid + off];
        __syncthreads();
    }
    if (tid == 0) out[g] = red[0] + bf[0];
}

// ---------------- final: sigmoid(z*y) -> clip -> logit -> [0, z1] ----------------
__global__ __launch_bounds__(256) void k_final(const float* __restrict__ z, const float* __restrict__ y,
                                               float* __restrict__ out) {
    int g = threadIdx.x;
    float t = z[g] * y[g];
    float p = 1.f / (1.f + expf(-t));
    p = fminf(fmaxf(p, 1e-6f), 1.f - 1e-6f);
    float z1 = logf(p / (1.f - p));
    out[2 * g] = 0.f;
    out[2 * g + 1] = z1;
}

extern "C" void kernel_launch(void* const* d_in, const int* in_sizes, int n_in,
                              void* d_out, int out_size, void* d_ws, size_t ws_size,
                              hipStream_t stream) {
    const float* x     = (const float*)d_in[0];
    const int*   ei    = (const int*)d_in[1];
    const float* W_in  = (const float*)d_in[2];
    const float* b_in  = (const float*)d_in[3];
    const float* W_g   = (const float*)d_in[4];
    const float* W_ih  = (const float*)d_in[5];
    const float* W_hh  = (const float*)d_in[6];
    const float* b_ih  = (const float*)d_in[7];
    const float* b_hh  = (const float*)d_in[8];
    const float* Wc1   = (const float*)d_in[9];
    const float* bc1   = (const float*)d_in[10];
    const float* Wc2   = (const float*)d_in[11];
    const float* bc2   = (const float*)d_in[12];
    const float* Wf1   = (const float*)d_in[13];
    const float* bf1   = (const float*)d_in[14];
    const float* Wf2   = (const float*)d_in[15];
    const float* bf2   = (const float*)d_in[16];

    float* ws = (float*)d_ws;
    // layout (float units), every region's end verified:
    const size_t OFF_S   = 0;           // S  f16 [N,256] = 6,553,600 fl -> 6,553,600
    const size_t OFF_HA  = 6553600;     // HA f16 [N,256] -> 13,107,200
    const size_t OFF_HB  = 13107200;    // HB f16 [N,256] -> 19,660,800
    const size_t OFF_RZ  = 19660800;    // RZ f16 [N,512] = 13,107,200 fl -> 32,768,000
    const size_t OFF_XF  = 32768000;    // XF f16 [N,768] = 19,660,800 fl -> 52,428,800
    const size_t OFF_WF  = 52428800;    // f16 arena 2,998,272 f16 = 1,499,136 fl -> 53,927,936
    const size_t OFF_BRZ = 53927936;    // [512] -> 53,928,448
    const size_t OFF_BNN = 53928448;    // [512] -> 53,928,960
    const size_t OFF_INT = 53928960;    // ints 563,201 -> 54,492,161
    const size_t OFF_ZB  = 54492200;    // [512] -> 54,492,712
    const size_t OFF_P2Z = 54500000;    // 1,305,600 -> 55,805,600
    const size_t OFF_P2Y = 55900000;    // 322,560  -> 56,222,560

    _Float16* S  = (_Float16*)(ws + OFF_S);
    _Float16* HA = (_Float16*)(ws + OFF_HA);
    _Float16* HB = (_Float16*)(ws + OFF_HB);
    _Float16* RZ = (_Float16*)(ws + OFF_RZ);
    _Float16* XF = (_Float16*)(ws + OFF_XF);

    _Float16* Win_h = (_Float16*)(ws + OFF_WF);  // [256][768] = 196,608
    _Float16* Wih_h = Win_h + 196608;            // [768][256]
    _Float16* Whh_h = Wih_h + 196608;            // [768][256]
    _Float16* Wg_h  = Whh_h + 196608;            // [6][256][256] = 393,216
    _Float16* Wrz2  = Wg_h  + 393216;            // [6][512][512] = 1,572,864
    _Float16* Wni2  = Wrz2  + 1572864;           // [6][256][256] = 393,216
    _Float16* Wp    = Wni2  + 393216;            // [4][64][192] = 49,152  (sum 2,998,272)
    _Float16* Whhn  = Whh_h + 512 * 256;         // Whh rows 512..767
    float* brz = ws + OFF_BRZ;
    float* bnn = ws + OFF_BNN;

    int* deg  = (int*)(ws + OFF_INT);
    int* fill = deg + N_NODES;
    int* rowp = fill + N_NODES;
    int* col  = rowp + (N_NODES + 1);
    float* zb = ws + OFF_ZB;
    float* yb = zb + 256;

    // conv-phase scratch in DEAD regions (live: HA, XF, weights, ints, zb):
    float* C1Z = ws + OFF_RZ;            // 13,107,200 fl -> ends 32,768,000 (== OFF_XF, no overlap)
    float* P1Z = ws + OFF_HB;            // 6,540,800 -> ends 19,648,000 (< OFF_RZ)
    float* C1Y = ws + OFF_S;             // 3,276,800 -> ends 3,276,800
    float* P1Y = ws + 3300000;           // 1,625,600 -> ends 4,925,600 (< OFF_HA)
    float* P2Z = ws + OFF_P2Z;
    float* P2Y = ws + OFF_P2Y;

    // ---- weight prep ----
    k_cvt<<<192, 256, 0, stream>>>(W_in, Win_h, 49152);
    k_cvt<<<192, 256, 0, stream>>>(W_ih, Wih_h, 49152);
    k_cvt<<<192, 256, 0, stream>>>(W_hh, Whh_h, 49152);
    k_cvt<<<384, 256, 0, stream>>>(W_g, Wg_h, 98304);
    k_cvt<<<38400, 256, 0, stream>>>(x, XF, 9830400);     // XF = fp16 copy of x
    k_bias<<<2, 256, 0, stream>>>(b_ih, b_hh, brz);
    k_bnn<<<2, 256, 0, stream>>>(b_ih, b_hh, bnn);
    k_wpack<<<192, 256, 0, stream>>>(Wc1, Wp);
    // fold Wg: Wrz2[l][:, :256] = Wih[0:512] @ Wg[l]^T ; Wni2[l] = Wih[512:768] @ Wg[l]^T
    k_gemm2<1, 1, 2, 0><<<48, 256, 0, stream>>>(Wih_h, 256, Wg_h, nullptr,
                                                Wrz2, 512, 256, 8, 0, 65536, 262144, 0);
    k_gemm2<1, 1, 2, 0><<<24, 256, 0, stream>>>(Wih_h + 512 * 256, 256, Wg_h, nullptr,
                                                Wni2, 256, 256, 4, 0, 65536, 65536, 0);
    k_wcopyrz<<<3072, 256, 0, stream>>>(Whh_h, Wrz2);

    // ---- CSR build ----
    hipMemsetAsync(deg, 0, N_NODES * sizeof(int), stream);
    hipMemsetAsync(fill, 0, N_NODES * sizeof(int), stream);
    k_deg<<<N_EDGES / 256, 256, 0, stream>>>(ei, deg);
    k_scan<<<1, 1024, 0, stream>>>(deg, rowp);
    k_fill<<<N_EDGES / 256, 256, 0, stream>>>(ei, rowp, fill, col);

    // ---- h0 = XF @ W_in^T + b_in -> HA (f16) ----
    k_gemm2<1, 1, 2, 1><<<800, 256, 0, stream>>>(XF, FEAT, Win_h, b_in, HA, HID,
                                                 FEAT, 800, 0, 0, 0, 0);

    // ---- GGNN layers (h ping-pongs HA <-> HB; ends in HA) ----
    for (int l = 0; l < 6; ++l) {
        _Float16* hc = (l & 1) ? HB : HA;
        _Float16* hn = (l & 1) ? HA : HB;
        k_agg4<<<12800, 256, 0, stream>>>(rowp, col, hc, S);
        k_gemmrz<<<1600, 256, 0, stream>>>(S, hc, Wrz2 + (size_t)l * 262144, brz, RZ);
        k_nngru<<<800, 512, 0, stream>>>(S, hc, Wni2 + (size_t)l * 65536, Whhn, bnn, RZ, hn);
    }

    // ---- conv head: Z path (concat [h|x], H=1024) ----
    k_conv1m<<<1024, 256, 0, stream>>>(HA, XF, Wp, bc1, C1Z, 1024, 4);
    k_pool1<<<dim3(G_GRAPHS, 50), 256, 0, stream>>>(C1Z, P1Z, 1024, 511);
    k_c2p2<<<dim3(G_GRAPHS, 20), 256, 0, stream>>>(P1Z, Wc2, bc2, P2Z, 511, 255);
    k_fc<<<G_GRAPHS, 256, 0, stream>>>(P2Z, Wf1, bf1, zb, 20 * 255);

    // ---- conv head: Y path (h only, H=256) ----
    k_conv1m<<<256, 256, 0, stream>>>(HA, XF, Wp, bc1, C1Y, 256, 1);
    k_pool1<<<dim3(G_GRAPHS, 50), 256, 0, stream>>>(C1Y, P1Y, 256, 127);
    k_c2p2<<<dim3(G_GRAPHS, 20), 256, 0, stream>>>(P1Y, Wc2, bc2, P2Y, 127, 63);
    k_fc<<<G_GRAPHS, 256, 0, stream>>>(P2Y, Wf2, bf2, yb, 20 * 63);

    // ---- final ----
    k_final<<<1, 256, 0, stream>>>(zb, yb, (float*)d_out);
}

// Round 11
// 1123.513 us; speedup vs baseline: 8.5417x; 1.0795x over previous
//
#include <hip/hip_runtime.h>
#include <math.h>

#define N_NODES 51200
#define N_EDGES 409600
#define FEAT    768
#define HID     256
#define NPG     200
#define G_GRAPHS 256

typedef _Float16 f16x8 __attribute__((ext_vector_type(8)));
typedef _Float16 f16x4 __attribute__((ext_vector_type(4)));
typedef float    f32x4 __attribute__((ext_vector_type(4)));

__device__ __forceinline__ void cvt4(const float* __restrict__ in, _Float16* __restrict__ out, int i) {
    float4 v = *(const float4*)&in[i * 4];
    f16x4 h;
    h[0] = (_Float16)v.x; h[1] = (_Float16)v.y; h[2] = (_Float16)v.z; h[3] = (_Float16)v.w;
    *(f16x4*)&out[i * 4] = h;
}

// ---------------- mega prep: all elementwise prep in ONE launch ----------------
// segments (item counts): Win 49152 | Wih 49152 | Whh 49152 | Wg 98304 | wpack 49152 |
// bias 1024 | wcopyrz 786432 | zero-deg 12800 | zero-fill 12800 | x->XF 9830400
__global__ __launch_bounds__(256) void k_prep(const float* __restrict__ W_in, const float* __restrict__ W_ih,
                                              const float* __restrict__ W_hh, const float* __restrict__ W_g,
                                              const float* __restrict__ x, const float* __restrict__ Wc1,
                                              const float* __restrict__ bih, const float* __restrict__ bhh,
                                              _Float16* __restrict__ Win_h, _Float16* __restrict__ Wih_h,
                                              _Float16* __restrict__ Whh_h, _Float16* __restrict__ Wg_h,
                                              _Float16* __restrict__ XF, _Float16* __restrict__ Wp,
                                              float* __restrict__ brz, float* __restrict__ bnn,
                                              _Float16* __restrict__ Wrz2,
                                              int* __restrict__ deg, int* __restrict__ fill) {
    int id = blockIdx.x * 256 + threadIdx.x;
    if (id < 49152) { cvt4(W_in, Win_h, id); return; }
    id -= 49152;
    if (id < 49152) { cvt4(W_ih, Wih_h, id); return; }
    id -= 49152;
    if (id < 49152) { cvt4(W_hh, Whh_h, id); return; }
    id -= 49152;
    if (id < 98304) { cvt4(W_g, Wg_h, id); return; }
    id -= 98304;
    if (id < 49152) {   // wpack: Wp[ch][o][dk*64+cc]
        int ch = id / 12288, r = id - ch * 12288;
        int o = r / 192, k = r - o * 192;
        int dk = k >> 6, cc = k & 63;
        int c = ch * 64 + cc;
        float v = 0.f;
        if (o < 50 && c < NPG) v = Wc1[(o * NPG + c) * 3 + dk];
        Wp[id] = (_Float16)v;
        return;
    }
    id -= 49152;
    if (id < 1024) {    // biases
        if (id < 512) brz[id] = bih[id] + bhh[id];
        else {
            int q = id - 512;
            bnn[q] = (q < 256) ? bih[512 + q] : bhh[512 + (q - 256)];
        }
        return;
    }
    id -= 1024;
    if (id < 786432) {  // Wrz2 right halves from fp32 W_hh: [l][j][256+c] = Whh[j][c]
        int l = id >> 17, r = id & 131071;
        int j = r >> 8, c = r & 255;
        Wrz2[(size_t)l * 262144 + j * 512 + 256 + c] = (_Float16)W_hh[j * 256 + c];
        return;
    }
    id -= 786432;
    if (id < 12800) { *(int4*)&deg[id * 4] = make_int4(0, 0, 0, 0); return; }
    id -= 12800;
    if (id < 12800) { *(int4*)&fill[id * 4] = make_int4(0, 0, 0, 0); return; }
    id -= 12800;
    if (id < 9830400) { cvt4(x, XF, id); return; }
}

// ---------------- CSR build ----------------
__global__ __launch_bounds__(256) void k_deg(const int* __restrict__ ei, int* __restrict__ deg) {
    int e = blockIdx.x * 256 + threadIdx.x;
    if (e < N_EDGES) atomicAdd(&deg[ei[N_EDGES + e]], 1);
}

__global__ __launch_bounds__(1024) void k_scan(const int* __restrict__ deg, int* __restrict__ rowp) {
    __shared__ int sums[1024];
    int tid = threadIdx.x;
    int base = tid * 50;
    int s = 0;
    for (int j = 0; j < 50; ++j) s += deg[base + j];
    sums[tid] = s;
    __syncthreads();
    for (int off = 1; off < 1024; off <<= 1) {
        int v = 0;
        if (tid >= off) v = sums[tid - off];
        __syncthreads();
        sums[tid] += v;
        __syncthreads();
    }
    int run = sums[tid] - s; // exclusive prefix
    for (int j = 0; j < 50; ++j) { rowp[base + j] = run; run += deg[base + j]; }
    if (tid == 1023) rowp[N_NODES] = run;
}

__global__ __launch_bounds__(256) void k_fill(const int* __restrict__ ei, const int* __restrict__ rowp,
                                              int* __restrict__ fill, int* __restrict__ col) {
    int e = blockIdx.x * 256 + threadIdx.x;
    if (e < N_EDGES) {
        int d = ei[N_EDGES + e];
        int pos = atomicAdd(&fill[d], 1);
        col[rowp[d] + pos] = ei[e];
    }
}

// ---------------- fp16 MFMA GEMM (NT): C[M,*] = A[M,K] @ B_f16[J,K]^T + bias ----------------
template<int AF16, int OUT, int COLB, int SWZ>
__global__ __launch_bounds__(256) void k_gemm2(const void* __restrict__ Av, int lda,
                                               const _Float16* __restrict__ B,
                                               const float* __restrict__ bias,
                                               void* __restrict__ Cv, int ldc,
                                               int K, int wgPerL, int aLStride, int bLStride,
                                               int cLStride, int biasStride) {
    __shared__ _Float16 As[128 * 64];
    __shared__ _Float16 Bs[128 * 64];
    int wg = blockIdx.x;
    int l = wg / wgPerL; wg -= l * wgPerL;
    if (AF16) Av = (const void*)((const _Float16*)Av + (size_t)l * aLStride);
    else      Av = (const void*)((const float*)Av + (size_t)l * aLStride);
    B += (size_t)l * bLStride;
    if (bias) bias += (size_t)l * biasStride;
    if (OUT == 1) Cv = (void*)((_Float16*)Cv + (size_t)l * cLStride);
    else          Cv = (void*)((float*)Cv + (size_t)l * cLStride);
    int rowBase, colBase;
    if (SWZ) {
        int xcd = wg & 7, t = wg >> 3;
        int cb = t % COLB, gidx = t / COLB;
        rowBase = (gidx * 8 + xcd) * 128;
        colBase = cb * 128;
    } else {
        rowBase = (wg / COLB) * 128;
        colBase = (wg % COLB) * 128;
    }
    int tid = threadIdx.x;
    int lane = tid & 63;
    int wid = tid >> 6;
    int wr = wid >> 1, wc = wid & 1;
    f32x4 acc[4][4] = {};
    for (int k0 = 0; k0 < K; k0 += 64) {
        __syncthreads();
        #pragma unroll
        for (int p = 0; p < 4; ++p) {
            int c = p * 256 + tid;
            int row = c >> 3, slot = c & 7;
            int dst = row * 64 + ((slot ^ (row & 7)) * 8);
            if (AF16) {
                const _Float16* srcA = (const _Float16*)Av + (size_t)(rowBase + row) * lda + k0 + slot * 8;
                *(f16x8*)&As[dst] = *(const f16x8*)srcA;
            } else {
                const float* srcA = (const float*)Av + (size_t)(rowBase + row) * lda + k0 + slot * 8;
                float4 f0 = *(const float4*)srcA;
                float4 f1 = *(const float4*)(srcA + 4);
                f16x8 hv;
                hv[0] = (_Float16)f0.x; hv[1] = (_Float16)f0.y; hv[2] = (_Float16)f0.z; hv[3] = (_Float16)f0.w;
                hv[4] = (_Float16)f1.x; hv[5] = (_Float16)f1.y; hv[6] = (_Float16)f1.z; hv[7] = (_Float16)f1.w;
                *(f16x8*)&As[dst] = hv;
            }
            const _Float16* srcB = B + (size_t)(colBase + row) * K + k0 + slot * 8;
            *(f16x8*)&Bs[dst] = *(const f16x8*)srcB;
        }
        __syncthreads();
        #pragma unroll
        for (int ks = 0; ks < 2; ++ks) {
            f16x8 af[4], bf[4];
            #pragma unroll
            for (int mi = 0; mi < 4; ++mi) {
                int row = wr * 64 + mi * 16 + (lane & 15);
                int slot = (lane >> 4) + ks * 4;
                af[mi] = *(const f16x8*)&As[row * 64 + ((slot ^ (row & 7)) * 8)];
            }
            #pragma unroll
            for (int nj = 0; nj < 4; ++nj) {
                int row = wc * 64 + nj * 16 + (lane & 15);
                int slot = (lane >> 4) + ks * 4;
                bf[nj] = *(const f16x8*)&Bs[row * 64 + ((slot ^ (row & 7)) * 8)];
            }
            #pragma unroll
            for (int mi = 0; mi < 4; ++mi)
                #pragma unroll
                for (int nj = 0; nj < 4; ++nj)
                    acc[mi][nj] = __builtin_amdgcn_mfma_f32_16x16x32_f16(af[mi], bf[nj], acc[mi][nj], 0, 0, 0);
        }
    }
    #pragma unroll
    for (int mi = 0; mi < 4; ++mi) {
        #pragma unroll
        for (int nj = 0; nj < 4; ++nj) {
            int col = colBase + wc * 64 + nj * 16 + (lane & 15);
            float bv = bias ? bias[col] : 0.f;
            #pragma unroll
            for (int r = 0; r < 4; ++r) {
                int row = rowBase + wr * 64 + mi * 16 + (lane >> 4) * 4 + r;
                float val = acc[mi][nj][r] + bv;
                if (OUT == 0) ((float*)Cv)[(size_t)row * ldc + col] = val;
                else          ((_Float16*)Cv)[(size_t)row * ldc + col] = (_Float16)val;
            }
        }
    }
}

// ---------------- rz GEMM: RZ[N,512] = [S|hc] @ Wrz2_l^T + brz (K=512, dual-A) ----------------
__global__ __launch_bounds__(256) void k_gemmrz(const _Float16* __restrict__ S, const _Float16* __restrict__ hc,
                                                const _Float16* __restrict__ B, const float* __restrict__ bias,
                                                _Float16* __restrict__ C) {
    __shared__ _Float16 As[128 * 64];
    __shared__ _Float16 Bs[128 * 64];
    int wg = blockIdx.x;                 // 1600 = 8 * 4 * 50
    int xcd = wg & 7, t = wg >> 3;
    int cb = t % 4, gidx = t / 4;
    int rowBase = (gidx * 8 + xcd) * 128;
    int colBase = cb * 128;
    int tid = threadIdx.x;
    int lane = tid & 63;
    int wid = tid >> 6;
    int wr = wid >> 1, wc = wid & 1;
    f32x4 acc[4][4] = {};
    for (int k0 = 0; k0 < 512; k0 += 64) {
        const _Float16* Abase = (k0 < 256) ? S : hc;
        int kk = k0 & 255;
        __syncthreads();
        #pragma unroll
        for (int p = 0; p < 4; ++p) {
            int c = p * 256 + tid;
            int row = c >> 3, slot = c & 7;
            int dst = row * 64 + ((slot ^ (row & 7)) * 8);
            *(f16x8*)&As[dst] = *(const f16x8*)&Abase[(size_t)(rowBase + row) * 256 + kk + slot * 8];
            *(f16x8*)&Bs[dst] = *(const f16x8*)&B[(size_t)(colBase + row) * 512 + k0 + slot * 8];
        }
        __syncthreads();
        #pragma unroll
        for (int ks = 0; ks < 2; ++ks) {
            f16x8 af[4], bf[4];
            #pragma unroll
            for (int mi = 0; mi < 4; ++mi) {
                int row = wr * 64 + mi * 16 + (lane & 15);
                int slot = (lane >> 4) + ks * 4;
                af[mi] = *(const f16x8*)&As[row * 64 + ((slot ^ (row & 7)) * 8)];
            }
            #pragma unroll
            for (int nj = 0; nj < 4; ++nj) {
                int row = wc * 64 + nj * 16 + (lane & 15);
                int slot = (lane >> 4) + ks * 4;
                bf[nj] = *(const f16x8*)&Bs[row * 64 + ((slot ^ (row & 7)) * 8)];
            }
            #pragma unroll
            for (int mi = 0; mi < 4; ++mi)
                #pragma unroll
                for (int nj = 0; nj < 4; ++nj)
                    acc[mi][nj] = __builtin_amdgcn_mfma_f32_16x16x32_f16(af[mi], bf[nj], acc[mi][nj], 0, 0, 0);
        }
    }
    #pragma unroll
    for (int mi = 0; mi < 4; ++mi) {
        #pragma unroll
        for (int nj = 0; nj < 4; ++nj) {
            int col = colBase + wc * 64 + nj * 16 + (lane & 15);
            float bv = bias[col];
            #pragma unroll
            for (int r = 0; r < 4; ++r) {
                int row = rowBase + wr * 64 + mi * 16 + (lane >> 4) * 4 + r;
                C[(size_t)row * 512 + col] = (_Float16)(acc[mi][nj][r] + bv);
            }
        }
    }
}

// ---------------- fused n-gate GEMMs + GRU ----------------
__global__ __launch_bounds__(512) void k_nngru(const _Float16* __restrict__ S, const _Float16* __restrict__ hc,
                                               const _Float16* __restrict__ B0, const _Float16* __restrict__ B1,
                                               const float* __restrict__ bnn, const _Float16* __restrict__ rz,
                                               _Float16* __restrict__ hn) {
    __shared__ _Float16 As0[128 * 64], As1[128 * 64], Bs0[128 * 64], Bs1[128 * 64];
    int wg = blockIdx.x;                 // 800 = 8 * 2 * 50
    int xcd = wg & 7, t = wg >> 3;
    int cb = t % 2, gidx = t / 2;
    int rowBase = (gidx * 8 + xcd) * 128;
    int colBase = cb * 128;
    int tid = threadIdx.x;
    int lane = tid & 63;
    int wid = tid >> 6;
    int wr = wid >> 2, wc = wid & 3;
    f32x4 acc0[4][2] = {}, acc1[4][2] = {};
    for (int k0 = 0; k0 < 256; k0 += 64) {
        __syncthreads();
        #pragma unroll
        for (int p = 0; p < 8; ++p) {
            int q = p * 512 + tid;
            int tile = q >> 10;
            int c = q & 1023;
            int row = c >> 3, slot = c & 7;
            int dst = row * 64 + ((slot ^ (row & 7)) * 8);
            const _Float16* src;
            _Float16* d;
            if (tile == 0)      { src = S  + (size_t)(rowBase + row) * 256 + k0 + slot * 8; d = As0; }
            else if (tile == 1) { src = hc + (size_t)(rowBase + row) * 256 + k0 + slot * 8; d = As1; }
            else if (tile == 2) { src = B0 + (size_t)(colBase + row) * 256 + k0 + slot * 8; d = Bs0; }
            else                { src = B1 + (size_t)(colBase + row) * 256 + k0 + slot * 8; d = Bs1; }
            *(f16x8*)&d[dst] = *(const f16x8*)src;
        }
        __syncthreads();
        #pragma unroll
        for (int ks = 0; ks < 2; ++ks) {
            f16x8 a0[4], a1[4], b0[2], b1[2];
            #pragma unroll
            for (int mi = 0; mi < 4; ++mi) {
                int row = wr * 64 + mi * 16 + (lane & 15);
                int slot = (lane >> 4) + ks * 4;
                int off = row * 64 + ((slot ^ (row & 7)) * 8);
                a0[mi] = *(const f16x8*)&As0[off];
                a1[mi] = *(const f16x8*)&As1[off];
            }
            #pragma unroll
            for (int nj = 0; nj < 2; ++nj) {
                int row = wc * 32 + nj * 16 + (lane & 15);
                int slot = (lane >> 4) + ks * 4;
                int off = row * 64 + ((slot ^ (row & 7)) * 8);
                b0[nj] = *(const f16x8*)&Bs0[off];
                b1[nj] = *(const f16x8*)&Bs1[off];
            }
            #pragma unroll
            for (int mi = 0; mi < 4; ++mi)
                #pragma unroll
                for (int nj = 0; nj < 2; ++nj) {
                    acc0[mi][nj] = __builtin_amdgcn_mfma_f32_16x16x32_f16(a0[mi], b0[nj], acc0[mi][nj], 0, 0, 0);
                    acc1[mi][nj] = __builtin_amdgcn_mfma_f32_16x16x32_f16(a1[mi], b1[nj], acc1[mi][nj], 0, 0, 0);
                }
        }
    }
    #pragma unroll
    for (int mi = 0; mi < 4; ++mi) {
        #pragma unroll
        for (int nj = 0; nj < 2; ++nj) {
            int col = colBase + wc * 32 + nj * 16 + (lane & 15);
            float bi = bnn[col], bh = bnn[256 + col];
            #pragma unroll
            for (int r = 0; r < 4; ++r) {
                int row = rowBase + wr * 64 + mi * 16 + (lane >> 4) * 4 + r;
                float rv = (float)rz[(size_t)row * 512 + col];
                float zv = (float)rz[(size_t)row * 512 + 256 + col];
                float rg = 1.f / (1.f + expf(-rv));
                float zg = 1.f / (1.f + expf(-zv));
                float ng = tanhf((acc0[mi][nj][r] + bi) + rg * (acc1[mi][nj][r] + bh));
                float ho = (float)hc[(size_t)row * 256 + col];
                hn[(size_t)row * 256 + col] = (_Float16)((1.f - zg) * ng + zg * ho);
            }
        }
    }
}

// ---------------- gather-sum of hc into S (wave-per-node, b64 loads, unroll 4) ----------------
__global__ __launch_bounds__(256) void k_agg4(const int* __restrict__ rowp, const int* __restrict__ col,
                                              const _Float16* __restrict__ hc, _Float16* __restrict__ S) {
    int v = blockIdx.x * 4 + (threadIdx.x >> 6);
    int lane = threadIdx.x & 63;
    int beg = rowp[v], end = rowp[v + 1];
    const _Float16* hf = hc + lane * 4;
    float a0 = 0.f, a1 = 0.f, a2 = 0.f, a3 = 0.f;
    int i = beg;
    for (; i + 3 < end; i += 4) {
        int c0 = col[i], c1 = col[i + 1], c2 = col[i + 2], c3 = col[i + 3];
        f16x4 u0 = *(const f16x4*)&hf[(size_t)c0 * 256];
        f16x4 u1 = *(const f16x4*)&hf[(size_t)c1 * 256];
        f16x4 u2 = *(const f16x4*)&hf[(size_t)c2 * 256];
        f16x4 u3 = *(const f16x4*)&hf[(size_t)c3 * 256];
        a0 += ((float)u0[0] + (float)u1[0]) + ((float)u2[0] + (float)u3[0]);
        a1 += ((float)u0[1] + (float)u1[1]) + ((float)u2[1] + (float)u3[1]);
        a2 += ((float)u0[2] + (float)u1[2]) + ((float)u2[2] + (float)u3[2]);
        a3 += ((float)u0[3] + (float)u1[3]) + ((float)u2[3] + (float)u3[3]);
    }
    for (; i < end; ++i) {
        f16x4 u = *(const f16x4*)&hf[(size_t)col[i] * 256];
        a0 += (float)u[0]; a1 += (float)u[1]; a2 += (float)u[2]; a3 += (float)u[3];
    }
    f16x4 o;
    o[0] = (_Float16)a0; o[1] = (_Float16)a1; o[2] = (_Float16)a2; o[3] = (_Float16)a3;
    *(f16x4*)&S[(size_t)v * 256 + lane * 4] = o;
}

// ---------------- conv1 as MFMA implicit GEMM, merged Z+Y launch ----------------
__global__ __launch_bounds__(256, 2) void k_conv1m(const _Float16* __restrict__ hf, const _Float16* __restrict__ xf,
                                                   const _Float16* __restrict__ Wp, const float* __restrict__ bc1,
                                                   float* __restrict__ outZ, float* __restrict__ outY) {
    __shared__ _Float16 XT[272 * 64];
    __shared__ _Float16 WL[64 * 192];
    int b = blockIdx.x;
    int g, t0, H;
    float* out;
    if (b < 1024) { g = b >> 2; t0 = (b & 3) * 256; H = 1024; out = outZ; }
    else          { g = b - 1024; t0 = 0; H = 256; out = outY; }
    int tid = threadIdx.x;
    int lane = tid & 63;
    int wn = (tid >> 6) * 64;
    f32x4 acc[4][4] = {};
    for (int ch = 0; ch < 4; ++ch) {
        __syncthreads();
        #pragma unroll
        for (int i = 0; i < 6; ++i) {
            int q = i * 256 + tid;
            int o = q / 24, sk = q - o * 24;
            int skp = (sk & 0x18) | ((sk & 7) ^ (o & 7));
            *(f16x8*)&WL[o * 192 + skp * 8] = *(const f16x8*)&Wp[ch * 12288 + o * 192 + sk * 8];
        }
        for (int u = tid; u < 272; u += 256) {
            int r8 = u / 34, pc = u - r8 * 34;
            int gstart = t0 - 8 + pc * 8;
            int c0 = r8 * 8;
            f16x8 zv;
            #pragma unroll
            for (int q = 0; q < 8; ++q) zv[q] = (_Float16)0.f;
            f16x8 rows[8];
            if (gstart < 0 || gstart >= H) {
                #pragma unroll
                for (int j = 0; j < 8; ++j) rows[j] = zv;
            } else {
                const _Float16* base;
                int stride;
                if (gstart < HID) { base = hf + gstart; stride = 256; }
                else              { base = xf + (gstart - HID); stride = 768; }
                int node0 = g * NPG + ch * 64 + c0;
                #pragma unroll
                for (int j = 0; j < 8; ++j) {
                    int cg = ch * 64 + c0 + j;
                    rows[j] = (cg < NPG) ? *(const f16x8*)&base[(size_t)(node0 + j) * stride] : zv;
                }
            }
            #pragma unroll
            for (int jj = 0; jj < 8; ++jj) {
                f16x8 w;
                #pragma unroll
                for (int j = 0; j < 8; ++j) w[j] = rows[j][jj];
                int p = pc * 8 + jj;
                int slot = r8 ^ jj ^ (pc & 7);
                *(f16x8*)&XT[p * 64 + slot * 8] = w;
            }
        }
        __syncthreads();
        #pragma unroll
        for (int ks = 0; ks < 6; ++ks) {
            int dk = ks >> 1, cs0 = (ks & 1) << 2;
            f16x8 af[4], bf[4];
            #pragma unroll
            for (int mi = 0; mi < 4; ++mi) {
                int o = mi * 16 + (lane & 15);
                int sk = ks * 4 + (lane >> 4);
                int skp = (sk & 0x18) | ((sk & 7) ^ (o & 7));
                af[mi] = *(const f16x8*)&WL[o * 192 + skp * 8];
            }
            #pragma unroll
            for (int nj = 0; nj < 4; ++nj) {
                int tw = wn + nj * 16 + (lane & 15) + dk + 7;
                int sp = (cs0 + (lane >> 4)) ^ (tw & 7) ^ ((tw >> 3) & 7);
                bf[nj] = *(const f16x8*)&XT[tw * 64 + sp * 8];
            }
            #pragma unroll
            for (int mi = 0; mi < 4; ++mi)
                #pragma unroll
                for (int nj = 0; nj < 4; ++nj)
                    acc[mi][nj] = __builtin_amdgcn_mfma_f32_16x16x32_f16(af[mi], bf[nj], acc[mi][nj], 0, 0, 0);
        }
    }
    #pragma unroll
    for (int mi = 0; mi < 4; ++mi) {
        #pragma unroll
        for (int r = 0; r < 4; ++r) {
            int o = mi * 16 + (lane >> 4) * 4 + r;
            if (o < 50) {
                float bv = bc1[o];
                #pragma unroll
                for (int nj = 0; nj < 4; ++nj) {
                    int t = t0 + wn + nj * 16 + (lane & 15);
                    float v = acc[mi][nj][r] + bv;
                    out[(size_t)g * 50 * H + (size_t)o * H + t] = v > 0.f ? v : 0.f;
                }
            }
        }
    }
}

// ---------------- maxpool1d k=3 s=2, merged Z+Y ----------------
__global__ __launch_bounds__(256) void k_pool1(const float* __restrict__ C1Z, const float* __restrict__ C1Y,
                                               float* __restrict__ P1Z, float* __restrict__ P1Y) {
    int b = blockIdx.x;
    const float* in;
    float* out;
    int H, U, go;
    if (b < 12800) { in = C1Z; out = P1Z; H = 1024; U = 511; go = b; }
    else           { in = C1Y; out = P1Y; H = 256;  U = 127; go = b - 12800; }
    const float* p = in + (size_t)go * H;
    float* q = out + (size_t)go * U;
    for (int u = threadIdx.x; u < U; u += 256) {
        float a = p[2 * u], bb = p[2 * u + 1], c = p[2 * u + 2];
        float mm = a > bb ? a : bb;
        q[u] = mm > c ? mm : c;
    }
}

// ---------------- conv2 (k=1) + maxpool k=2 s=2, merged Z+Y ----------------
__global__ __launch_bounds__(256) void k_c2p2(const float* __restrict__ P1Z, const float* __restrict__ P1Y,
                                              const float* __restrict__ Wc2, const float* __restrict__ bc2,
                                              float* __restrict__ P2Z, float* __restrict__ P2Y) {
    int g = blockIdx.x, oy = blockIdx.y;
    const float* P1;
    float* out;
    int U, U2, o2;
    if (oy < 20) { P1 = P1Z; out = P2Z; U = 511; U2 = 255; o2 = oy; }
    else         { P1 = P1Y; out = P2Y; U = 127; U2 = 63;  o2 = oy - 20; }
    float b = bc2[o2];
    for (int u2 = threadIdx.x; u2 < U2; u2 += 256) {
        float a0 = b, a1 = b;
        #pragma unroll 5
        for (int i = 0; i < 50; ++i) {
            float wv = Wc2[o2 * 50 + i];
            const float* p = P1 + ((size_t)g * 50 + i) * U + 2 * u2;
            a0 = fmaf(p[0], wv, a0);
            a1 = fmaf(p[1], wv, a1);
        }
        out[((size_t)g * 20 + o2) * U2 + u2] = a0 > a1 ? a0 : a1;
    }
}

// ---------------- fully-connected (per-graph dot), merged Z+Y ----------------
__global__ __launch_bounds__(256) void k_fc(const float* __restrict__ P2Z, const float* __restrict__ P2Y,
                                            const float* __restrict__ Wf1, const float* __restrict__ bf1,
                                            const float* __restrict__ Wf2, const float* __restrict__ bf2,
                                            float* __restrict__ zb, float* __restrict__ yb) {
    __shared__ float red[256];
    int b = blockIdx.x, tid = threadIdx.x;
    int g = b & 255;
    const float* P2;
    const float* Wf;
    const float* bf;
    float* out;
    int len;
    if (b < 256) { P2 = P2Z; Wf = Wf1; bf = bf1; out = zb; len = 20 * 255; }
    else         { P2 = P2Y; Wf = Wf2; bf = bf2; out = yb; len = 20 * 63; }
    const float* p = P2 + (size_t)g * len;
    float s = 0.f;
    for (int i = tid; i < len; i += 256) s = fmaf(p[i], Wf[i], s);
    red[tid] = s;
    __syncthreads();
    for (int off = 128; off > 0; off >>= 1) {
        if (tid < off) red[tid] += red[tid + off];
        __syncthreads();
    }
    if (tid == 0) out[g] = red[0] + bf[0];
}

// ---------------- final: sigmoid(z*y) -> clip -> logit -> [0, z1] ----------------
__global__ __launch_bounds__(256) void k_final(const float* __restrict__ z, const float* __restrict__ y,
                                               float* __restrict__ out) {
    int g = threadIdx.x;
    float t = z[g] * y[g];
    float p = 1.f / (1.f + expf(-t));
    p = fminf(fmaxf(p, 1e-6f), 1.f - 1e-6f);
    float z1 = logf(p / (1.f - p));
    out[2 * g] = 0.f;
    out[2 * g + 1] = z1;
}

extern "C" void kernel_launch(void* const* d_in, const int* in_sizes, int n_in,
                              void* d_out, int out_size, void* d_ws, size_t ws_size,
                              hipStream_t stream) {
    const float* x     = (const float*)d_in[0];
    const int*   ei    = (const int*)d_in[1];
    const float* W_in  = (const float*)d_in[2];
    const float* b_in  = (const float*)d_in[3];
    const float* W_g   = (const float*)d_in[4];
    const float* W_ih  = (const float*)d_in[5];
    const float* W_hh  = (const float*)d_in[6];
    const float* b_ih  = (const float*)d_in[7];
    const float* b_hh  = (const float*)d_in[8];
    const float* Wc1   = (const float*)d_in[9];
    const float* bc1   = (const float*)d_in[10];
    const float* Wc2   = (const float*)d_in[11];
    const float* bc2   = (const float*)d_in[12];
    const float* Wf1   = (const float*)d_in[13];
    const float* bf1   = (const float*)d_in[14];
    const float* Wf2   = (const float*)d_in[15];
    const float* bf2   = (const float*)d_in[16];

    float* ws = (float*)d_ws;
    // layout (float units) — identical to round 10 (verified):
    const size_t OFF_S   = 0;           // S  f16 [N,256] -> 6,553,600
    const size_t OFF_HA  = 6553600;     // HA f16 [N,256] -> 13,107,200
    const size_t OFF_HB  = 13107200;    // HB f16 [N,256] -> 19,660,800
    const size_t OFF_RZ  = 19660800;    // RZ f16 [N,512] -> 32,768,000
    const size_t OFF_XF  = 32768000;    // XF f16 [N,768] -> 52,428,800
    const size_t OFF_WF  = 52428800;    // f16 arena 2,998,272 f16 -> 53,927,936
    const size_t OFF_BRZ = 53927936;    // [512] -> 53,928,448
    const size_t OFF_BNN = 53928448;    // [512] -> 53,928,960
    const size_t OFF_INT = 53928960;    // ints 563,201 -> 54,492,161
    const size_t OFF_ZB  = 54492200;    // [512]
    const size_t OFF_P2Z = 54500000;    // 1,305,600 -> 55,805,600
    const size_t OFF_P2Y = 55900000;    // 322,560  -> 56,222,560

    _Float16* S  = (_Float16*)(ws + OFF_S);
    _Float16* HA = (_Float16*)(ws + OFF_HA);
    _Float16* HB = (_Float16*)(ws + OFF_HB);
    _Float16* RZ = (_Float16*)(ws + OFF_RZ);
    _Float16* XF = (_Float16*)(ws + OFF_XF);

    _Float16* Win_h = (_Float16*)(ws + OFF_WF);  // [256][768] = 196,608
    _Float16* Wih_h = Win_h + 196608;            // [768][256]
    _Float16* Whh_h = Wih_h + 196608;            // [768][256]
    _Float16* Wg_h  = Whh_h + 196608;            // [6][256][256] = 393,216
    _Float16* Wrz2  = Wg_h  + 393216;            // [6][512][512] = 1,572,864
    _Float16* Wni2  = Wrz2  + 1572864;           // [6][256][256] = 393,216
    _Float16* Wp    = Wni2  + 393216;            // [4][64][192] = 49,152
    _Float16* Whhn  = Whh_h + 512 * 256;         // Whh rows 512..767
    float* brz = ws + OFF_BRZ;
    float* bnn = ws + OFF_BNN;

    int* deg  = (int*)(ws + OFF_INT);
    int* fill = deg + N_NODES;
    int* rowp = fill + N_NODES;
    int* col  = rowp + (N_NODES + 1);
    float* zb = ws + OFF_ZB;
    float* yb = zb + 256;

    // conv-phase scratch in DEAD regions (live then: HA, XF, weights, ints, zb):
    float* C1Z = ws + OFF_RZ;            // 13,107,200 -> ends 32,768,000 (== OFF_XF)
    float* P1Z = ws + OFF_HB;            // 6,540,800  -> ends 19,648,000 (< OFF_RZ)
    float* C1Y = ws + OFF_S;             // 3,276,800
    float* P1Y = ws + 3300000;           // 1,625,600  -> ends 4,925,600 (< OFF_HA)
    float* P2Z = ws + OFF_P2Z;
    float* P2Y = ws + OFF_P2Y;

    // ---- mega prep (all elementwise prep + deg/fill zeroing, ONE launch) ----
    k_prep<<<42728, 256, 0, stream>>>(W_in, W_ih, W_hh, W_g, x, Wc1, b_ih, b_hh,
                                      Win_h, Wih_h, Whh_h, Wg_h, XF, Wp, brz, bnn, Wrz2,
                                      deg, fill);
    // fold Wg: Wrz2[l][:, :256] = Wih[0:512] @ Wg[l]^T ; Wni2[l] = Wih[512:768] @ Wg[l]^T
    k_gemm2<1, 1, 2, 0><<<48, 256, 0, stream>>>(Wih_h, 256, Wg_h, nullptr,
                                                Wrz2, 512, 256, 8, 0, 65536, 262144, 0);
    k_gemm2<1, 1, 2, 0><<<24, 256, 0, stream>>>(Wih_h + 512 * 256, 256, Wg_h, nullptr,
                                                Wni2, 256, 256, 4, 0, 65536, 65536, 0);

    // ---- CSR build ----
    k_deg<<<N_EDGES / 256, 256, 0, stream>>>(ei, deg);
    k_scan<<<1, 1024, 0, stream>>>(deg, rowp);
    k_fill<<<N_EDGES / 256, 256, 0, stream>>>(ei, rowp, fill, col);

    // ---- h0 = XF @ W_in^T + b_in -> HA (f16) ----
    k_gemm2<1, 1, 2, 1><<<800, 256, 0, stream>>>(XF, FEAT, Win_h, b_in, HA, HID,
                                                 FEAT, 800, 0, 0, 0, 0);

    // ---- GGNN layers (h ping-pongs HA <-> HB; ends in HA) ----
    for (int l = 0; l < 6; ++l) {
        _Float16* hc = (l & 1) ? HB : HA;
        _Float16* hn = (l & 1) ? HA : HB;
        k_agg4<<<12800, 256, 0, stream>>>(rowp, col, hc, S);
        k_gemmrz<<<1600, 256, 0, stream>>>(S, hc, Wrz2 + (size_t)l * 262144, brz, RZ);
        k_nngru<<<800, 512, 0, stream>>>(S, hc, Wni2 + (size_t)l * 65536, Whhn, bnn, RZ, hn);
    }

    // ---- conv head, merged Z+Y launches ----
    k_conv1m<<<1280, 256, 0, stream>>>(HA, XF, Wp, bc1, C1Z, C1Y);
    k_pool1<<<25600, 256, 0, stream>>>(C1Z, C1Y, P1Z, P1Y);
    k_c2p2<<<dim3(G_GRAPHS, 40), 256, 0, stream>>>(P1Z, P1Y, Wc2, bc2, P2Z, P2Y);
    k_fc<<<512, 256, 0, stream>>>(P2Z, P2Y, Wf1, bf1, Wf2, bf2, zb, yb);

    // ---- final ----
    k_final<<<1, 256, 0, stream>>>(zb, yb, (float*)d_out);
}